// Round 1
// baseline (2160.796 us; speedup 1.0000x reference)
//
#include <hip/hip_runtime.h>
#include <math.h>

#define B_ 128
#define N_ 197
#define F_ 768
#define NH_ 512
#define D2_ 1024
#define D4_ 2048
#define NC_ 1000
#define ROWS_ (B_ * N_)   // 25216
#define LDA2_ 208         // padded leading dim for A2f (multiple of 16 floats)

// workspace offsets (bytes, all 16B aligned)
#define OFF_A2F   0ull                 // dist [B,N,N] f32 (early) / A2f [B,N,LDA2] f32 (late): 20,979,712
#define OFF_SQ    20979712ull          // [ROWS] f32: 100,864
#define OFF_ABITS 21080576ull          // [ROWS][4] u64: 806,912
#define OFF_DEG   21887488ull          // [ROWS] f32: 100,864
#define OFF_MSG   21988352ull          // [ROWS,512] f32: 51,642,368
#define OFF_H1    73630720ull          // [ROWS,1024] f32: 103,284,736
#define OFF_POOL  176915456ull         // [B,2048] f32: 1,048,576
#define OFF_P     177964032ull         // [B,512] f32: 262,144

// ---------------- squared norms ----------------
__global__ __launch_bounds__(256) void sqnorm_kernel(const float* __restrict__ X,
                                                     float* __restrict__ sq) {
  int row = blockIdx.x * 4 + (threadIdx.x >> 6);
  int lane = threadIdx.x & 63;
  const float4* xp = (const float4*)(X + (size_t)row * F_);
  float s = 0.f;
#pragma unroll
  for (int i = 0; i < 3; i++) {  // 768/4 = 192 = 3*64
    float4 v = xp[lane + i * 64];
    s += v.x * v.x + v.y * v.y + v.z * v.z + v.w * v.w;
  }
#pragma unroll
  for (int o = 32; o > 0; o >>= 1) s += __shfl_down(s, o);
  if (lane == 0) sq[row] = s;
}

// ---------------- pairwise distances (Gram, tiled) ----------------
__global__ __launch_bounds__(256) void dist_kernel(const float* __restrict__ X,
                                                   const float* __restrict__ sq,
                                                   float* __restrict__ dist) {
  __shared__ float As[32][33];
  __shared__ float Bs[32][33];
  int b = blockIdx.z;
  int n0 = blockIdx.y * 32, m0 = blockIdx.x * 32;
  int tx = threadIdx.x, ty = threadIdx.y;
  int tid = ty * 16 + tx;
  const float* Xb = X + (size_t)b * N_ * F_;
  float acc00 = 0.f, acc01 = 0.f, acc10 = 0.f, acc11 = 0.f;
  for (int k0 = 0; k0 < F_; k0 += 32) {
#pragma unroll
    for (int i = 0; i < 4; i++) {
      int e = tid + i * 256;
      int r = e >> 5, k = e & 31;
      As[k][r] = (n0 + r < N_) ? Xb[(size_t)(n0 + r) * F_ + k0 + k] : 0.f;
      Bs[k][r] = (m0 + r < N_) ? Xb[(size_t)(m0 + r) * F_ + k0 + k] : 0.f;
    }
    __syncthreads();
#pragma unroll
    for (int k = 0; k < 32; k++) {
      float a0 = As[k][ty], a1 = As[k][ty + 16];
      float b0 = Bs[k][tx], b1 = Bs[k][tx + 16];
      acc00 = fmaf(a0, b0, acc00);
      acc01 = fmaf(a0, b1, acc01);
      acc10 = fmaf(a1, b0, acc10);
      acc11 = fmaf(a1, b1, acc11);
    }
    __syncthreads();
  }
  float accs[2][2] = {{acc00, acc01}, {acc10, acc11}};
  int n_base = b * N_;
#pragma unroll
  for (int i = 0; i < 2; i++) {
    int n = n0 + ty + i * 16;
    if (n >= N_) continue;
    float sn = sq[n_base + n];
#pragma unroll
    for (int j = 0; j < 2; j++) {
      int m = m0 + tx + j * 16;
      if (m >= N_) continue;
      float d = sn + sq[n_base + m] - 2.f * accs[i][j];
      if (n == m) d = INFINITY;
      dist[((size_t)n_base + n) * N_ + m] = d;
    }
  }
}

// ---------------- top-4 per row -> symmetric adjacency bitmask ----------------
__global__ __launch_bounds__(256) void topk_kernel(const float* __restrict__ dist,
                                                   unsigned long long* __restrict__ Abits) {
  int row = blockIdx.x * 4 + (threadIdx.x >> 6);
  int lane = threadIdx.x & 63;
  int b = row / N_, n = row - b * N_;
  const float* dr = dist + (size_t)row * N_;
  float v[4];
  int vi[4];
#pragma unroll
  for (int i = 0; i < 4; i++) {
    int m = lane + i * 64;
    bool ok = (m < N_);
    v[i] = ok ? dr[m] : INFINITY;
    vi[i] = ok ? m : 0x3fffffff;
  }
  unsigned long long nbr[4] = {0ull, 0ull, 0ull, 0ull};
#pragma unroll
  for (int t = 0; t < 4; t++) {
    float bv = v[0];
    int bi = vi[0];
#pragma unroll
    for (int i = 1; i < 4; i++)
      if (v[i] < bv || (v[i] == bv && vi[i] < bi)) { bv = v[i]; bi = vi[i]; }
#pragma unroll
    for (int o = 1; o < 64; o <<= 1) {
      float ov = __shfl_xor(bv, o);
      int oi = __shfl_xor(bi, o);
      if (ov < bv || (ov == bv && oi < bi)) { bv = ov; bi = oi; }
    }
#pragma unroll
    for (int i = 0; i < 4; i++)
      if (vi[i] == bi) { v[i] = INFINITY; vi[i] = 0x3fffffff; }
    if (lane == 0) {
      nbr[bi >> 6] |= 1ull << (bi & 63);
      // reverse edge (symmetrize)
      atomicOr(&Abits[((size_t)b * N_ + bi) * 4 + (n >> 6)], 1ull << (n & 63));
    }
  }
  if (lane == 0) {
#pragma unroll
    for (int w = 0; w < 4; w++)
      if (nbr[w]) atomicOr(&Abits[(size_t)row * 4 + w], nbr[w]);
  }
}

// ---------------- 2-hop adjacency (OR of neighbor bit-rows) ----------------
__global__ __launch_bounds__(256) void a2_kernel(const unsigned long long* __restrict__ Abits,
                                                 float* __restrict__ A2f,
                                                 float* __restrict__ deg) {
  int row = blockIdx.x * 4 + (threadIdx.x >> 6);
  int lane = threadIdx.x & 63;
  int b = row / N_, n = row - b * N_;
  const unsigned long long* arow = Abits + (size_t)row * 4;
  const unsigned long long* base = Abits + (size_t)b * N_ * 4;
  unsigned long long r0 = 0, r1 = 0, r2 = 0, r3 = 0;
#pragma unroll
  for (int w = 0; w < 4; w++) {
    if ((arow[w] >> lane) & 1ull) {
      const unsigned long long* mr = base + (size_t)(w * 64 + lane) * 4;
      r0 |= mr[0]; r1 |= mr[1]; r2 |= mr[2]; r3 |= mr[3];
    }
  }
#pragma unroll
  for (int o = 1; o < 64; o <<= 1) {
    r0 |= __shfl_xor(r0, o);
    r1 |= __shfl_xor(r1, o);
    r2 |= __shfl_xor(r2, o);
    r3 |= __shfl_xor(r3, o);
  }
  unsigned long long rr[4] = {r0, r1, r2, r3};
  rr[n >> 6] &= ~(1ull << (n & 63));  // zero diagonal
  float* out = A2f + (size_t)row * LDA2_;
#pragma unroll
  for (int i = 0; i < 4; i++) {
    int m = lane + i * 64;
    if (m < LDA2_)
      out[m] = (m < N_ && ((rr[m >> 6] >> (m & 63)) & 1ull)) ? 1.f : 0.f;
  }
  if (lane == 0) {
    int dg = __popcll(rr[0]) + __popcll(rr[1]) + __popcll(rr[2]) + __popcll(rr[3]);
    deg[row] = (float)(dg > 0 ? dg : 1);
  }
}

// ---------------- generic linear: Y = opt_relu(X @ W^T + bias) ----------------
// MODE 0: store; MODE 1: store + relu; MODE 2: relu + per-batch row-sum into pool (atomic)
template <int MODE>
__global__ __launch_bounds__(256) void linear_kernel(const float* __restrict__ Xg,
                                                     const float* __restrict__ W,
                                                     const float* __restrict__ bias,
                                                     float* __restrict__ Y, int ldy, int colOff,
                                                     int Rows, int Fin, int O,
                                                     float* __restrict__ pool, int poolOff) {
  __shared__ float Xs[16][68];
  __shared__ float Ws[16][68];
  int tx = threadIdx.x, ty = threadIdx.y;
  int tid = ty * 16 + tx;
  int lr = tid >> 2;
  int lk = (tid & 3) * 4;
  int rbase = blockIdx.y * 64;
  int o0 = blockIdx.x * 64;
  const float* X = Xg;
  if (MODE == 2) { X = Xg + (size_t)blockIdx.z * N_ * Fin; Rows = N_; }
  float acc[4][4] = {};
  for (int k0 = 0; k0 < Fin; k0 += 16) {
    float4 xv = make_float4(0.f, 0.f, 0.f, 0.f);
    if (rbase + lr < Rows) xv = *(const float4*)&X[(size_t)(rbase + lr) * Fin + k0 + lk];
    Xs[lk][lr] = xv.x; Xs[lk + 1][lr] = xv.y; Xs[lk + 2][lr] = xv.z; Xs[lk + 3][lr] = xv.w;
    float4 wv = make_float4(0.f, 0.f, 0.f, 0.f);
    if (o0 + lr < O) wv = *(const float4*)&W[(size_t)(o0 + lr) * Fin + k0 + lk];
    Ws[lk][lr] = wv.x; Ws[lk + 1][lr] = wv.y; Ws[lk + 2][lr] = wv.z; Ws[lk + 3][lr] = wv.w;
    __syncthreads();
#pragma unroll
    for (int k = 0; k < 16; k++) {
      float4 a = *(const float4*)&Xs[k][ty * 4];
      float4 bb = *(const float4*)&Ws[k][tx * 4];
      float av[4] = {a.x, a.y, a.z, a.w};
      float bv[4] = {bb.x, bb.y, bb.z, bb.w};
#pragma unroll
      for (int i = 0; i < 4; i++)
#pragma unroll
        for (int j = 0; j < 4; j++) acc[i][j] = fmaf(av[i], bv[j], acc[i][j]);
    }
    __syncthreads();
  }
  if (MODE <= 1) {
#pragma unroll
    for (int i = 0; i < 4; i++) {
      int rrow = rbase + ty * 4 + i;
      if (rrow >= Rows) continue;
#pragma unroll
      for (int j = 0; j < 4; j++) {
        int c = o0 + tx * 4 + j;
        if (c >= O) continue;
        float vv = acc[i][j] + bias[c];
        if (MODE == 1) vv = fmaxf(vv, 0.f);
        Y[(size_t)rrow * ldy + colOff + c] = vv;
      }
    }
  } else {
    float cs[4];
#pragma unroll
    for (int j = 0; j < 4; j++) {
      int c = o0 + tx * 4 + j;
      float bsv = (c < O) ? bias[c] : 0.f;
      float s = 0.f;
#pragma unroll
      for (int i = 0; i < 4; i++) {
        int rrow = rbase + ty * 4 + i;
        if (rrow < Rows) s += fmaxf(acc[i][j] + bsv, 0.f);
      }
      cs[j] = s;
    }
    __syncthreads();
#pragma unroll
    for (int j = 0; j < 4; j++) Xs[ty][tx * 4 + j] = cs[j];
    __syncthreads();
    if (ty == 0) {
#pragma unroll
      for (int j = 0; j < 4; j++) {
        int c = o0 + tx * 4 + j;
        if (c >= O) continue;
        float s = 0.f;
#pragma unroll
        for (int t = 0; t < 16; t++) s += Xs[t][tx * 4 + j];
        atomicAdd(&pool[(size_t)blockIdx.z * D4_ + poolOff + c], s);
      }
    }
  }
}

// ---------------- aggregation: agg = relu((A2f @ msg) / deg) ----------------
// MODE 0: write into h1[:, NH:2NH]; MODE 1: per-batch row-sum into pool (atomic)
template <int MODE>
__global__ __launch_bounds__(256) void agg_kernel(const float* __restrict__ A2f,
                                                  const float* __restrict__ msg,
                                                  const float* __restrict__ deg,
                                                  float* __restrict__ h1,
                                                  float* __restrict__ pool, int poolOff) {
  __shared__ float Xs[16][68];
  __shared__ float Ws[16][68];
  int b = blockIdx.z;
  int n0 = blockIdx.y * 64;
  int o0 = blockIdx.x * 64;
  int tx = threadIdx.x, ty = threadIdx.y;
  int tid = ty * 16 + tx;
  const float* Ab = A2f + (size_t)b * N_ * LDA2_;
  const float* Mb = msg + (size_t)b * N_ * NH_;
  int lr = tid >> 2;
  int lk = (tid & 3) * 4;
  int wk = tid >> 4;        // 0..15 (k within tile)
  int wc = (tid & 15) * 4;  // 0..60 (col within tile)
  float acc[4][4] = {};
  for (int k0 = 0; k0 < LDA2_; k0 += 16) {
    float4 xv = make_float4(0.f, 0.f, 0.f, 0.f);
    if (n0 + lr < N_) xv = *(const float4*)&Ab[(size_t)(n0 + lr) * LDA2_ + k0 + lk];
    Xs[lk][lr] = xv.x; Xs[lk + 1][lr] = xv.y; Xs[lk + 2][lr] = xv.z; Xs[lk + 3][lr] = xv.w;
    float4 wv = make_float4(0.f, 0.f, 0.f, 0.f);
    int krow = k0 + wk;
    if (krow < N_) wv = *(const float4*)&Mb[(size_t)krow * NH_ + o0 + wc];
    *(float4*)&Ws[wk][wc] = wv;
    __syncthreads();
#pragma unroll
    for (int k = 0; k < 16; k++) {
      float4 a = *(const float4*)&Xs[k][ty * 4];
      float4 bb = *(const float4*)&Ws[k][tx * 4];
      float av[4] = {a.x, a.y, a.z, a.w};
      float bv[4] = {bb.x, bb.y, bb.z, bb.w};
#pragma unroll
      for (int i = 0; i < 4; i++)
#pragma unroll
        for (int j = 0; j < 4; j++) acc[i][j] = fmaf(av[i], bv[j], acc[i][j]);
    }
    __syncthreads();
  }
  if (MODE == 0) {
#pragma unroll
    for (int i = 0; i < 4; i++) {
      int n = n0 + ty * 4 + i;
      if (n >= N_) continue;
      float dinv = 1.f / deg[b * N_ + n];
#pragma unroll
      for (int j = 0; j < 4; j++) {
        int c = o0 + tx * 4 + j;
        h1[((size_t)b * N_ + n) * D2_ + NH_ + c] = fmaxf(acc[i][j] * dinv, 0.f);
      }
    }
  } else {
    float cs[4] = {0.f, 0.f, 0.f, 0.f};
#pragma unroll
    for (int i = 0; i < 4; i++) {
      int n = n0 + ty * 4 + i;
      if (n >= N_) continue;
      float dinv = 1.f / deg[b * N_ + n];
#pragma unroll
      for (int j = 0; j < 4; j++) cs[j] += fmaxf(acc[i][j] * dinv, 0.f);
    }
    __syncthreads();
#pragma unroll
    for (int j = 0; j < 4; j++) Xs[ty][tx * 4 + j] = cs[j];
    __syncthreads();
    if (ty == 0) {
#pragma unroll
      for (int j = 0; j < 4; j++) {
        float s = 0.f;
#pragma unroll
        for (int t = 0; t < 16; t++) s += Xs[t][tx * 4 + j];
        atomicAdd(&pool[(size_t)b * D4_ + poolOff + o0 + tx * 4 + j], s);
      }
    }
  }
}

// ---------------- pooling ----------------
__global__ void pool_h1_kernel(const float* __restrict__ h1, float* __restrict__ gf) {
  int b = blockIdx.y;
  int c = blockIdx.x * 256 + threadIdx.x;  // 0..1023
  const float* hp = h1 + (size_t)b * N_ * D2_ + c;
  float s = 0.f;
  for (int n = 0; n < N_; n++) s += hp[(size_t)n * D2_];
  gf[(size_t)b * D4_ + c] = s * (1.f / N_);
}

__global__ void pool_h2_kernel(const float* __restrict__ pool, float* __restrict__ gf) {
  int b = blockIdx.y;
  int c = D2_ + blockIdx.x * 256 + threadIdx.x;  // 1024..2047
  gf[(size_t)b * D4_ + c] = pool[(size_t)b * D4_ + c] * (1.f / N_);
}

// ---------------- host launch ----------------
extern "C" void kernel_launch(void* const* d_in, const int* in_sizes, int n_in,
                              void* d_out, int out_size, void* d_ws, size_t ws_size,
                              hipStream_t stream) {
  const float* Fet  = (const float*)d_in[0];
  const float* w1_0 = (const float*)d_in[1];
  const float* b1_0 = (const float*)d_in[2];
  const float* w2_0 = (const float*)d_in[3];
  const float* b2_0 = (const float*)d_in[4];
  const float* w1_1 = (const float*)d_in[5];
  const float* b1_1 = (const float*)d_in[6];
  const float* w2_1 = (const float*)d_in[7];
  const float* b2_1 = (const float*)d_in[8];
  const float* fc1_w = (const float*)d_in[9];
  const float* fc1_b = (const float*)d_in[10];
  const float* fc2_w = (const float*)d_in[11];
  const float* fc2_b = (const float*)d_in[12];

  char* ws = (char*)d_ws;
  float* A2f = (float*)(ws + OFF_A2F);
  float* dist = A2f;  // lifetime-disjoint overlay
  float* sq = (float*)(ws + OFF_SQ);
  unsigned long long* Abits = (unsigned long long*)(ws + OFF_ABITS);
  float* deg = (float*)(ws + OFF_DEG);
  float* msg = (float*)(ws + OFF_MSG);
  float* h1 = (float*)(ws + OFF_H1);
  float* pool = (float*)(ws + OFF_POOL);
  float* p = (float*)(ws + OFF_P);

  float* out = (float*)d_out;            // [B, NC]
  float* gf = out + (size_t)B_ * NC_;    // [B, D4] graph_features

  hipMemsetAsync(Abits, 0, (size_t)ROWS_ * 4 * sizeof(unsigned long long), stream);
  hipMemsetAsync(pool, 0, (size_t)B_ * D4_ * sizeof(float), stream);

  // graph construction
  sqnorm_kernel<<<ROWS_ / 4, 256, 0, stream>>>(Fet, sq);
  dist_kernel<<<dim3(7, 7, B_), dim3(16, 16), 0, stream>>>(Fet, sq, dist);
  topk_kernel<<<ROWS_ / 4, 256, 0, stream>>>(dist, Abits);
  a2_kernel<<<ROWS_ / 4, 256, 0, stream>>>(Abits, A2f, deg);

  // layer 1
  linear_kernel<0><<<dim3(8, 394), dim3(16, 16), 0, stream>>>(
      Fet, w2_0, b2_0, msg, NH_, 0, ROWS_, F_, NH_, nullptr, 0);            // msg1
  linear_kernel<1><<<dim3(8, 394), dim3(16, 16), 0, stream>>>(
      Fet, w1_0, b1_0, h1, D2_, 0, ROWS_, F_, NH_, nullptr, 0);             // ego1 -> h1[:, :512]
  agg_kernel<0><<<dim3(8, 4, B_), dim3(16, 16), 0, stream>>>(
      A2f, msg, deg, h1, nullptr, 0);                                       // agg1 -> h1[:, 512:]

  // layer 2 (h2 fused into pool)
  linear_kernel<0><<<dim3(8, 394), dim3(16, 16), 0, stream>>>(
      h1, w2_1, b2_1, msg, NH_, 0, ROWS_, D2_, NH_, nullptr, 0);            // msg2
  linear_kernel<2><<<dim3(8, 4, B_), dim3(16, 16), 0, stream>>>(
      h1, w1_1, b1_1, nullptr, 0, 0, N_, D2_, NH_, pool, D2_);              // ego2 -> pool[1024:1536]
  agg_kernel<1><<<dim3(8, 4, B_), dim3(16, 16), 0, stream>>>(
      A2f, msg, deg, nullptr, pool, D2_ + NH_);                             // agg2 -> pool[1536:2048]

  // pooling -> graph_features (second output)
  pool_h1_kernel<<<dim3(4, B_), 256, 0, stream>>>(h1, gf);
  pool_h2_kernel<<<dim3(4, B_), 256, 0, stream>>>(pool, gf);

  // head
  linear_kernel<1><<<dim3(8, 2), dim3(16, 16), 0, stream>>>(
      gf, fc1_w, fc1_b, p, NH_, 0, B_, D4_, NH_, nullptr, 0);               // fc1 + relu
  linear_kernel<0><<<dim3(16, 2), dim3(16, 16), 0, stream>>>(
      p, fc2_w, fc2_b, out, NC_, 0, B_, NH_, NC_, nullptr, 0);              // fc2 -> out
}

// Round 2
// 915.641 us; speedup vs baseline: 2.3599x; 2.3599x over previous
//
#include <hip/hip_runtime.h>
#include <hip/hip_bf16.h>
#include <math.h>

typedef __attribute__((ext_vector_type(8))) short bf16x8;
typedef __attribute__((ext_vector_type(4))) float f32x4;

#define B_ 128
#define N_ 197
#define F_ 768
#define NH_ 512
#define D2_ 1024
#define D4_ 2048
#define NC_ 1000
#define ROWS_ (B_ * N_)   // 25216 = 197 * 128 (exact 128-row tiling!)
#define KA_ 224           // agg K padded (197 -> 224 = 7*32)
#define NA_ 256           // agg node rows padded (197 -> 256 = 2*128)

// workspace offsets (bytes). dist (f32, 19.87MB) and A2bf (bf16, 14.68MB) overlay:
// dist is dead after topk_kernel; A2bf garbage rows (n>=197) are only read into
// discarded output rows and are finite (old dist bytes / 0xAA poison).
#define OFF_DIST   0ull
#define OFF_SQ     19871232ull
#define OFF_ABITS  19972352ull
#define OFF_DEG    20779520ull
#define OFF_FETBF  20880640ull   // [25216][768] bf16
#define OFF_MSG    59612672ull   // [25248][512] bf16 (32 slack rows for agg B over-read)
#define OFF_H1     85466880ull   // [25280][1024] bf16 (64 slack rows for ego2 A over-read)
#define OFF_POOL   137240576ull  // [128][2048] f32
#define OFF_P      138289408ull  // [128][512] f32
#define OFF_W10    138551808ull  // w1_0 bf16 [512][768]
#define OFF_W20    139338240ull
#define OFF_W11    140124672ull  // w1_1 bf16 [512][1024]
#define OFF_W21    141173248ull  // end 142,221,824

__device__ __forceinline__ void gll16(const void* g, void* l) {
  __builtin_amdgcn_global_load_lds((const __attribute__((address_space(1))) void*)g,
                                   (__attribute__((address_space(3))) void*)l, 16, 0, 0);
}

// ---------------- f32 -> bf16 cast ----------------
__global__ __launch_bounds__(256) void cast_bf16_kernel(const float* __restrict__ src,
                                                        __hip_bfloat16* __restrict__ dst,
                                                        int n4) {
  int i = blockIdx.x * 256 + threadIdx.x;
  if (i >= n4) return;
  float4 v = ((const float4*)src)[i];
  union { __hip_bfloat16 h[4]; uint2 u; } pk;
  pk.h[0] = __float2bfloat16(v.x);
  pk.h[1] = __float2bfloat16(v.y);
  pk.h[2] = __float2bfloat16(v.z);
  pk.h[3] = __float2bfloat16(v.w);
  ((uint2*)dst)[i] = pk.u;
}

// ---------------- squared norms ----------------
__global__ __launch_bounds__(256) void sqnorm_kernel(const float* __restrict__ X,
                                                     float* __restrict__ sq) {
  int row = blockIdx.x * 4 + (threadIdx.x >> 6);
  int lane = threadIdx.x & 63;
  const float4* xp = (const float4*)(X + (size_t)row * F_);
  float s = 0.f;
#pragma unroll
  for (int i = 0; i < 3; i++) {
    float4 v = xp[lane + i * 64];
    s += v.x * v.x + v.y * v.y + v.z * v.z + v.w * v.w;
  }
#pragma unroll
  for (int o = 32; o > 0; o >>= 1) s += __shfl_down(s, o);
  if (lane == 0) sq[row] = s;
}

// ---------------- pairwise distances (f32 — keep kNN selection bit-identical) ----------------
__global__ __launch_bounds__(256) void dist_kernel(const float* __restrict__ X,
                                                   const float* __restrict__ sq,
                                                   float* __restrict__ dist) {
  __shared__ float As[32][33];
  __shared__ float Bs[32][33];
  int b = blockIdx.z;
  int n0 = blockIdx.y * 32, m0 = blockIdx.x * 32;
  int tx = threadIdx.x, ty = threadIdx.y;
  int tid = ty * 16 + tx;
  const float* Xb = X + (size_t)b * N_ * F_;
  float acc00 = 0.f, acc01 = 0.f, acc10 = 0.f, acc11 = 0.f;
  for (int k0 = 0; k0 < F_; k0 += 32) {
#pragma unroll
    for (int i = 0; i < 4; i++) {
      int e = tid + i * 256;
      int r = e >> 5, k = e & 31;
      As[k][r] = (n0 + r < N_) ? Xb[(size_t)(n0 + r) * F_ + k0 + k] : 0.f;
      Bs[k][r] = (m0 + r < N_) ? Xb[(size_t)(m0 + r) * F_ + k0 + k] : 0.f;
    }
    __syncthreads();
#pragma unroll
    for (int k = 0; k < 32; k++) {
      float a0 = As[k][ty], a1 = As[k][ty + 16];
      float b0 = Bs[k][tx], b1 = Bs[k][tx + 16];
      acc00 = fmaf(a0, b0, acc00);
      acc01 = fmaf(a0, b1, acc01);
      acc10 = fmaf(a1, b0, acc10);
      acc11 = fmaf(a1, b1, acc11);
    }
    __syncthreads();
  }
  float accs[2][2] = {{acc00, acc01}, {acc10, acc11}};
  int n_base = b * N_;
#pragma unroll
  for (int i = 0; i < 2; i++) {
    int n = n0 + ty + i * 16;
    if (n >= N_) continue;
    float sn = sq[n_base + n];
#pragma unroll
    for (int j = 0; j < 2; j++) {
      int m = m0 + tx + j * 16;
      if (m >= N_) continue;
      float d = sn + sq[n_base + m] - 2.f * accs[i][j];
      if (n == m) d = INFINITY;
      dist[((size_t)n_base + n) * N_ + m] = d;
    }
  }
}

// ---------------- top-4 per row -> symmetric adjacency bitmask ----------------
__global__ __launch_bounds__(256) void topk_kernel(const float* __restrict__ dist,
                                                   unsigned long long* __restrict__ Abits) {
  int row = blockIdx.x * 4 + (threadIdx.x >> 6);
  int lane = threadIdx.x & 63;
  int b = row / N_, n = row - b * N_;
  const float* dr = dist + (size_t)row * N_;
  float v[4];
  int vi[4];
#pragma unroll
  for (int i = 0; i < 4; i++) {
    int m = lane + i * 64;
    bool ok = (m < N_);
    v[i] = ok ? dr[m] : INFINITY;
    vi[i] = ok ? m : 0x3fffffff;
  }
  unsigned long long nbr[4] = {0ull, 0ull, 0ull, 0ull};
#pragma unroll
  for (int t = 0; t < 4; t++) {
    float bv = v[0];
    int bi = vi[0];
#pragma unroll
    for (int i = 1; i < 4; i++)
      if (v[i] < bv || (v[i] == bv && vi[i] < bi)) { bv = v[i]; bi = vi[i]; }
#pragma unroll
    for (int o = 1; o < 64; o <<= 1) {
      float ov = __shfl_xor(bv, o);
      int oi = __shfl_xor(bi, o);
      if (ov < bv || (ov == bv && oi < bi)) { bv = ov; bi = oi; }
    }
#pragma unroll
    for (int i = 0; i < 4; i++)
      if (vi[i] == bi) { v[i] = INFINITY; vi[i] = 0x3fffffff; }
    if (lane == 0) {
      nbr[bi >> 6] |= 1ull << (bi & 63);
      atomicOr(&Abits[((size_t)b * N_ + bi) * 4 + (n >> 6)], 1ull << (n & 63));
    }
  }
  if (lane == 0) {
#pragma unroll
    for (int w = 0; w < 4; w++)
      if (nbr[w]) atomicOr(&Abits[(size_t)row * 4 + w], nbr[w]);
  }
}

// ---------------- 2-hop adjacency -> bf16 [B][256][224] + deg ----------------
__global__ __launch_bounds__(256) void a2_kernel(const unsigned long long* __restrict__ Abits,
                                                 __hip_bfloat16* __restrict__ A2bf,
                                                 float* __restrict__ deg) {
  int row = blockIdx.x * 4 + (threadIdx.x >> 6);
  int lane = threadIdx.x & 63;
  int b = row / N_, n = row - b * N_;
  const unsigned long long* arow = Abits + (size_t)row * 4;
  const unsigned long long* base = Abits + (size_t)b * N_ * 4;
  unsigned long long r0 = 0, r1 = 0, r2 = 0, r3 = 0;
#pragma unroll
  for (int w = 0; w < 4; w++) {
    if ((arow[w] >> lane) & 1ull) {
      const unsigned long long* mr = base + (size_t)(w * 64 + lane) * 4;
      r0 |= mr[0]; r1 |= mr[1]; r2 |= mr[2]; r3 |= mr[3];
    }
  }
#pragma unroll
  for (int o = 1; o < 64; o <<= 1) {
    r0 |= __shfl_xor(r0, o);
    r1 |= __shfl_xor(r1, o);
    r2 |= __shfl_xor(r2, o);
    r3 |= __shfl_xor(r3, o);
  }
  unsigned long long rr[4] = {r0, r1, r2, r3};
  rr[n >> 6] &= ~(1ull << (n & 63));
  __hip_bfloat16* out = A2bf + ((size_t)b * NA_ + n) * KA_;
  const __hip_bfloat16 one = __float2bfloat16(1.f);
  const __hip_bfloat16 zer = __float2bfloat16(0.f);
#pragma unroll
  for (int i = 0; i < 4; i++) {
    int m = lane + i * 64;
    if (m < KA_)
      out[m] = (m < N_ && ((rr[m >> 6] >> (m & 63)) & 1ull)) ? one : zer;
  }
  if (lane == 0) {
    int dg = __popcll(rr[0]) + __popcll(rr[1]) + __popcll(rr[2]) + __popcll(rr[3]);
    deg[row] = (float)(dg > 0 ? dg : 1);
  }
}

// ---------------- MFMA GEMM: Y = opt_relu(X @ W^T + bias), bf16 in/out, f32 acc ----
// Dense: Rows % 128 == 0, K % 32 == 0, O % 128 == 0. Tile 128x128xBK32, 4 waves.
// LDS swizzle: logical (row, slot) at phys byte row*64 + (slot^(row&3))*16; staged
// via global_load_lds with inverse-swizzled global source (linear LDS dest).
template <bool RELU>
__global__ __launch_bounds__(256) void mfma_linear(const __hip_bfloat16* __restrict__ X,
                                                   const __hip_bfloat16* __restrict__ W,
                                                   const float* __restrict__ bias,
                                                   __hip_bfloat16* __restrict__ Y,
                                                   int K, int ldy, int colOff) {
  __shared__ short As[4096];
  __shared__ short Bs[4096];
  const int t = threadIdx.x;
  const int m0 = blockIdx.y * 128, o0 = blockIdx.x * 128;
  const int l = t & 63, w = t >> 6;
  const int wm = (w >> 1) * 64, wn = (w & 1) * 64;
  const int frow = l & 15, fch = l >> 4;
  const int srow = t >> 2, sslot = t & 3;
  const char* Abase = (const char*)(X + (size_t)m0 * K);
  const char* Bbase = (const char*)(W + (size_t)o0 * K);
  const int rb = K * 2;
  char* AsB = (char*)As;
  char* BsB = (char*)Bs;
  f32x4 zero = {0.f, 0.f, 0.f, 0.f};
  f32x4 acc[4][4];
#pragma unroll
  for (int i = 0; i < 4; i++)
#pragma unroll
    for (int j = 0; j < 4; j++) acc[i][j] = zero;
  const int KT = K >> 5;
  for (int kt = 0; kt < KT; kt++) {
    const int kb = kt * 64;
#pragma unroll
    for (int u = 0; u < 2; u++) {
      int grow = u * 64 + srow;
      int gslot = sslot ^ (grow & 3);
      gll16(Abase + (size_t)grow * rb + kb + gslot * 16, AsB + u * 4096 + t * 16);
      gll16(Bbase + (size_t)grow * rb + kb + gslot * 16, BsB + u * 4096 + t * 16);
    }
    __syncthreads();
    bf16x8 af[4], bfv[4];
#pragma unroll
    for (int i = 0; i < 4; i++) {
      int ar = wm + i * 16 + frow;
      af[i] = *(const bf16x8*)(AsB + ar * 64 + ((fch ^ (ar & 3)) * 16));
      int br = wn + i * 16 + frow;
      bfv[i] = *(const bf16x8*)(BsB + br * 64 + ((fch ^ (br & 3)) * 16));
    }
#pragma unroll
    for (int i = 0; i < 4; i++)
#pragma unroll
      for (int j = 0; j < 4; j++)
        acc[i][j] = __builtin_amdgcn_mfma_f32_16x16x32_bf16(af[i], bfv[j], acc[i][j], 0, 0, 0);
    __syncthreads();
  }
  // D layout: col = lane&15, row = (lane>>4)*4 + reg  [m89-verified]
#pragma unroll
  for (int j = 0; j < 4; j++) {
    int c = o0 + wn + j * 16 + frow;
    float bv = bias[c];
#pragma unroll
    for (int i = 0; i < 4; i++) {
      int r0 = m0 + wm + i * 16 + fch * 4;
#pragma unroll
      for (int r = 0; r < 4; r++) {
        float v = acc[i][j][r] + bv;
        if (RELU) v = fmaxf(v, 0.f);
        Y[(size_t)(r0 + r) * ldy + colOff + c] = __float2bfloat16(v);
      }
    }
  }
}

// ---------------- MFMA ego2 with fused pooling (per-batch, rows padded to 256) ----
__global__ __launch_bounds__(256) void mfma_ego_pool(const __hip_bfloat16* __restrict__ h1,
                                                     const __hip_bfloat16* __restrict__ W,
                                                     const float* __restrict__ bias,
                                                     float* __restrict__ pool, int poolOff) {
  __shared__ short As[4096];
  __shared__ short Bs[4096];
  const int t = threadIdx.x;
  const int b = blockIdx.z;
  const int m0 = blockIdx.y * 128, o0 = blockIdx.x * 128;
  const int l = t & 63, w = t >> 6;
  const int wm = (w >> 1) * 64, wn = (w & 1) * 64;
  const int frow = l & 15, fch = l >> 4;
  const int srow = t >> 2, sslot = t & 3;
  const char* Abase = (const char*)(h1 + ((size_t)b * N_ + m0) * D2_);
  const char* Bbase = (const char*)(W + (size_t)o0 * D2_);
  char* AsB = (char*)As;
  char* BsB = (char*)Bs;
  f32x4 zero = {0.f, 0.f, 0.f, 0.f};
  f32x4 acc[4][4];
#pragma unroll
  for (int i = 0; i < 4; i++)
#pragma unroll
    for (int j = 0; j < 4; j++) acc[i][j] = zero;
  for (int kt = 0; kt < 32; kt++) {
    const int kb = kt * 64;
#pragma unroll
    for (int u = 0; u < 2; u++) {
      int grow = u * 64 + srow;
      int gslot = sslot ^ (grow & 3);
      gll16(Abase + (size_t)grow * (D2_ * 2) + kb + gslot * 16, AsB + u * 4096 + t * 16);
      gll16(Bbase + (size_t)grow * (D2_ * 2) + kb + gslot * 16, BsB + u * 4096 + t * 16);
    }
    __syncthreads();
    bf16x8 af[4], bfv[4];
#pragma unroll
    for (int i = 0; i < 4; i++) {
      int ar = wm + i * 16 + frow;
      af[i] = *(const bf16x8*)(AsB + ar * 64 + ((fch ^ (ar & 3)) * 16));
      int br = wn + i * 16 + frow;
      bfv[i] = *(const bf16x8*)(BsB + br * 64 + ((fch ^ (br & 3)) * 16));
    }
#pragma unroll
    for (int i = 0; i < 4; i++)
#pragma unroll
      for (int j = 0; j < 4; j++)
        acc[i][j] = __builtin_amdgcn_mfma_f32_16x16x32_bf16(af[i], bfv[j], acc[i][j], 0, 0, 0);
    __syncthreads();
  }
#pragma unroll
  for (int j = 0; j < 4; j++) {
    int c = o0 + wn + j * 16 + frow;
    float bv = bias[c];
    float s = 0.f;
#pragma unroll
    for (int i = 0; i < 4; i++) {
#pragma unroll
      for (int r = 0; r < 4; r++) {
        int n = m0 + wm + i * 16 + fch * 4 + r;
        if (n < N_) s += fmaxf(acc[i][j][r] + bv, 0.f);
      }
    }
    s += __shfl_down(s, 32);
    s += __shfl_down(s, 16);
    if (l < 16) atomicAdd(&pool[(size_t)b * D4_ + poolOff + c], s);
  }
}

// ---------------- MFMA aggregation: A2 @ msg (per batch) ----------------
// A from A2bf [256][224] via global_load_lds; B (msg, [node][feat]) reg-transposed
// into LDS [feat][k] layout. MODE 0: h1[:,512:]; MODE 1: fused pool.
template <int MODE>
__global__ __launch_bounds__(256) void mfma_agg(const __hip_bfloat16* __restrict__ A2bf,
                                                const __hip_bfloat16* __restrict__ msg,
                                                const float* __restrict__ deg,
                                                __hip_bfloat16* __restrict__ H,
                                                float* __restrict__ pool, int poolOff) {
  __shared__ short As[4096];
  __shared__ short Bs[4096];
  const int t = threadIdx.x;
  const int b = blockIdx.z;
  const int m0 = blockIdx.y * 128, o0 = blockIdx.x * 128;
  const int l = t & 63, w = t >> 6;
  const int wm = (w >> 1) * 64, wn = (w & 1) * 64;
  const int frow = l & 15, fch = l >> 4;
  const int srow = t >> 2, sslot = t & 3;
  const char* Abase = (const char*)(A2bf + ((size_t)b * NA_ + m0) * KA_);
  const __hip_bfloat16* Mb = msg + (size_t)b * N_ * NH_;
  const int bk = t >> 3;        // 0..31 (k within tile)
  const int bf0 = (t & 7) * 16; // feat base within tile
  char* AsB = (char*)As;
  char* BsB = (char*)Bs;
  f32x4 zero = {0.f, 0.f, 0.f, 0.f};
  f32x4 acc[4][4];
#pragma unroll
  for (int i = 0; i < 4; i++)
#pragma unroll
    for (int j = 0; j < 4; j++) acc[i][j] = zero;
  for (int kt = 0; kt < 7; kt++) {
#pragma unroll
    for (int u = 0; u < 2; u++) {
      int grow = u * 64 + srow;
      int gslot = sslot ^ (grow & 3);
      gll16(Abase + (size_t)grow * (KA_ * 2) + kt * 64 + gslot * 16, AsB + u * 4096 + t * 16);
    }
    int krow = kt * 32 + bk;  // up to 223: reads msg slack rows (x0 in A) — OK
    const __hip_bfloat16* mp = Mb + (size_t)krow * NH_ + o0 + bf0;
    bf16x8 v0 = *(const bf16x8*)mp;
    bf16x8 v1 = *(const bf16x8*)(mp + 8);
#pragma unroll
    for (int e = 0; e < 8; e++) {
      int f0a = bf0 + e;
      int f1a = bf0 + 8 + e;
      *(short*)(BsB + f0a * 64 + (((bk >> 3) ^ (f0a & 3)) * 16) + (bk & 7) * 2) = v0[e];
      *(short*)(BsB + f1a * 64 + (((bk >> 3) ^ (f1a & 3)) * 16) + (bk & 7) * 2) = v1[e];
    }
    __syncthreads();
    bf16x8 af[4], bfv[4];
#pragma unroll
    for (int i = 0; i < 4; i++) {
      int ar = wm + i * 16 + frow;
      af[i] = *(const bf16x8*)(AsB + ar * 64 + ((fch ^ (ar & 3)) * 16));
      int br = wn + i * 16 + frow;
      bfv[i] = *(const bf16x8*)(BsB + br * 64 + ((fch ^ (br & 3)) * 16));
    }
#pragma unroll
    for (int i = 0; i < 4; i++)
#pragma unroll
      for (int j = 0; j < 4; j++)
        acc[i][j] = __builtin_amdgcn_mfma_f32_16x16x32_bf16(af[i], bfv[j], acc[i][j], 0, 0, 0);
    __syncthreads();
  }
  if (MODE == 0) {
#pragma unroll
    for (int j = 0; j < 4; j++) {
      int c = o0 + wn + j * 16 + frow;
#pragma unroll
      for (int i = 0; i < 4; i++) {
#pragma unroll
        for (int r = 0; r < 4; r++) {
          int n = m0 + wm + i * 16 + fch * 4 + r;
          if (n < N_) {
            float dv = deg[b * N_ + n];
            float v = fmaxf(acc[i][j][r] / dv, 0.f);
            H[((size_t)b * N_ + n) * D2_ + NH_ + c] = __float2bfloat16(v);
          }
        }
      }
    }
  } else {
#pragma unroll
    for (int j = 0; j < 4; j++) {
      int c = o0 + wn + j * 16 + frow;
      float s = 0.f;
#pragma unroll
      for (int i = 0; i < 4; i++) {
#pragma unroll
        for (int r = 0; r < 4; r++) {
          int n = m0 + wm + i * 16 + fch * 4 + r;
          if (n < N_) {
            float dv = deg[b * N_ + n];
            s += fmaxf(acc[i][j][r] / dv, 0.f);
          }
        }
      }
      s += __shfl_down(s, 32);
      s += __shfl_down(s, 16);
      if (l < 16) atomicAdd(&pool[(size_t)b * D4_ + poolOff + c], s);
    }
  }
}

// ---------------- pooling: gf[:, :1024] = mean h1; gf[:, 1024:] = pool/N ----------------
__global__ __launch_bounds__(256) void pool_kernel(const __hip_bfloat16* __restrict__ h1,
                                                   const float* __restrict__ pool,
                                                   float* __restrict__ gf) {
  int b = blockIdx.y;
  int c = blockIdx.x * 256 + threadIdx.x;
  if (c < D2_) {
    const __hip_bfloat16* p = h1 + (size_t)b * N_ * D2_ + c;
    float s = 0.f;
    for (int n = 0; n < N_; n++) s += __bfloat162float(p[(size_t)n * D2_]);
    gf[(size_t)b * D4_ + c] = s * (1.f / N_);
  } else {
    gf[(size_t)b * D4_ + c] = pool[(size_t)b * D4_ + c] * (1.f / N_);
  }
}

// ---------------- f32 linear for the small head ----------------
template <int MODE>
__global__ __launch_bounds__(256) void linear_kernel(const float* __restrict__ Xg,
                                                     const float* __restrict__ W,
                                                     const float* __restrict__ bias,
                                                     float* __restrict__ Y, int ldy, int colOff,
                                                     int Rows, int Fin, int O,
                                                     float* __restrict__ pool, int poolOff) {
  __shared__ float Xs[16][68];
  __shared__ float Ws[16][68];
  int tx = threadIdx.x, ty = threadIdx.y;
  int tid = ty * 16 + tx;
  int lr = tid >> 2;
  int lk = (tid & 3) * 4;
  int rbase = blockIdx.y * 64;
  int o0 = blockIdx.x * 64;
  const float* X = Xg;
  float acc[4][4] = {};
  for (int k0 = 0; k0 < Fin; k0 += 16) {
    float4 xv = make_float4(0.f, 0.f, 0.f, 0.f);
    if (rbase + lr < Rows) xv = *(const float4*)&X[(size_t)(rbase + lr) * Fin + k0 + lk];
    Xs[lk][lr] = xv.x; Xs[lk + 1][lr] = xv.y; Xs[lk + 2][lr] = xv.z; Xs[lk + 3][lr] = xv.w;
    float4 wv = make_float4(0.f, 0.f, 0.f, 0.f);
    if (o0 + lr < O) wv = *(const float4*)&W[(size_t)(o0 + lr) * Fin + k0 + lk];
    Ws[lk][lr] = wv.x; Ws[lk + 1][lr] = wv.y; Ws[lk + 2][lr] = wv.z; Ws[lk + 3][lr] = wv.w;
    __syncthreads();
#pragma unroll
    for (int k = 0; k < 16; k++) {
      float4 a = *(const float4*)&Xs[k][ty * 4];
      float4 bb = *(const float4*)&Ws[k][tx * 4];
      float av[4] = {a.x, a.y, a.z, a.w};
      float bv[4] = {bb.x, bb.y, bb.z, bb.w};
#pragma unroll
      for (int i = 0; i < 4; i++)
#pragma unroll
        for (int j = 0; j < 4; j++) acc[i][j] = fmaf(av[i], bv[j], acc[i][j]);
    }
    __syncthreads();
  }
#pragma unroll
  for (int i = 0; i < 4; i++) {
    int rrow = rbase + ty * 4 + i;
    if (rrow >= Rows) continue;
#pragma unroll
    for (int j = 0; j < 4; j++) {
      int c = o0 + tx * 4 + j;
      if (c >= O) continue;
      float vv = acc[i][j] + bias[c];
      if (MODE == 1) vv = fmaxf(vv, 0.f);
      Y[(size_t)rrow * ldy + colOff + c] = vv;
    }
  }
}

// ---------------- host launch ----------------
extern "C" void kernel_launch(void* const* d_in, const int* in_sizes, int n_in,
                              void* d_out, int out_size, void* d_ws, size_t ws_size,
                              hipStream_t stream) {
  const float* Fet  = (const float*)d_in[0];
  const float* w1_0 = (const float*)d_in[1];
  const float* b1_0 = (const float*)d_in[2];
  const float* w2_0 = (const float*)d_in[3];
  const float* b2_0 = (const float*)d_in[4];
  const float* w1_1 = (const float*)d_in[5];
  const float* b1_1 = (const float*)d_in[6];
  const float* w2_1 = (const float*)d_in[7];
  const float* b2_1 = (const float*)d_in[8];
  const float* fc1_w = (const float*)d_in[9];
  const float* fc1_b = (const float*)d_in[10];
  const float* fc2_w = (const float*)d_in[11];
  const float* fc2_b = (const float*)d_in[12];

  char* ws = (char*)d_ws;
  float* dist = (float*)(ws + OFF_DIST);
  __hip_bfloat16* A2bf = (__hip_bfloat16*)(ws + OFF_DIST);  // overlay (dist dead after topk)
  float* sq = (float*)(ws + OFF_SQ);
  unsigned long long* Abits = (unsigned long long*)(ws + OFF_ABITS);
  float* deg = (float*)(ws + OFF_DEG);
  __hip_bfloat16* Fet_bf = (__hip_bfloat16*)(ws + OFF_FETBF);
  __hip_bfloat16* msg = (__hip_bfloat16*)(ws + OFF_MSG);
  __hip_bfloat16* h1 = (__hip_bfloat16*)(ws + OFF_H1);
  float* pool = (float*)(ws + OFF_POOL);
  float* p = (float*)(ws + OFF_P);
  __hip_bfloat16* w10b = (__hip_bfloat16*)(ws + OFF_W10);
  __hip_bfloat16* w20b = (__hip_bfloat16*)(ws + OFF_W20);
  __hip_bfloat16* w11b = (__hip_bfloat16*)(ws + OFF_W11);
  __hip_bfloat16* w21b = (__hip_bfloat16*)(ws + OFF_W21);

  float* out = (float*)d_out;          // [B, NC]
  float* gf = out + (size_t)B_ * NC_;  // [B, D4]

  hipMemsetAsync(Abits, 0, (size_t)ROWS_ * 4 * sizeof(unsigned long long), stream);
  hipMemsetAsync(pool, 0, (size_t)B_ * D4_ * sizeof(float), stream);

  // casts
  cast_bf16_kernel<<<(ROWS_ * F_ / 4 + 255) / 256, 256, 0, stream>>>(Fet, Fet_bf, ROWS_ * F_ / 4);
  cast_bf16_kernel<<<384, 256, 0, stream>>>(w1_0, w10b, NH_ * F_ / 4);
  cast_bf16_kernel<<<384, 256, 0, stream>>>(w2_0, w20b, NH_ * F_ / 4);
  cast_bf16_kernel<<<512, 256, 0, stream>>>(w1_1, w11b, NH_ * D2_ / 4);
  cast_bf16_kernel<<<512, 256, 0, stream>>>(w2_1, w21b, NH_ * D2_ / 4);

  // graph construction (f32 — selection exactness)
  sqnorm_kernel<<<ROWS_ / 4, 256, 0, stream>>>(Fet, sq);
  dist_kernel<<<dim3(7, 7, B_), dim3(16, 16), 0, stream>>>(Fet, sq, dist);
  topk_kernel<<<ROWS_ / 4, 256, 0, stream>>>(dist, Abits);
  a2_kernel<<<ROWS_ / 4, 256, 0, stream>>>(Abits, A2bf, deg);

  // layer 1
  mfma_linear<false><<<dim3(4, 197), 256, 0, stream>>>(Fet_bf, w20b, b2_0, msg, F_, NH_, 0);
  mfma_linear<true><<<dim3(4, 197), 256, 0, stream>>>(Fet_bf, w10b, b1_0, h1, F_, D2_, 0);
  mfma_agg<0><<<dim3(4, 2, B_), 256, 0, stream>>>(A2bf, msg, deg, h1, nullptr, 0);

  // layer 2 (h2 fused into pool)
  mfma_linear<false><<<dim3(4, 197), 256, 0, stream>>>(h1, w21b, b2_1, msg, D2_, NH_, 0);
  mfma_ego_pool<<<dim3(4, 2, B_), 256, 0, stream>>>(h1, w11b, b1_1, pool, D2_);
  mfma_agg<1><<<dim3(4, 2, B_), 256, 0, stream>>>(A2bf, msg, deg, nullptr, pool, D2_ + NH_);

  // pooling -> graph_features
  pool_kernel<<<dim3(8, B_), 256, 0, stream>>>(h1, pool, gf);

  // head (f32, small)
  linear_kernel<1><<<dim3(8, 2), dim3(16, 16), 0, stream>>>(
      gf, fc1_w, fc1_b, p, NH_, 0, B_, D4_, NH_, nullptr, 0);
  linear_kernel<0><<<dim3(16, 2), dim3(16, 16), 0, stream>>>(
      p, fc2_w, fc2_b, out, NC_, 0, B_, NH_, NC_, nullptr, 0);
}

// Round 3
// 634.541 us; speedup vs baseline: 3.4053x; 1.4430x over previous
//
#include <hip/hip_runtime.h>
#include <hip/hip_bf16.h>
#include <math.h>

typedef __attribute__((ext_vector_type(8))) short bf16x8;
typedef __attribute__((ext_vector_type(4))) float f32x4;

#define B_ 128
#define N_ 197
#define F_ 768
#define NH_ 512
#define D2_ 1024
#define D4_ 2048
#define NC_ 1000
#define ROWS_ (B_ * N_)   // 25216 = 197 * 128 (exact 128-row tiling!)
#define KA_ 224           // agg K padded (197 -> 224 = 7*32)
#define NA_ 256           // agg node rows padded (197 -> 256 = 2*128)

// workspace offsets (bytes).
// dist (f32, 19.87MB) overlays A2bf (bf16, 14.68MB): dist dead after topk.
// Fet_lo (38.8MB) overlays msg+h1 head: lo dead after mfma_gram, msg/h1 written after.
#define OFF_DIST   0ull
#define OFF_SQ     19871232ull
#define OFF_ABITS  19972352ull
#define OFF_DEG    20779520ull
#define OFF_FETHI  20880640ull   // [25280][768] bf16 (64 slack rows for gram over-read)
#define OFF_MSG    59710720ull   // [25248][512] bf16 (32 slack rows for agg B over-read)
#define OFF_H1     85564672ull   // [25280][1024] bf16 (64 slack rows for ego2 A over-read)
#define OFF_FETLO  OFF_MSG       // overlay: [25280][768] bf16, ends 98,540,800
#define OFF_POOL   137338112ull  // [128][2048] f32
#define OFF_P      138386688ull  // [128][512] f32
#define OFF_W10    138648832ull
#define OFF_W20    139435264ull
#define OFF_W11    140221696ull
#define OFF_W21    141270272ull  // end 142,318,848

__device__ __forceinline__ void gll16(const void* g, void* l) {
  __builtin_amdgcn_global_load_lds((const __attribute__((address_space(1))) void*)g,
                                   (__attribute__((address_space(3))) void*)l, 16, 0, 0);
}

// ---------------- f32 -> bf16 cast (weights) ----------------
__global__ __launch_bounds__(256) void cast_bf16_kernel(const float* __restrict__ src,
                                                        __hip_bfloat16* __restrict__ dst,
                                                        int n4) {
  int i = blockIdx.x * 256 + threadIdx.x;
  if (i >= n4) return;
  float4 v = ((const float4*)src)[i];
  union { __hip_bfloat16 h[4]; uint2 u; } pk;
  pk.h[0] = __float2bfloat16(v.x);
  pk.h[1] = __float2bfloat16(v.y);
  pk.h[2] = __float2bfloat16(v.z);
  pk.h[3] = __float2bfloat16(v.w);
  ((uint2*)dst)[i] = pk.u;
}

// ---------------- f32 -> bf16 hi/lo split (features) ----------------
__global__ __launch_bounds__(256) void cast_hilo_kernel(const float* __restrict__ src,
                                                        __hip_bfloat16* __restrict__ hi,
                                                        __hip_bfloat16* __restrict__ lo,
                                                        int n4) {
  int i = blockIdx.x * 256 + threadIdx.x;
  if (i >= n4) return;
  float4 v = ((const float4*)src)[i];
  float f[4] = {v.x, v.y, v.z, v.w};
  union { __hip_bfloat16 h[4]; uint2 u; } ph, pl;
#pragma unroll
  for (int k = 0; k < 4; k++) {
    __hip_bfloat16 h = __float2bfloat16(f[k]);
    ph.h[k] = h;
    pl.h[k] = __float2bfloat16(f[k] - __bfloat162float(h));
  }
  ((uint2*)hi)[i] = ph.u;
  ((uint2*)lo)[i] = pl.u;
}

// ---------------- squared norms (f32 input) ----------------
__global__ __launch_bounds__(256) void sqnorm_kernel(const float* __restrict__ X,
                                                     float* __restrict__ sq) {
  int row = blockIdx.x * 4 + (threadIdx.x >> 6);
  int lane = threadIdx.x & 63;
  const float4* xp = (const float4*)(X + (size_t)row * F_);
  float s = 0.f;
#pragma unroll
  for (int i = 0; i < 3; i++) {
    float4 v = xp[lane + i * 64];
    s += v.x * v.x + v.y * v.y + v.z * v.z + v.w * v.w;
  }
#pragma unroll
  for (int o = 32; o > 0; o >>= 1) s += __shfl_down(s, o);
  if (lane == 0) sq[row] = s;
}

// ---------------- pairwise Gram via MFMA, split-bf16 3-pass ----------------
// dist = sq_n + sq_m - 2*(hi.hi + hi.lo + lo.hi); error ~2^-16 relative (kNN-safe).
// 3 blocks/batch: (m0,o0) in {(0,0),(128,0 mirrored),(128,128)}.
__global__ __launch_bounds__(256) void mfma_gram(const __hip_bfloat16* __restrict__ Xhi,
                                                 const __hip_bfloat16* __restrict__ Xlo,
                                                 const float* __restrict__ sq,
                                                 float* __restrict__ dist) {
  __shared__ short AsH[4096];
  __shared__ short BsH[4096];
  __shared__ short AsL[4096];
  __shared__ short BsL[4096];
  const int t = threadIdx.x;
  const int b = blockIdx.z;
  const int bx = blockIdx.x;
  const int m0 = (bx == 0) ? 0 : 128;
  const int o0 = (bx == 2) ? 128 : 0;
  const bool mirror = (bx == 1);
  const int l = t & 63, w = t >> 6;
  const int wm = (w >> 1) * 64, wn = (w & 1) * 64;
  const int frow = l & 15, fch = l >> 4;
  const int srow = t >> 2, sslot = t & 3;
  const size_t rowbase = (size_t)b * N_;
  const char* AhiB = (const char*)(Xhi + (rowbase + m0) * F_);
  const char* AloB = (const char*)(Xlo + (rowbase + m0) * F_);
  const char* BhiB = (const char*)(Xhi + (rowbase + o0) * F_);
  const char* BloB = (const char*)(Xlo + (rowbase + o0) * F_);
  const int rb = F_ * 2;
  char* AsHB = (char*)AsH;
  char* BsHB = (char*)BsH;
  char* AsLB = (char*)AsL;
  char* BsLB = (char*)BsL;
  f32x4 zero = {0.f, 0.f, 0.f, 0.f};
  f32x4 acc[4][4];
#pragma unroll
  for (int i = 0; i < 4; i++)
#pragma unroll
    for (int j = 0; j < 4; j++) acc[i][j] = zero;
  for (int kt = 0; kt < F_ / 32; kt++) {
    const int kb = kt * 64;
#pragma unroll
    for (int u = 0; u < 2; u++) {
      int grow = u * 64 + srow;
      int gslot = sslot ^ (grow & 3);
      size_t go = (size_t)grow * rb + kb + gslot * 16;
      gll16(AhiB + go, AsHB + u * 4096 + t * 16);
      gll16(BhiB + go, BsHB + u * 4096 + t * 16);
      gll16(AloB + go, AsLB + u * 4096 + t * 16);
      gll16(BloB + go, BsLB + u * 4096 + t * 16);
    }
    __syncthreads();
    bf16x8 ah[4], al[4], bh[4], bl[4];
#pragma unroll
    for (int i = 0; i < 4; i++) {
      int ar = wm + i * 16 + frow;
      int aoff = ar * 64 + ((fch ^ (ar & 3)) * 16);
      ah[i] = *(const bf16x8*)(AsHB + aoff);
      al[i] = *(const bf16x8*)(AsLB + aoff);
      int br = wn + i * 16 + frow;
      int boff = br * 64 + ((fch ^ (br & 3)) * 16);
      bh[i] = *(const bf16x8*)(BsHB + boff);
      bl[i] = *(const bf16x8*)(BsLB + boff);
    }
#pragma unroll
    for (int i = 0; i < 4; i++)
#pragma unroll
      for (int j = 0; j < 4; j++) {
        acc[i][j] = __builtin_amdgcn_mfma_f32_16x16x32_bf16(ah[i], bh[j], acc[i][j], 0, 0, 0);
        acc[i][j] = __builtin_amdgcn_mfma_f32_16x16x32_bf16(ah[i], bl[j], acc[i][j], 0, 0, 0);
        acc[i][j] = __builtin_amdgcn_mfma_f32_16x16x32_bf16(al[i], bh[j], acc[i][j], 0, 0, 0);
      }
    __syncthreads();
  }
#pragma unroll
  for (int j = 0; j < 4; j++) {
    int m = o0 + wn + j * 16 + frow;
    if (m >= N_) continue;
    float sm = sq[rowbase + m];
#pragma unroll
    for (int i = 0; i < 4; i++) {
      int nb = m0 + wm + i * 16 + fch * 4;
#pragma unroll
      for (int r = 0; r < 4; r++) {
        int n = nb + r;
        if (n >= N_) continue;
        float d = sq[rowbase + n] + sm - 2.f * acc[i][j][r];
        if (n == m) d = INFINITY;
        dist[(rowbase + n) * N_ + m] = d;
        if (mirror) dist[(rowbase + m) * N_ + n] = d;
      }
    }
  }
}

// ---------------- top-4 per row -> symmetric adjacency bitmask ----------------
__global__ __launch_bounds__(256) void topk_kernel(const float* __restrict__ dist,
                                                   unsigned long long* __restrict__ Abits) {
  int row = blockIdx.x * 4 + (threadIdx.x >> 6);
  int lane = threadIdx.x & 63;
  int b = row / N_, n = row - b * N_;
  const float* dr = dist + (size_t)row * N_;
  float v[4];
  int vi[4];
#pragma unroll
  for (int i = 0; i < 4; i++) {
    int m = lane + i * 64;
    bool ok = (m < N_);
    v[i] = ok ? dr[m] : INFINITY;
    vi[i] = ok ? m : 0x3fffffff;
  }
  unsigned long long nbr[4] = {0ull, 0ull, 0ull, 0ull};
#pragma unroll
  for (int t = 0; t < 4; t++) {
    float bv = v[0];
    int bi = vi[0];
#pragma unroll
    for (int i = 1; i < 4; i++)
      if (v[i] < bv || (v[i] == bv && vi[i] < bi)) { bv = v[i]; bi = vi[i]; }
#pragma unroll
    for (int o = 1; o < 64; o <<= 1) {
      float ov = __shfl_xor(bv, o);
      int oi = __shfl_xor(bi, o);
      if (ov < bv || (ov == bv && oi < bi)) { bv = ov; bi = oi; }
    }
#pragma unroll
    for (int i = 0; i < 4; i++)
      if (vi[i] == bi) { v[i] = INFINITY; vi[i] = 0x3fffffff; }
    if (lane == 0) {
      nbr[bi >> 6] |= 1ull << (bi & 63);
      atomicOr(&Abits[((size_t)b * N_ + bi) * 4 + (n >> 6)], 1ull << (n & 63));
    }
  }
  if (lane == 0) {
#pragma unroll
    for (int w = 0; w < 4; w++)
      if (nbr[w]) atomicOr(&Abits[(size_t)row * 4 + w], nbr[w]);
  }
}

// ---------------- 2-hop adjacency -> bf16 [B][256][224] + deg ----------------
__global__ __launch_bounds__(256) void a2_kernel(const unsigned long long* __restrict__ Abits,
                                                 __hip_bfloat16* __restrict__ A2bf,
                                                 float* __restrict__ deg) {
  int row = blockIdx.x * 4 + (threadIdx.x >> 6);
  int lane = threadIdx.x & 63;
  int b = row / N_, n = row - b * N_;
  const unsigned long long* arow = Abits + (size_t)row * 4;
  const unsigned long long* base = Abits + (size_t)b * N_ * 4;
  unsigned long long r0 = 0, r1 = 0, r2 = 0, r3 = 0;
#pragma unroll
  for (int w = 0; w < 4; w++) {
    if ((arow[w] >> lane) & 1ull) {
      const unsigned long long* mr = base + (size_t)(w * 64 + lane) * 4;
      r0 |= mr[0]; r1 |= mr[1]; r2 |= mr[2]; r3 |= mr[3];
    }
  }
#pragma unroll
  for (int o = 1; o < 64; o <<= 1) {
    r0 |= __shfl_xor(r0, o);
    r1 |= __shfl_xor(r1, o);
    r2 |= __shfl_xor(r2, o);
    r3 |= __shfl_xor(r3, o);
  }
  unsigned long long rr[4] = {r0, r1, r2, r3};
  rr[n >> 6] &= ~(1ull << (n & 63));
  __hip_bfloat16* out = A2bf + ((size_t)b * NA_ + n) * KA_;
  const __hip_bfloat16 one = __float2bfloat16(1.f);
  const __hip_bfloat16 zer = __float2bfloat16(0.f);
#pragma unroll
  for (int i = 0; i < 4; i++) {
    int m = lane + i * 64;
    if (m < KA_)
      out[m] = (m < N_ && ((rr[m >> 6] >> (m & 63)) & 1ull)) ? one : zer;
  }
  if (lane == 0) {
    int dg = __popcll(rr[0]) + __popcll(rr[1]) + __popcll(rr[2]) + __popcll(rr[3]);
    deg[row] = (float)(dg > 0 ? dg : 1);
  }
}

// ---------------- MFMA GEMM: Y = opt_relu(X @ W^T + bias), bf16 in/out, f32 acc ----
template <bool RELU>
__global__ __launch_bounds__(256) void mfma_linear(const __hip_bfloat16* __restrict__ X,
                                                   const __hip_bfloat16* __restrict__ W,
                                                   const float* __restrict__ bias,
                                                   __hip_bfloat16* __restrict__ Y,
                                                   int K, int ldy, int colOff) {
  __shared__ short As[4096];
  __shared__ short Bs[4096];
  const int t = threadIdx.x;
  const int m0 = blockIdx.y * 128, o0 = blockIdx.x * 128;
  const int l = t & 63, w = t >> 6;
  const int wm = (w >> 1) * 64, wn = (w & 1) * 64;
  const int frow = l & 15, fch = l >> 4;
  const int srow = t >> 2, sslot = t & 3;
  const char* Abase = (const char*)(X + (size_t)m0 * K);
  const char* Bbase = (const char*)(W + (size_t)o0 * K);
  const int rb = K * 2;
  char* AsB = (char*)As;
  char* BsB = (char*)Bs;
  f32x4 zero = {0.f, 0.f, 0.f, 0.f};
  f32x4 acc[4][4];
#pragma unroll
  for (int i = 0; i < 4; i++)
#pragma unroll
    for (int j = 0; j < 4; j++) acc[i][j] = zero;
  const int KT = K >> 5;
  for (int kt = 0; kt < KT; kt++) {
    const int kb = kt * 64;
#pragma unroll
    for (int u = 0; u < 2; u++) {
      int grow = u * 64 + srow;
      int gslot = sslot ^ (grow & 3);
      gll16(Abase + (size_t)grow * rb + kb + gslot * 16, AsB + u * 4096 + t * 16);
      gll16(Bbase + (size_t)grow * rb + kb + gslot * 16, BsB + u * 4096 + t * 16);
    }
    __syncthreads();
    bf16x8 af[4], bfv[4];
#pragma unroll
    for (int i = 0; i < 4; i++) {
      int ar = wm + i * 16 + frow;
      af[i] = *(const bf16x8*)(AsB + ar * 64 + ((fch ^ (ar & 3)) * 16));
      int br = wn + i * 16 + frow;
      bfv[i] = *(const bf16x8*)(BsB + br * 64 + ((fch ^ (br & 3)) * 16));
    }
#pragma unroll
    for (int i = 0; i < 4; i++)
#pragma unroll
      for (int j = 0; j < 4; j++)
        acc[i][j] = __builtin_amdgcn_mfma_f32_16x16x32_bf16(af[i], bfv[j], acc[i][j], 0, 0, 0);
    __syncthreads();
  }
#pragma unroll
  for (int j = 0; j < 4; j++) {
    int c = o0 + wn + j * 16 + frow;
    float bv = bias[c];
#pragma unroll
    for (int i = 0; i < 4; i++) {
      int r0 = m0 + wm + i * 16 + fch * 4;
#pragma unroll
      for (int r = 0; r < 4; r++) {
        float v = acc[i][j][r] + bv;
        if (RELU) v = fmaxf(v, 0.f);
        Y[(size_t)(r0 + r) * ldy + colOff + c] = __float2bfloat16(v);
      }
    }
  }
}

// ---------------- MFMA ego2 with fused pooling ----------------
__global__ __launch_bounds__(256) void mfma_ego_pool(const __hip_bfloat16* __restrict__ h1,
                                                     const __hip_bfloat16* __restrict__ W,
                                                     const float* __restrict__ bias,
                                                     float* __restrict__ pool, int poolOff) {
  __shared__ short As[4096];
  __shared__ short Bs[4096];
  const int t = threadIdx.x;
  const int b = blockIdx.z;
  const int m0 = blockIdx.y * 128, o0 = blockIdx.x * 128;
  const int l = t & 63, w = t >> 6;
  const int wm = (w >> 1) * 64, wn = (w & 1) * 64;
  const int frow = l & 15, fch = l >> 4;
  const int srow = t >> 2, sslot = t & 3;
  const char* Abase = (const char*)(h1 + ((size_t)b * N_ + m0) * D2_);
  const char* Bbase = (const char*)(W + (size_t)o0 * D2_);
  char* AsB = (char*)As;
  char* BsB = (char*)Bs;
  f32x4 zero = {0.f, 0.f, 0.f, 0.f};
  f32x4 acc[4][4];
#pragma unroll
  for (int i = 0; i < 4; i++)
#pragma unroll
    for (int j = 0; j < 4; j++) acc[i][j] = zero;
  for (int kt = 0; kt < 32; kt++) {
    const int kb = kt * 64;
#pragma unroll
    for (int u = 0; u < 2; u++) {
      int grow = u * 64 + srow;
      int gslot = sslot ^ (grow & 3);
      gll16(Abase + (size_t)grow * (D2_ * 2) + kb + gslot * 16, AsB + u * 4096 + t * 16);
      gll16(Bbase + (size_t)grow * (D2_ * 2) + kb + gslot * 16, BsB + u * 4096 + t * 16);
    }
    __syncthreads();
    bf16x8 af[4], bfv[4];
#pragma unroll
    for (int i = 0; i < 4; i++) {
      int ar = wm + i * 16 + frow;
      af[i] = *(const bf16x8*)(AsB + ar * 64 + ((fch ^ (ar & 3)) * 16));
      int br = wn + i * 16 + frow;
      bfv[i] = *(const bf16x8*)(BsB + br * 64 + ((fch ^ (br & 3)) * 16));
    }
#pragma unroll
    for (int i = 0; i < 4; i++)
#pragma unroll
      for (int j = 0; j < 4; j++)
        acc[i][j] = __builtin_amdgcn_mfma_f32_16x16x32_bf16(af[i], bfv[j], acc[i][j], 0, 0, 0);
    __syncthreads();
  }
#pragma unroll
  for (int j = 0; j < 4; j++) {
    int c = o0 + wn + j * 16 + frow;
    float bv = bias[c];
    float s = 0.f;
#pragma unroll
    for (int i = 0; i < 4; i++) {
#pragma unroll
      for (int r = 0; r < 4; r++) {
        int n = m0 + wm + i * 16 + fch * 4 + r;
        if (n < N_) s += fmaxf(acc[i][j][r] + bv, 0.f);
      }
    }
    s += __shfl_down(s, 32);
    s += __shfl_down(s, 16);
    if (l < 16) atomicAdd(&pool[(size_t)b * D4_ + poolOff + c], s);
  }
}

// ---------------- MFMA aggregation: A2 @ msg (per batch) ----------------
template <int MODE>
__global__ __launch_bounds__(256) void mfma_agg(const __hip_bfloat16* __restrict__ A2bf,
                                                const __hip_bfloat16* __restrict__ msg,
                                                const float* __restrict__ deg,
                                                __hip_bfloat16* __restrict__ H,
                                                float* __restrict__ pool, int poolOff) {
  __shared__ short As[4096];
  __shared__ short Bs[4096];
  const int t = threadIdx.x;
  const int b = blockIdx.z;
  const int m0 = blockIdx.y * 128, o0 = blockIdx.x * 128;
  const int l = t & 63, w = t >> 6;
  const int wm = (w >> 1) * 64, wn = (w & 1) * 64;
  const int frow = l & 15, fch = l >> 4;
  const int srow = t >> 2, sslot = t & 3;
  const char* Abase = (const char*)(A2bf + ((size_t)b * NA_ + m0) * KA_);
  const __hip_bfloat16* Mb = msg + (size_t)b * N_ * NH_;
  const int bk = t >> 3;
  const int bf0 = (t & 7) * 16;
  char* AsB = (char*)As;
  char* BsB = (char*)Bs;
  f32x4 zero = {0.f, 0.f, 0.f, 0.f};
  f32x4 acc[4][4];
#pragma unroll
  for (int i = 0; i < 4; i++)
#pragma unroll
    for (int j = 0; j < 4; j++) acc[i][j] = zero;
  for (int kt = 0; kt < 7; kt++) {
#pragma unroll
    for (int u = 0; u < 2; u++) {
      int grow = u * 64 + srow;
      int gslot = sslot ^ (grow & 3);
      gll16(Abase + (size_t)grow * (KA_ * 2) + kt * 64 + gslot * 16, AsB + u * 4096 + t * 16);
    }
    int krow = kt * 32 + bk;
    const __hip_bfloat16* mp = Mb + (size_t)krow * NH_ + o0 + bf0;
    bf16x8 v0 = *(const bf16x8*)mp;
    bf16x8 v1 = *(const bf16x8*)(mp + 8);
#pragma unroll
    for (int e = 0; e < 8; e++) {
      int f0a = bf0 + e;
      int f1a = bf0 + 8 + e;
      *(short*)(BsB + f0a * 64 + (((bk >> 3) ^ (f0a & 3)) * 16) + (bk & 7) * 2) = v0[e];
      *(short*)(BsB + f1a * 64 + (((bk >> 3) ^ (f1a & 3)) * 16) + (bk & 7) * 2) = v1[e];
    }
    __syncthreads();
    bf16x8 af[4], bfv[4];
#pragma unroll
    for (int i = 0; i < 4; i++) {
      int ar = wm + i * 16 + frow;
      af[i] = *(const bf16x8*)(AsB + ar * 64 + ((fch ^ (ar & 3)) * 16));
      int br = wn + i * 16 + frow;
      bfv[i] = *(const bf16x8*)(BsB + br * 64 + ((fch ^ (br & 3)) * 16));
    }
#pragma unroll
    for (int i = 0; i < 4; i++)
#pragma unroll
      for (int j = 0; j < 4; j++)
        acc[i][j] = __builtin_amdgcn_mfma_f32_16x16x32_bf16(af[i], bfv[j], acc[i][j], 0, 0, 0);
    __syncthreads();
  }
  if (MODE == 0) {
#pragma unroll
    for (int j = 0; j < 4; j++) {
      int c = o0 + wn + j * 16 + frow;
#pragma unroll
      for (int i = 0; i < 4; i++) {
#pragma unroll
        for (int r = 0; r < 4; r++) {
          int n = m0 + wm + i * 16 + fch * 4 + r;
          if (n < N_) {
            float dv = deg[b * N_ + n];
            float v = fmaxf(acc[i][j][r] / dv, 0.f);
            H[((size_t)b * N_ + n) * D2_ + NH_ + c] = __float2bfloat16(v);
          }
        }
      }
    }
  } else {
#pragma unroll
    for (int j = 0; j < 4; j++) {
      int c = o0 + wn + j * 16 + frow;
      float s = 0.f;
#pragma unroll
      for (int i = 0; i < 4; i++) {
#pragma unroll
        for (int r = 0; r < 4; r++) {
          int n = m0 + wm + i * 16 + fch * 4 + r;
          if (n < N_) {
            float dv = deg[b * N_ + n];
            s += fmaxf(acc[i][j][r] / dv, 0.f);
          }
        }
      }
      s += __shfl_down(s, 32);
      s += __shfl_down(s, 16);
      if (l < 16) atomicAdd(&pool[(size_t)b * D4_ + poolOff + c], s);
    }
  }
}

// ---------------- pooling ----------------
__global__ __launch_bounds__(256) void pool_kernel(const __hip_bfloat16* __restrict__ h1,
                                                   const float* __restrict__ pool,
                                                   float* __restrict__ gf) {
  int b = blockIdx.y;
  int c = blockIdx.x * 256 + threadIdx.x;
  if (c < D2_) {
    const __hip_bfloat16* p = h1 + (size_t)b * N_ * D2_ + c;
    float s = 0.f;
    for (int n = 0; n < N_; n++) s += __bfloat162float(p[(size_t)n * D2_]);
    gf[(size_t)b * D4_ + c] = s * (1.f / N_);
  } else {
    gf[(size_t)b * D4_ + c] = pool[(size_t)b * D4_ + c] * (1.f / N_);
  }
}

// ---------------- f32 linear for the small head ----------------
template <int MODE>
__global__ __launch_bounds__(256) void linear_kernel(const float* __restrict__ Xg,
                                                     const float* __restrict__ W,
                                                     const float* __restrict__ bias,
                                                     float* __restrict__ Y, int ldy, int colOff,
                                                     int Rows, int Fin, int O,
                                                     float* __restrict__ pool, int poolOff) {
  __shared__ float Xs[16][68];
  __shared__ float Ws[16][68];
  int tx = threadIdx.x, ty = threadIdx.y;
  int tid = ty * 16 + tx;
  int lr = tid >> 2;
  int lk = (tid & 3) * 4;
  int rbase = blockIdx.y * 64;
  int o0 = blockIdx.x * 64;
  const float* X = Xg;
  float acc[4][4] = {};
  for (int k0 = 0; k0 < Fin; k0 += 16) {
    float4 xv = make_float4(0.f, 0.f, 0.f, 0.f);
    if (rbase + lr < Rows) xv = *(const float4*)&X[(size_t)(rbase + lr) * Fin + k0 + lk];
    Xs[lk][lr] = xv.x; Xs[lk + 1][lr] = xv.y; Xs[lk + 2][lr] = xv.z; Xs[lk + 3][lr] = xv.w;
    float4 wv = make_float4(0.f, 0.f, 0.f, 0.f);
    if (o0 + lr < O) wv = *(const float4*)&W[(size_t)(o0 + lr) * Fin + k0 + lk];
    Ws[lk][lr] = wv.x; Ws[lk + 1][lr] = wv.y; Ws[lk + 2][lr] = wv.z; Ws[lk + 3][lr] = wv.w;
    __syncthreads();
#pragma unroll
    for (int k = 0; k < 16; k++) {
      float4 a = *(const float4*)&Xs[k][ty * 4];
      float4 bb = *(const float4*)&Ws[k][tx * 4];
      float av[4] = {a.x, a.y, a.z, a.w};
      float bv[4] = {bb.x, bb.y, bb.z, bb.w};
#pragma unroll
      for (int i = 0; i < 4; i++)
#pragma unroll
        for (int j = 0; j < 4; j++) acc[i][j] = fmaf(av[i], bv[j], acc[i][j]);
    }
    __syncthreads();
  }
#pragma unroll
  for (int i = 0; i < 4; i++) {
    int rrow = rbase + ty * 4 + i;
    if (rrow >= Rows) continue;
#pragma unroll
    for (int j = 0; j < 4; j++) {
      int c = o0 + tx * 4 + j;
      if (c >= O) continue;
      float vv = acc[i][j] + bias[c];
      if (MODE == 1) vv = fmaxf(vv, 0.f);
      Y[(size_t)rrow * ldy + colOff + c] = vv;
    }
  }
}

// ---------------- host launch ----------------
extern "C" void kernel_launch(void* const* d_in, const int* in_sizes, int n_in,
                              void* d_out, int out_size, void* d_ws, size_t ws_size,
                              hipStream_t stream) {
  const float* Fet  = (const float*)d_in[0];
  const float* w1_0 = (const float*)d_in[1];
  const float* b1_0 = (const float*)d_in[2];
  const float* w2_0 = (const float*)d_in[3];
  const float* b2_0 = (const float*)d_in[4];
  const float* w1_1 = (const float*)d_in[5];
  const float* b1_1 = (const float*)d_in[6];
  const float* w2_1 = (const float*)d_in[7];
  const float* b2_1 = (const float*)d_in[8];
  const float* fc1_w = (const float*)d_in[9];
  const float* fc1_b = (const float*)d_in[10];
  const float* fc2_w = (const float*)d_in[11];
  const float* fc2_b = (const float*)d_in[12];

  char* ws = (char*)d_ws;
  float* dist = (float*)(ws + OFF_DIST);
  __hip_bfloat16* A2bf = (__hip_bfloat16*)(ws + OFF_DIST);  // overlay (dist dead after topk)
  float* sq = (float*)(ws + OFF_SQ);
  unsigned long long* Abits = (unsigned long long*)(ws + OFF_ABITS);
  float* deg = (float*)(ws + OFF_DEG);
  __hip_bfloat16* Fet_hi = (__hip_bfloat16*)(ws + OFF_FETHI);
  __hip_bfloat16* Fet_lo = (__hip_bfloat16*)(ws + OFF_FETLO);  // overlay msg/h1 head
  __hip_bfloat16* msg = (__hip_bfloat16*)(ws + OFF_MSG);
  __hip_bfloat16* h1 = (__hip_bfloat16*)(ws + OFF_H1);
  float* pool = (float*)(ws + OFF_POOL);
  float* p = (float*)(ws + OFF_P);
  __hip_bfloat16* w10b = (__hip_bfloat16*)(ws + OFF_W10);
  __hip_bfloat16* w20b = (__hip_bfloat16*)(ws + OFF_W20);
  __hip_bfloat16* w11b = (__hip_bfloat16*)(ws + OFF_W11);
  __hip_bfloat16* w21b = (__hip_bfloat16*)(ws + OFF_W21);

  float* out = (float*)d_out;          // [B, NC]
  float* gf = out + (size_t)B_ * NC_;  // [B, D4]

  hipMemsetAsync(Abits, 0, (size_t)ROWS_ * 4 * sizeof(unsigned long long), stream);
  hipMemsetAsync(pool, 0, (size_t)B_ * D4_ * sizeof(float), stream);

  // casts (features hi/lo split for the gram; weights hi only)
  cast_hilo_kernel<<<(ROWS_ * F_ / 4 + 255) / 256, 256, 0, stream>>>(
      Fet, Fet_hi, Fet_lo, ROWS_ * F_ / 4);
  cast_bf16_kernel<<<384, 256, 0, stream>>>(w1_0, w10b, NH_ * F_ / 4);
  cast_bf16_kernel<<<384, 256, 0, stream>>>(w2_0, w20b, NH_ * F_ / 4);
  cast_bf16_kernel<<<512, 256, 0, stream>>>(w1_1, w11b, NH_ * D2_ / 4);
  cast_bf16_kernel<<<512, 256, 0, stream>>>(w2_1, w21b, NH_ * D2_ / 4);

  // graph construction
  sqnorm_kernel<<<ROWS_ / 4, 256, 0, stream>>>(Fet, sq);
  mfma_gram<<<dim3(3, 1, B_), 256, 0, stream>>>(Fet_hi, Fet_lo, sq, dist);
  topk_kernel<<<ROWS_ / 4, 256, 0, stream>>>(dist, Abits);
  a2_kernel<<<ROWS_ / 4, 256, 0, stream>>>(Abits, A2bf, deg);

  // layer 1 (Fet_lo dead from here; msg/h1 overwrite it)
  mfma_linear<false><<<dim3(4, 197), 256, 0, stream>>>(Fet_hi, w20b, b2_0, msg, F_, NH_, 0);
  mfma_linear<true><<<dim3(4, 197), 256, 0, stream>>>(Fet_hi, w10b, b1_0, h1, F_, D2_, 0);
  mfma_agg<0><<<dim3(4, 2, B_), 256, 0, stream>>>(A2bf, msg, deg, h1, nullptr, 0);

  // layer 2 (h2 fused into pool)
  mfma_linear<false><<<dim3(4, 197), 256, 0, stream>>>(h1, w21b, b2_1, msg, D2_, NH_, 0);
  mfma_ego_pool<<<dim3(4, 2, B_), 256, 0, stream>>>(h1, w11b, b1_1, pool, D2_);
  mfma_agg<1><<<dim3(4, 2, B_), 256, 0, stream>>>(A2bf, msg, deg, nullptr, pool, D2_ + NH_);

  // pooling -> graph_features
  pool_kernel<<<dim3(8, B_), 256, 0, stream>>>(h1, pool, gf);

  // head (f32, small)
  linear_kernel<1><<<dim3(8, 2), dim3(16, 16), 0, stream>>>(
      gf, fc1_w, fc1_b, p, NH_, 0, B_, D4_, NH_, nullptr, 0);
  linear_kernel<0><<<dim3(16, 2), dim3(16, 16), 0, stream>>>(
      p, fc2_w, fc2_b, out, NC_, 0, B_, NH_, NC_, nullptr, 0);
}

// Round 4
// 545.346 us; speedup vs baseline: 3.9622x; 1.1636x over previous
//
#include <hip/hip_runtime.h>
#include <hip/hip_bf16.h>
#include <math.h>

typedef __attribute__((ext_vector_type(8))) short bf16x8;
typedef __attribute__((ext_vector_type(4))) float f32x4;

#define B_ 128
#define N_ 197
#define F_ 768
#define NH_ 512
#define D2_ 1024
#define D4_ 2048
#define NC_ 1000
#define ROWS_ (B_ * N_)   // 25216 = 197 * 128 (exact 128-row tiling!)
#define KA_ 224           // agg K padded (197 -> 224 = 7*32)
#define NA_ 256           // agg node rows padded (197 -> 256 = 2*128)

// workspace offsets (bytes).
// dist (f32, 19.87MB) overlays A2bf (bf16, 14.68MB): dist dead after topk.
// Fet_lo (38.8MB) overlays msg+h1 head: lo dead after mfma_gram, msg/h1 written after.
#define OFF_DIST   0ull
#define OFF_SQ     19871232ull
#define OFF_ABITS  19972352ull
#define OFF_DEG    20779520ull
#define OFF_FETHI  20880640ull   // [25280][768] bf16 (64 slack rows for gram over-read)
#define OFF_MSG    59710720ull   // [25248][512] bf16 (32 slack rows for agg B over-read)
#define OFF_H1     85564672ull   // [25280][1024] bf16 (64 slack rows for ego2 A over-read)
#define OFF_FETLO  OFF_MSG       // overlay: [25280][768] bf16, ends 98,540,800
#define OFF_POOL   137338112ull  // [128][2048] f32
#define OFF_P      138386688ull  // [128][512] f32
#define OFF_W10    138648832ull
#define OFF_W20    139435264ull
#define OFF_W11    140221696ull
#define OFF_W21    141270272ull  // end 142,318,848

__device__ __forceinline__ void gll16(const void* g, void* l) {
  __builtin_amdgcn_global_load_lds((const __attribute__((address_space(1))) void*)g,
                                   (__attribute__((address_space(3))) void*)l, 16, 0, 0);
}

// ---------------- f32 -> bf16 cast (weights) ----------------
__global__ __launch_bounds__(256) void cast_bf16_kernel(const float* __restrict__ src,
                                                        __hip_bfloat16* __restrict__ dst,
                                                        int n4) {
  int i = blockIdx.x * 256 + threadIdx.x;
  if (i >= n4) return;
  float4 v = ((const float4*)src)[i];
  union { __hip_bfloat16 h[4]; uint2 u; } pk;
  pk.h[0] = __float2bfloat16(v.x);
  pk.h[1] = __float2bfloat16(v.y);
  pk.h[2] = __float2bfloat16(v.z);
  pk.h[3] = __float2bfloat16(v.w);
  ((uint2*)dst)[i] = pk.u;
}

// ---------------- f32 -> bf16 hi/lo split (features) ----------------
__global__ __launch_bounds__(256) void cast_hilo_kernel(const float* __restrict__ src,
                                                        __hip_bfloat16* __restrict__ hi,
                                                        __hip_bfloat16* __restrict__ lo,
                                                        int n4) {
  int i = blockIdx.x * 256 + threadIdx.x;
  if (i >= n4) return;
  float4 v = ((const float4*)src)[i];
  float f[4] = {v.x, v.y, v.z, v.w};
  union { __hip_bfloat16 h[4]; uint2 u; } ph, pl;
#pragma unroll
  for (int k = 0; k < 4; k++) {
    __hip_bfloat16 h = __float2bfloat16(f[k]);
    ph.h[k] = h;
    pl.h[k] = __float2bfloat16(f[k] - __bfloat162float(h));
  }
  ((uint2*)hi)[i] = ph.u;
  ((uint2*)lo)[i] = pl.u;
}

// ---------------- squared norms (f32 input) ----------------
__global__ __launch_bounds__(256) void sqnorm_kernel(const float* __restrict__ X,
                                                     float* __restrict__ sq) {
  int row = blockIdx.x * 4 + (threadIdx.x >> 6);
  int lane = threadIdx.x & 63;
  const float4* xp = (const float4*)(X + (size_t)row * F_);
  float s = 0.f;
#pragma unroll
  for (int i = 0; i < 3; i++) {
    float4 v = xp[lane + i * 64];
    s += v.x * v.x + v.y * v.y + v.z * v.z + v.w * v.w;
  }
#pragma unroll
  for (int o = 32; o > 0; o >>= 1) s += __shfl_down(s, o);
  if (lane == 0) sq[row] = s;
}

// ---------------- pairwise Gram via MFMA, split-bf16 3-pass ----------------
__global__ __launch_bounds__(256) void mfma_gram(const __hip_bfloat16* __restrict__ Xhi,
                                                 const __hip_bfloat16* __restrict__ Xlo,
                                                 const float* __restrict__ sq,
                                                 float* __restrict__ dist) {
  __shared__ short AsH[4096];
  __shared__ short BsH[4096];
  __shared__ short AsL[4096];
  __shared__ short BsL[4096];
  const int t = threadIdx.x;
  const int b = blockIdx.z;
  const int bx = blockIdx.x;
  const int m0 = (bx == 0) ? 0 : 128;
  const int o0 = (bx == 2) ? 128 : 0;
  const bool mirror = (bx == 1);
  const int l = t & 63, w = t >> 6;
  const int wm = (w >> 1) * 64, wn = (w & 1) * 64;
  const int frow = l & 15, fch = l >> 4;
  const int srow = t >> 2, sslot = t & 3;
  const size_t rowbase = (size_t)b * N_;
  const char* AhiB = (const char*)(Xhi + (rowbase + m0) * F_);
  const char* AloB = (const char*)(Xlo + (rowbase + m0) * F_);
  const char* BhiB = (const char*)(Xhi + (rowbase + o0) * F_);
  const char* BloB = (const char*)(Xlo + (rowbase + o0) * F_);
  const int rb = F_ * 2;
  char* AsHB = (char*)AsH;
  char* BsHB = (char*)BsH;
  char* AsLB = (char*)AsL;
  char* BsLB = (char*)BsL;
  f32x4 zero = {0.f, 0.f, 0.f, 0.f};
  f32x4 acc[4][4];
#pragma unroll
  for (int i = 0; i < 4; i++)
#pragma unroll
    for (int j = 0; j < 4; j++) acc[i][j] = zero;
  for (int kt = 0; kt < F_ / 32; kt++) {
    const int kb = kt * 64;
#pragma unroll
    for (int u = 0; u < 2; u++) {
      int grow = u * 64 + srow;
      int gslot = sslot ^ (grow & 3);
      size_t go = (size_t)grow * rb + kb + gslot * 16;
      gll16(AhiB + go, AsHB + u * 4096 + t * 16);
      gll16(BhiB + go, BsHB + u * 4096 + t * 16);
      gll16(AloB + go, AsLB + u * 4096 + t * 16);
      gll16(BloB + go, BsLB + u * 4096 + t * 16);
    }
    __syncthreads();
    bf16x8 ah[4], al[4], bh[4], bl[4];
#pragma unroll
    for (int i = 0; i < 4; i++) {
      int ar = wm + i * 16 + frow;
      int aoff = ar * 64 + ((fch ^ (ar & 3)) * 16);
      ah[i] = *(const bf16x8*)(AsHB + aoff);
      al[i] = *(const bf16x8*)(AsLB + aoff);
      int br = wn + i * 16 + frow;
      int boff = br * 64 + ((fch ^ (br & 3)) * 16);
      bh[i] = *(const bf16x8*)(BsHB + boff);
      bl[i] = *(const bf16x8*)(BsLB + boff);
    }
#pragma unroll
    for (int i = 0; i < 4; i++)
#pragma unroll
      for (int j = 0; j < 4; j++) {
        acc[i][j] = __builtin_amdgcn_mfma_f32_16x16x32_bf16(ah[i], bh[j], acc[i][j], 0, 0, 0);
        acc[i][j] = __builtin_amdgcn_mfma_f32_16x16x32_bf16(ah[i], bl[j], acc[i][j], 0, 0, 0);
        acc[i][j] = __builtin_amdgcn_mfma_f32_16x16x32_bf16(al[i], bh[j], acc[i][j], 0, 0, 0);
      }
    __syncthreads();
  }
#pragma unroll
  for (int j = 0; j < 4; j++) {
    int m = o0 + wn + j * 16 + frow;
    if (m >= N_) continue;
    float sm = sq[rowbase + m];
#pragma unroll
    for (int i = 0; i < 4; i++) {
      int nb = m0 + wm + i * 16 + fch * 4;
#pragma unroll
      for (int r = 0; r < 4; r++) {
        int n = nb + r;
        if (n >= N_) continue;
        float d = sq[rowbase + n] + sm - 2.f * acc[i][j][r];
        if (n == m) d = INFINITY;
        dist[(rowbase + n) * N_ + m] = d;
        if (mirror) dist[(rowbase + m) * N_ + n] = d;
      }
    }
  }
}

// ---------------- top-4 per row -> symmetric adjacency bitmask ----------------
__global__ __launch_bounds__(256) void topk_kernel(const float* __restrict__ dist,
                                                   unsigned long long* __restrict__ Abits) {
  int row = blockIdx.x * 4 + (threadIdx.x >> 6);
  int lane = threadIdx.x & 63;
  int b = row / N_, n = row - b * N_;
  const float* dr = dist + (size_t)row * N_;
  float v[4];
  int vi[4];
#pragma unroll
  for (int i = 0; i < 4; i++) {
    int m = lane + i * 64;
    bool ok = (m < N_);
    v[i] = ok ? dr[m] : INFINITY;
    vi[i] = ok ? m : 0x3fffffff;
  }
  unsigned long long nbr[4] = {0ull, 0ull, 0ull, 0ull};
#pragma unroll
  for (int t = 0; t < 4; t++) {
    float bv = v[0];
    int bi = vi[0];
#pragma unroll
    for (int i = 1; i < 4; i++)
      if (v[i] < bv || (v[i] == bv && vi[i] < bi)) { bv = v[i]; bi = vi[i]; }
#pragma unroll
    for (int o = 1; o < 64; o <<= 1) {
      float ov = __shfl_xor(bv, o);
      int oi = __shfl_xor(bi, o);
      if (ov < bv || (ov == bv && oi < bi)) { bv = ov; bi = oi; }
    }
#pragma unroll
    for (int i = 0; i < 4; i++)
      if (vi[i] == bi) { v[i] = INFINITY; vi[i] = 0x3fffffff; }
    if (lane == 0) {
      nbr[bi >> 6] |= 1ull << (bi & 63);
      atomicOr(&Abits[((size_t)b * N_ + bi) * 4 + (n >> 6)], 1ull << (n & 63));
    }
  }
  if (lane == 0) {
#pragma unroll
    for (int w = 0; w < 4; w++)
      if (nbr[w]) atomicOr(&Abits[(size_t)row * 4 + w], nbr[w]);
  }
}

// ---------------- 2-hop adjacency -> bf16 [B][256][224] + deg ----------------
__global__ __launch_bounds__(256) void a2_kernel(const unsigned long long* __restrict__ Abits,
                                                 __hip_bfloat16* __restrict__ A2bf,
                                                 float* __restrict__ deg) {
  int row = blockIdx.x * 4 + (threadIdx.x >> 6);
  int lane = threadIdx.x & 63;
  int b = row / N_, n = row - b * N_;
  const unsigned long long* arow = Abits + (size_t)row * 4;
  const unsigned long long* base = Abits + (size_t)b * N_ * 4;
  unsigned long long r0 = 0, r1 = 0, r2 = 0, r3 = 0;
#pragma unroll
  for (int w = 0; w < 4; w++) {
    if ((arow[w] >> lane) & 1ull) {
      const unsigned long long* mr = base + (size_t)(w * 64 + lane) * 4;
      r0 |= mr[0]; r1 |= mr[1]; r2 |= mr[2]; r3 |= mr[3];
    }
  }
#pragma unroll
  for (int o = 1; o < 64; o <<= 1) {
    r0 |= __shfl_xor(r0, o);
    r1 |= __shfl_xor(r1, o);
    r2 |= __shfl_xor(r2, o);
    r3 |= __shfl_xor(r3, o);
  }
  unsigned long long rr[4] = {r0, r1, r2, r3};
  rr[n >> 6] &= ~(1ull << (n & 63));
  __hip_bfloat16* out = A2bf + ((size_t)b * NA_ + n) * KA_;
  const __hip_bfloat16 one = __float2bfloat16(1.f);
  const __hip_bfloat16 zer = __float2bfloat16(0.f);
#pragma unroll
  for (int i = 0; i < 4; i++) {
    int m = lane + i * 64;
    if (m < KA_)
      out[m] = (m < N_ && ((rr[m >> 6] >> (m & 63)) & 1ull)) ? one : zer;
  }
  if (lane == 0) {
    int dg = __popcll(rr[0]) + __popcll(rr[1]) + __popcll(rr[2]) + __popcll(rr[3]);
    deg[row] = (float)(dg > 0 ? dg : 1);
  }
}

// ---------------- MFMA GEMM: Y = opt_relu(X @ W^T + bias), bf16 in/out, f32 acc ----
template <bool RELU>
__global__ __launch_bounds__(256) void mfma_linear(const __hip_bfloat16* __restrict__ X,
                                                   const __hip_bfloat16* __restrict__ W,
                                                   const float* __restrict__ bias,
                                                   __hip_bfloat16* __restrict__ Y,
                                                   int K, int ldy, int colOff) {
  __shared__ short As[4096];
  __shared__ short Bs[4096];
  const int t = threadIdx.x;
  const int m0 = blockIdx.y * 128, o0 = blockIdx.x * 128;
  const int l = t & 63, w = t >> 6;
  const int wm = (w >> 1) * 64, wn = (w & 1) * 64;
  const int frow = l & 15, fch = l >> 4;
  const int srow = t >> 2, sslot = t & 3;
  const char* Abase = (const char*)(X + (size_t)m0 * K);
  const char* Bbase = (const char*)(W + (size_t)o0 * K);
  const int rb = K * 2;
  char* AsB = (char*)As;
  char* BsB = (char*)Bs;
  f32x4 zero = {0.f, 0.f, 0.f, 0.f};
  f32x4 acc[4][4];
#pragma unroll
  for (int i = 0; i < 4; i++)
#pragma unroll
    for (int j = 0; j < 4; j++) acc[i][j] = zero;
  const int KT = K >> 5;
  for (int kt = 0; kt < KT; kt++) {
    const int kb = kt * 64;
#pragma unroll
    for (int u = 0; u < 2; u++) {
      int grow = u * 64 + srow;
      int gslot = sslot ^ (grow & 3);
      gll16(Abase + (size_t)grow * rb + kb + gslot * 16, AsB + u * 4096 + t * 16);
      gll16(Bbase + (size_t)grow * rb + kb + gslot * 16, BsB + u * 4096 + t * 16);
    }
    __syncthreads();
    bf16x8 af[4], bfv[4];
#pragma unroll
    for (int i = 0; i < 4; i++) {
      int ar = wm + i * 16 + frow;
      af[i] = *(const bf16x8*)(AsB + ar * 64 + ((fch ^ (ar & 3)) * 16));
      int br = wn + i * 16 + frow;
      bfv[i] = *(const bf16x8*)(BsB + br * 64 + ((fch ^ (br & 3)) * 16));
    }
#pragma unroll
    for (int i = 0; i < 4; i++)
#pragma unroll
      for (int j = 0; j < 4; j++)
        acc[i][j] = __builtin_amdgcn_mfma_f32_16x16x32_bf16(af[i], bfv[j], acc[i][j], 0, 0, 0);
    __syncthreads();
  }
#pragma unroll
  for (int j = 0; j < 4; j++) {
    int c = o0 + wn + j * 16 + frow;
    float bv = bias[c];
#pragma unroll
    for (int i = 0; i < 4; i++) {
      int r0 = m0 + wm + i * 16 + fch * 4;
#pragma unroll
      for (int r = 0; r < 4; r++) {
        float v = acc[i][j][r] + bv;
        if (RELU) v = fmaxf(v, 0.f);
        Y[(size_t)(r0 + r) * ldy + colOff + c] = __float2bfloat16(v);
      }
    }
  }
}

// ---------------- MFMA ego2 with fused pooling ----------------
__global__ __launch_bounds__(256) void mfma_ego_pool(const __hip_bfloat16* __restrict__ h1,
                                                     const __hip_bfloat16* __restrict__ W,
                                                     const float* __restrict__ bias,
                                                     float* __restrict__ pool, int poolOff) {
  __shared__ short As[4096];
  __shared__ short Bs[4096];
  const int t = threadIdx.x;
  const int b = blockIdx.z;
  const int m0 = blockIdx.y * 128, o0 = blockIdx.x * 128;
  const int l = t & 63, w = t >> 6;
  const int wm = (w >> 1) * 64, wn = (w & 1) * 64;
  const int frow = l & 15, fch = l >> 4;
  const int srow = t >> 2, sslot = t & 3;
  const char* Abase = (const char*)(h1 + ((size_t)b * N_ + m0) * D2_);
  const char* Bbase = (const char*)(W + (size_t)o0 * D2_);
  char* AsB = (char*)As;
  char* BsB = (char*)Bs;
  f32x4 zero = {0.f, 0.f, 0.f, 0.f};
  f32x4 acc[4][4];
#pragma unroll
  for (int i = 0; i < 4; i++)
#pragma unroll
    for (int j = 0; j < 4; j++) acc[i][j] = zero;
  for (int kt = 0; kt < 32; kt++) {
    const int kb = kt * 64;
#pragma unroll
    for (int u = 0; u < 2; u++) {
      int grow = u * 64 + srow;
      int gslot = sslot ^ (grow & 3);
      gll16(Abase + (size_t)grow * (D2_ * 2) + kb + gslot * 16, AsB + u * 4096 + t * 16);
      gll16(Bbase + (size_t)grow * (D2_ * 2) + kb + gslot * 16, BsB + u * 4096 + t * 16);
    }
    __syncthreads();
    bf16x8 af[4], bfv[4];
#pragma unroll
    for (int i = 0; i < 4; i++) {
      int ar = wm + i * 16 + frow;
      af[i] = *(const bf16x8*)(AsB + ar * 64 + ((fch ^ (ar & 3)) * 16));
      int br = wn + i * 16 + frow;
      bfv[i] = *(const bf16x8*)(BsB + br * 64 + ((fch ^ (br & 3)) * 16));
    }
#pragma unroll
    for (int i = 0; i < 4; i++)
#pragma unroll
      for (int j = 0; j < 4; j++)
        acc[i][j] = __builtin_amdgcn_mfma_f32_16x16x32_bf16(af[i], bfv[j], acc[i][j], 0, 0, 0);
    __syncthreads();
  }
#pragma unroll
  for (int j = 0; j < 4; j++) {
    int c = o0 + wn + j * 16 + frow;
    float bv = bias[c];
    float s = 0.f;
#pragma unroll
    for (int i = 0; i < 4; i++) {
#pragma unroll
      for (int r = 0; r < 4; r++) {
        int n = m0 + wm + i * 16 + fch * 4 + r;
        if (n < N_) s += fmaxf(acc[i][j][r] + bv, 0.f);
      }
    }
    s += __shfl_down(s, 32);
    s += __shfl_down(s, 16);
    if (l < 16) atomicAdd(&pool[(size_t)b * D4_ + poolOff + c], s);
  }
}

// ---------------- MFMA aggregation: A2 @ msg (per batch) ----------------
template <int MODE>
__global__ __launch_bounds__(256) void mfma_agg(const __hip_bfloat16* __restrict__ A2bf,
                                                const __hip_bfloat16* __restrict__ msg,
                                                const float* __restrict__ deg,
                                                __hip_bfloat16* __restrict__ H,
                                                float* __restrict__ pool, int poolOff) {
  __shared__ short As[4096];
  __shared__ short Bs[4096];
  const int t = threadIdx.x;
  const int b = blockIdx.z;
  const int m0 = blockIdx.y * 128, o0 = blockIdx.x * 128;
  const int l = t & 63, w = t >> 6;
  const int wm = (w >> 1) * 64, wn = (w & 1) * 64;
  const int frow = l & 15, fch = l >> 4;
  const int srow = t >> 2, sslot = t & 3;
  const char* Abase = (const char*)(A2bf + ((size_t)b * NA_ + m0) * KA_);
  const __hip_bfloat16* Mb = msg + (size_t)b * N_ * NH_;
  const int bk = t >> 3;
  const int bf0 = (t & 7) * 16;
  char* AsB = (char*)As;
  char* BsB = (char*)Bs;
  f32x4 zero = {0.f, 0.f, 0.f, 0.f};
  f32x4 acc[4][4];
#pragma unroll
  for (int i = 0; i < 4; i++)
#pragma unroll
    for (int j = 0; j < 4; j++) acc[i][j] = zero;
  for (int kt = 0; kt < 7; kt++) {
#pragma unroll
    for (int u = 0; u < 2; u++) {
      int grow = u * 64 + srow;
      int gslot = sslot ^ (grow & 3);
      gll16(Abase + (size_t)grow * (KA_ * 2) + kt * 64 + gslot * 16, AsB + u * 4096 + t * 16);
    }
    int krow = kt * 32 + bk;
    const __hip_bfloat16* mp = Mb + (size_t)krow * NH_ + o0 + bf0;
    bf16x8 v0 = *(const bf16x8*)mp;
    bf16x8 v1 = *(const bf16x8*)(mp + 8);
#pragma unroll
    for (int e = 0; e < 8; e++) {
      int f0a = bf0 + e;
      int f1a = bf0 + 8 + e;
      *(short*)(BsB + f0a * 64 + (((bk >> 3) ^ (f0a & 3)) * 16) + (bk & 7) * 2) = v0[e];
      *(short*)(BsB + f1a * 64 + (((bk >> 3) ^ (f1a & 3)) * 16) + (bk & 7) * 2) = v1[e];
    }
    __syncthreads();
    bf16x8 af[4], bfv[4];
#pragma unroll
    for (int i = 0; i < 4; i++) {
      int ar = wm + i * 16 + frow;
      af[i] = *(const bf16x8*)(AsB + ar * 64 + ((fch ^ (ar & 3)) * 16));
      int br = wn + i * 16 + frow;
      bfv[i] = *(const bf16x8*)(BsB + br * 64 + ((fch ^ (br & 3)) * 16));
    }
#pragma unroll
    for (int i = 0; i < 4; i++)
#pragma unroll
      for (int j = 0; j < 4; j++)
        acc[i][j] = __builtin_amdgcn_mfma_f32_16x16x32_bf16(af[i], bfv[j], acc[i][j], 0, 0, 0);
    __syncthreads();
  }
  if (MODE == 0) {
#pragma unroll
    for (int j = 0; j < 4; j++) {
      int c = o0 + wn + j * 16 + frow;
#pragma unroll
      for (int i = 0; i < 4; i++) {
#pragma unroll
        for (int r = 0; r < 4; r++) {
          int n = m0 + wm + i * 16 + fch * 4 + r;
          if (n < N_) {
            float dv = deg[b * N_ + n];
            float v = fmaxf(acc[i][j][r] / dv, 0.f);
            H[((size_t)b * N_ + n) * D2_ + NH_ + c] = __float2bfloat16(v);
          }
        }
      }
    }
  } else {
#pragma unroll
    for (int j = 0; j < 4; j++) {
      int c = o0 + wn + j * 16 + frow;
      float s = 0.f;
#pragma unroll
      for (int i = 0; i < 4; i++) {
#pragma unroll
        for (int r = 0; r < 4; r++) {
          int n = m0 + wm + i * 16 + fch * 4 + r;
          if (n < N_) {
            float dv = deg[b * N_ + n];
            s += fmaxf(acc[i][j][r] / dv, 0.f);
          }
        }
      }
      s += __shfl_down(s, 32);
      s += __shfl_down(s, 16);
      if (l < 16) atomicAdd(&pool[(size_t)b * D4_ + poolOff + c], s);
    }
  }
}

// ---------------- pooling ----------------
__global__ __launch_bounds__(256) void pool_kernel(const __hip_bfloat16* __restrict__ h1,
                                                   const float* __restrict__ pool,
                                                   float* __restrict__ gf) {
  int b = blockIdx.y;
  int c = blockIdx.x * 256 + threadIdx.x;
  if (c < D2_) {
    const __hip_bfloat16* p = h1 + (size_t)b * N_ * D2_ + c;
    float s = 0.f;
    for (int n = 0; n < N_; n++) s += __bfloat162float(p[(size_t)n * D2_]);
    gf[(size_t)b * D4_ + c] = s * (1.f / N_);
  } else {
    gf[(size_t)b * D4_ + c] = pool[(size_t)b * D4_ + c] * (1.f / N_);
  }
}

// ---------------- head GEMM: split-K f32, atomic accumulate ----------------
// Y[r][c] (+)= sum_kchunk X[r][k]*W[c][k]  (+ bias at z==0). RELUX applies relu
// to X on load (fc1's relu folded into fc2's read). Y must be zeroed first.
template <bool RELUX>
__global__ __launch_bounds__(256) void head_gemm(const float* __restrict__ Xg,
                                                 const float* __restrict__ W,
                                                 const float* __restrict__ bias,
                                                 float* __restrict__ Y,
                                                 int Rows, int Fin, int O, int kchunk) {
  __shared__ float Xs[16][68];
  __shared__ float Ws[16][68];
  int tx = threadIdx.x, ty = threadIdx.y;
  int tid = ty * 16 + tx;
  int lr = tid >> 2;
  int lk = (tid & 3) * 4;
  int rbase = blockIdx.y * 64;
  int o0 = blockIdx.x * 64;
  int k0base = blockIdx.z * kchunk;
  float acc[4][4] = {};
  for (int k0 = k0base; k0 < k0base + kchunk; k0 += 16) {
    float4 xv = make_float4(0.f, 0.f, 0.f, 0.f);
    if (rbase + lr < Rows) xv = *(const float4*)&Xg[(size_t)(rbase + lr) * Fin + k0 + lk];
    if (RELUX) {
      xv.x = fmaxf(xv.x, 0.f); xv.y = fmaxf(xv.y, 0.f);
      xv.z = fmaxf(xv.z, 0.f); xv.w = fmaxf(xv.w, 0.f);
    }
    Xs[lk][lr] = xv.x; Xs[lk + 1][lr] = xv.y; Xs[lk + 2][lr] = xv.z; Xs[lk + 3][lr] = xv.w;
    float4 wv = make_float4(0.f, 0.f, 0.f, 0.f);
    if (o0 + lr < O) wv = *(const float4*)&W[(size_t)(o0 + lr) * Fin + k0 + lk];
    Ws[lk][lr] = wv.x; Ws[lk + 1][lr] = wv.y; Ws[lk + 2][lr] = wv.z; Ws[lk + 3][lr] = wv.w;
    __syncthreads();
#pragma unroll
    for (int k = 0; k < 16; k++) {
      float4 a = *(const float4*)&Xs[k][ty * 4];
      float4 bb = *(const float4*)&Ws[k][tx * 4];
      float av[4] = {a.x, a.y, a.z, a.w};
      float bv[4] = {bb.x, bb.y, bb.z, bb.w};
#pragma unroll
      for (int i = 0; i < 4; i++)
#pragma unroll
        for (int j = 0; j < 4; j++) acc[i][j] = fmaf(av[i], bv[j], acc[i][j]);
    }
    __syncthreads();
  }
#pragma unroll
  for (int i = 0; i < 4; i++) {
    int rrow = rbase + ty * 4 + i;
    if (rrow >= Rows) continue;
#pragma unroll
    for (int j = 0; j < 4; j++) {
      int c = o0 + tx * 4 + j;
      if (c >= O) continue;
      float vv = acc[i][j] + ((blockIdx.z == 0) ? bias[c] : 0.f);
      atomicAdd(&Y[(size_t)rrow * O + c], vv);
    }
  }
}

// ---------------- host launch ----------------
extern "C" void kernel_launch(void* const* d_in, const int* in_sizes, int n_in,
                              void* d_out, int out_size, void* d_ws, size_t ws_size,
                              hipStream_t stream) {
  const float* Fet  = (const float*)d_in[0];
  const float* w1_0 = (const float*)d_in[1];
  const float* b1_0 = (const float*)d_in[2];
  const float* w2_0 = (const float*)d_in[3];
  const float* b2_0 = (const float*)d_in[4];
  const float* w1_1 = (const float*)d_in[5];
  const float* b1_1 = (const float*)d_in[6];
  const float* w2_1 = (const float*)d_in[7];
  const float* b2_1 = (const float*)d_in[8];
  const float* fc1_w = (const float*)d_in[9];
  const float* fc1_b = (const float*)d_in[10];
  const float* fc2_w = (const float*)d_in[11];
  const float* fc2_b = (const float*)d_in[12];

  char* ws = (char*)d_ws;
  float* dist = (float*)(ws + OFF_DIST);
  __hip_bfloat16* A2bf = (__hip_bfloat16*)(ws + OFF_DIST);  // overlay (dist dead after topk)
  float* sq = (float*)(ws + OFF_SQ);
  unsigned long long* Abits = (unsigned long long*)(ws + OFF_ABITS);
  float* deg = (float*)(ws + OFF_DEG);
  __hip_bfloat16* Fet_hi = (__hip_bfloat16*)(ws + OFF_FETHI);
  __hip_bfloat16* Fet_lo = (__hip_bfloat16*)(ws + OFF_FETLO);  // overlay msg/h1 head
  __hip_bfloat16* msg = (__hip_bfloat16*)(ws + OFF_MSG);
  __hip_bfloat16* h1 = (__hip_bfloat16*)(ws + OFF_H1);
  float* pool = (float*)(ws + OFF_POOL);
  float* p = (float*)(ws + OFF_P);
  __hip_bfloat16* w10b = (__hip_bfloat16*)(ws + OFF_W10);
  __hip_bfloat16* w20b = (__hip_bfloat16*)(ws + OFF_W20);
  __hip_bfloat16* w11b = (__hip_bfloat16*)(ws + OFF_W11);
  __hip_bfloat16* w21b = (__hip_bfloat16*)(ws + OFF_W21);

  float* out = (float*)d_out;          // [B, NC]
  float* gf = out + (size_t)B_ * NC_;  // [B, D4]

  hipMemsetAsync(Abits, 0, (size_t)ROWS_ * 4 * sizeof(unsigned long long), stream);
  hipMemsetAsync(pool, 0, (size_t)B_ * D4_ * sizeof(float), stream);
  hipMemsetAsync(p, 0, (size_t)B_ * NH_ * sizeof(float), stream);
  hipMemsetAsync(out, 0, (size_t)B_ * NC_ * sizeof(float), stream);

  // casts (features hi/lo split for the gram; weights hi only)
  cast_hilo_kernel<<<(ROWS_ * F_ / 4 + 255) / 256, 256, 0, stream>>>(
      Fet, Fet_hi, Fet_lo, ROWS_ * F_ / 4);
  cast_bf16_kernel<<<384, 256, 0, stream>>>(w1_0, w10b, NH_ * F_ / 4);
  cast_bf16_kernel<<<384, 256, 0, stream>>>(w2_0, w20b, NH_ * F_ / 4);
  cast_bf16_kernel<<<512, 256, 0, stream>>>(w1_1, w11b, NH_ * D2_ / 4);
  cast_bf16_kernel<<<512, 256, 0, stream>>>(w2_1, w21b, NH_ * D2_ / 4);

  // graph construction
  sqnorm_kernel<<<ROWS_ / 4, 256, 0, stream>>>(Fet, sq);
  mfma_gram<<<dim3(3, 1, B_), 256, 0, stream>>>(Fet_hi, Fet_lo, sq, dist);
  topk_kernel<<<ROWS_ / 4, 256, 0, stream>>>(dist, Abits);
  a2_kernel<<<ROWS_ / 4, 256, 0, stream>>>(Abits, A2bf, deg);

  // layer 1 (Fet_lo dead from here; msg/h1 overwrite it)
  mfma_linear<false><<<dim3(4, 197), 256, 0, stream>>>(Fet_hi, w20b, b2_0, msg, F_, NH_, 0);
  mfma_linear<true><<<dim3(4, 197), 256, 0, stream>>>(Fet_hi, w10b, b1_0, h1, F_, D2_, 0);
  mfma_agg<0><<<dim3(4, 2, B_), 256, 0, stream>>>(A2bf, msg, deg, h1, nullptr, 0);

  // layer 2 (h2 fused into pool)
  mfma_linear<false><<<dim3(4, 197), 256, 0, stream>>>(h1, w21b, b2_1, msg, D2_, NH_, 0);
  mfma_ego_pool<<<dim3(4, 2, B_), 256, 0, stream>>>(h1, w11b, b1_1, pool, D2_);
  mfma_agg<1><<<dim3(4, 2, B_), 256, 0, stream>>>(A2bf, msg, deg, nullptr, pool, D2_ + NH_);

  // pooling -> graph_features
  pool_kernel<<<dim3(8, B_), 256, 0, stream>>>(h1, pool, gf);

  // head (f32, split-K + atomics; fc1 relu folded into fc2 X-load)
  head_gemm<false><<<dim3(8, 2, 16), dim3(16, 16), 0, stream>>>(
      gf, fc1_w, fc1_b, p, B_, D4_, NH_, 128);
  head_gemm<true><<<dim3(16, 2, 8), dim3(16, 16), 0, stream>>>(
      p, fc2_w, fc2_b, out, B_, NH_, NC_, 64);
}

// Round 5
// 535.577 us; speedup vs baseline: 4.0345x; 1.0182x over previous
//
#include <hip/hip_runtime.h>
#include <hip/hip_bf16.h>
#include <math.h>

typedef __attribute__((ext_vector_type(8))) short bf16x8;
typedef __attribute__((ext_vector_type(4))) float f32x4;

#define B_ 128
#define N_ 197
#define F_ 768
#define NH_ 512
#define D2_ 1024
#define D4_ 2048
#define NC_ 1000
#define ROWS_ (B_ * N_)   // 25216 = 197 * 128 (exact 128-row tiling)
#define KA_ 224           // agg K padded (197 -> 224 = 7*32)
#define NA_ 256           // agg node rows padded (197 -> 256 = 2*128)

// workspace offsets (bytes).
// g0 (f32, 19.87MB) overlays A2bf (bf16, 14.68MB): g0 dead after topk.
// Fet_lo (38.8MB) overlays msg + h1 head: lo dead after mfma_gram.
#define OFF_DIST0  0ull
#define OFF_SQ     19871232ull
#define OFF_ABITS  19972352ull
#define OFF_DEG    20779520ull
#define OFF_FETHI  20880640ull   // [25280][768] bf16 (64 slack rows for gram over-read)
#define OFF_MSG    59710720ull   // [25248][512] bf16 (32 slack rows for agg B over-read)
#define OFF_H1     85564672ull   // [25280][1024] bf16
#define OFF_FETLO  OFF_MSG       // overlay: [25280][768] bf16, ends 98,540,800
#define OFF_POOL   137338112ull  // [128][2048] f32
#define OFF_P      138386688ull  // [128][512] f32
#define OFF_WC1    138648832ull  // [1024][768] bf16: rows 0-511=w1_0(ego), 512-1023=w2_0(msg)
#define OFF_WC2    140221696ull  // [1024][1024] bf16: rows 0-511=w1_1, 512-1023=w2_1
#define OFF_DIST1  142318848ull  // [B][N][N] f32, end 162,190,080

__device__ __forceinline__ void gll16(const void* g, void* l) {
  __builtin_amdgcn_global_load_lds((const __attribute__((address_space(1))) void*)g,
                                   (__attribute__((address_space(3))) void*)l, 16, 0, 0);
}

// ---------------- f32 -> bf16 cast (weights) ----------------
__global__ __launch_bounds__(256) void cast_bf16_kernel(const float* __restrict__ src,
                                                        __hip_bfloat16* __restrict__ dst,
                                                        int n4) {
  int i = blockIdx.x * 256 + threadIdx.x;
  if (i >= n4) return;
  float4 v = ((const float4*)src)[i];
  union { __hip_bfloat16 h[4]; uint2 u; } pk;
  pk.h[0] = __float2bfloat16(v.x);
  pk.h[1] = __float2bfloat16(v.y);
  pk.h[2] = __float2bfloat16(v.z);
  pk.h[3] = __float2bfloat16(v.w);
  ((uint2*)dst)[i] = pk.u;
}

// ---------------- f32 -> bf16 hi/lo split + squared norms (one Fet read) ----------------
__global__ __launch_bounds__(256) void cast_hilo_sq(const float* __restrict__ X,
                                                    __hip_bfloat16* __restrict__ hi,
                                                    __hip_bfloat16* __restrict__ lo,
                                                    float* __restrict__ sq) {
  int row = blockIdx.x * 4 + (threadIdx.x >> 6);
  int lane = threadIdx.x & 63;
  const float4* xp = (const float4*)(X + (size_t)row * F_);
  uint2* hp = (uint2*)(hi + (size_t)row * F_);
  uint2* lp = (uint2*)(lo + (size_t)row * F_);
  float s = 0.f;
#pragma unroll
  for (int i = 0; i < 3; i++) {  // 768/4 = 192 = 3*64
    float4 v = xp[lane + i * 64];
    s += v.x * v.x + v.y * v.y + v.z * v.z + v.w * v.w;
    float f[4] = {v.x, v.y, v.z, v.w};
    union { __hip_bfloat16 h[4]; uint2 u; } ph, pl;
#pragma unroll
    for (int k = 0; k < 4; k++) {
      __hip_bfloat16 h = __float2bfloat16(f[k]);
      ph.h[k] = h;
      pl.h[k] = __float2bfloat16(f[k] - __bfloat162float(h));
    }
    hp[lane + i * 64] = ph.u;
    lp[lane + i * 64] = pl.u;
  }
#pragma unroll
  for (int o = 32; o > 0; o >>= 1) s += __shfl_down(s, o);
  if (lane == 0) sq[row] = s;
}

// ---------------- pairwise Gram via MFMA, split-bf16 3-pass, K-split x2 ----------------
// Writes raw dot partials g = hi.hi + hi.lo + lo.hi for its K-half into g0/g1.
// topk folds sq[m] - 2*(g0+g1) (sq[n] row-constant -> ranking-invariant) + diag INF.
__global__ __launch_bounds__(256) void mfma_gram(const __hip_bfloat16* __restrict__ Xhi,
                                                 const __hip_bfloat16* __restrict__ Xlo,
                                                 float* __restrict__ g0,
                                                 float* __restrict__ g1) {
  __shared__ short AsH[4096];
  __shared__ short BsH[4096];
  __shared__ short AsL[4096];
  __shared__ short BsL[4096];
  const int t = threadIdx.x;
  const int b = blockIdx.z;
  const int bx = blockIdx.x;
  const int khalf = blockIdx.y;
  const int m0 = (bx == 0) ? 0 : 128;
  const int o0 = (bx == 2) ? 128 : 0;
  const bool mirror = (bx == 1);
  const int l = t & 63, w = t >> 6;
  const int wm = (w >> 1) * 64, wn = (w & 1) * 64;
  const int frow = l & 15, fch = l >> 4;
  const int srow = t >> 2, sslot = t & 3;
  const size_t rowbase = (size_t)b * N_;
  const char* AhiB = (const char*)(Xhi + (rowbase + m0) * F_);
  const char* AloB = (const char*)(Xlo + (rowbase + m0) * F_);
  const char* BhiB = (const char*)(Xhi + (rowbase + o0) * F_);
  const char* BloB = (const char*)(Xlo + (rowbase + o0) * F_);
  const int rb = F_ * 2;
  char* AsHB = (char*)AsH;
  char* BsHB = (char*)BsH;
  char* AsLB = (char*)AsL;
  char* BsLB = (char*)BsL;
  float* go = khalf ? g1 : g0;
  f32x4 zero = {0.f, 0.f, 0.f, 0.f};
  f32x4 acc[4][4];
#pragma unroll
  for (int i = 0; i < 4; i++)
#pragma unroll
    for (int j = 0; j < 4; j++) acc[i][j] = zero;
  const int kt0 = khalf * 12;
  for (int kt = kt0; kt < kt0 + 12; kt++) {
    const int kb = kt * 64;
#pragma unroll
    for (int u = 0; u < 2; u++) {
      int grow = u * 64 + srow;
      int gslot = sslot ^ (grow & 3);
      size_t goff = (size_t)grow * rb + kb + gslot * 16;
      gll16(AhiB + goff, AsHB + u * 4096 + t * 16);
      gll16(BhiB + goff, BsHB + u * 4096 + t * 16);
      gll16(AloB + goff, AsLB + u * 4096 + t * 16);
      gll16(BloB + goff, BsLB + u * 4096 + t * 16);
    }
    __syncthreads();
    bf16x8 ah[4], al[4], bh[4], bl[4];
#pragma unroll
    for (int i = 0; i < 4; i++) {
      int ar = wm + i * 16 + frow;
      int aoff = ar * 64 + ((fch ^ (ar & 3)) * 16);
      ah[i] = *(const bf16x8*)(AsHB + aoff);
      al[i] = *(const bf16x8*)(AsLB + aoff);
      int br = wn + i * 16 + frow;
      int boff = br * 64 + ((fch ^ (br & 3)) * 16);
      bh[i] = *(const bf16x8*)(BsHB + boff);
      bl[i] = *(const bf16x8*)(BsLB + boff);
    }
#pragma unroll
    for (int i = 0; i < 4; i++)
#pragma unroll
      for (int j = 0; j < 4; j++) {
        acc[i][j] = __builtin_amdgcn_mfma_f32_16x16x32_bf16(ah[i], bh[j], acc[i][j], 0, 0, 0);
        acc[i][j] = __builtin_amdgcn_mfma_f32_16x16x32_bf16(ah[i], bl[j], acc[i][j], 0, 0, 0);
        acc[i][j] = __builtin_amdgcn_mfma_f32_16x16x32_bf16(al[i], bh[j], acc[i][j], 0, 0, 0);
      }
    __syncthreads();
  }
#pragma unroll
  for (int j = 0; j < 4; j++) {
    int m = o0 + wn + j * 16 + frow;
    if (m >= N_) continue;
#pragma unroll
    for (int i = 0; i < 4; i++) {
      int nb = m0 + wm + i * 16 + fch * 4;
#pragma unroll
      for (int r = 0; r < 4; r++) {
        int n = nb + r;
        if (n >= N_) continue;
        float g = acc[i][j][r];
        go[(rowbase + n) * N_ + m] = g;
        if (mirror) go[(rowbase + m) * N_ + n] = g;
      }
    }
  }
}

// ---------------- top-4 per row -> symmetric adjacency bitmask ----------------
__global__ __launch_bounds__(256) void topk_kernel(const float* __restrict__ g0,
                                                   const float* __restrict__ g1,
                                                   const float* __restrict__ sq,
                                                   unsigned long long* __restrict__ Abits) {
  int row = blockIdx.x * 4 + (threadIdx.x >> 6);
  int lane = threadIdx.x & 63;
  int b = row / N_, n = row - b * N_;
  const float* g0r = g0 + (size_t)row * N_;
  const float* g1r = g1 + (size_t)row * N_;
  const float* sqb = sq + (size_t)b * N_;
  float v[4];
  int vi[4];
#pragma unroll
  for (int i = 0; i < 4; i++) {
    int m = lane + i * 64;
    bool ok = (m < N_) && (m != n);
    v[i] = ok ? (sqb[m] - 2.f * (g0r[m] + g1r[m])) : INFINITY;
    vi[i] = ok ? m : 0x3fffffff;
  }
  unsigned long long nbr[4] = {0ull, 0ull, 0ull, 0ull};
#pragma unroll
  for (int t = 0; t < 4; t++) {
    float bv = v[0];
    int bi = vi[0];
#pragma unroll
    for (int i = 1; i < 4; i++)
      if (v[i] < bv || (v[i] == bv && vi[i] < bi)) { bv = v[i]; bi = vi[i]; }
#pragma unroll
    for (int o = 1; o < 64; o <<= 1) {
      float ov = __shfl_xor(bv, o);
      int oi = __shfl_xor(bi, o);
      if (ov < bv || (ov == bv && oi < bi)) { bv = ov; bi = oi; }
    }
#pragma unroll
    for (int i = 0; i < 4; i++)
      if (vi[i] == bi) { v[i] = INFINITY; vi[i] = 0x3fffffff; }
    if (lane == 0) {
      nbr[bi >> 6] |= 1ull << (bi & 63);
      atomicOr(&Abits[((size_t)b * N_ + bi) * 4 + (n >> 6)], 1ull << (n & 63));
    }
  }
  if (lane == 0) {
#pragma unroll
    for (int w = 0; w < 4; w++)
      if (nbr[w]) atomicOr(&Abits[(size_t)row * 4 + w], nbr[w]);
  }
}

// ---------------- 2-hop adjacency -> bf16 [B][256][224] + deg ----------------
__global__ __launch_bounds__(256) void a2_kernel(const unsigned long long* __restrict__ Abits,
                                                 __hip_bfloat16* __restrict__ A2bf,
                                                 float* __restrict__ deg) {
  int row = blockIdx.x * 4 + (threadIdx.x >> 6);
  int lane = threadIdx.x & 63;
  int b = row / N_, n = row - b * N_;
  const unsigned long long* arow = Abits + (size_t)row * 4;
  const unsigned long long* base = Abits + (size_t)b * N_ * 4;
  unsigned long long r0 = 0, r1 = 0, r2 = 0, r3 = 0;
#pragma unroll
  for (int w = 0; w < 4; w++) {
    if ((arow[w] >> lane) & 1ull) {
      const unsigned long long* mr = base + (size_t)(w * 64 + lane) * 4;
      r0 |= mr[0]; r1 |= mr[1]; r2 |= mr[2]; r3 |= mr[3];
    }
  }
#pragma unroll
  for (int o = 1; o < 64; o <<= 1) {
    r0 |= __shfl_xor(r0, o);
    r1 |= __shfl_xor(r1, o);
    r2 |= __shfl_xor(r2, o);
    r3 |= __shfl_xor(r3, o);
  }
  unsigned long long rr[4] = {r0, r1, r2, r3};
  rr[n >> 6] &= ~(1ull << (n & 63));
  __hip_bfloat16* out = A2bf + ((size_t)b * NA_ + n) * KA_;
  const __hip_bfloat16 one = __float2bfloat16(1.f);
  const __hip_bfloat16 zer = __float2bfloat16(0.f);
#pragma unroll
  for (int i = 0; i < 4; i++) {
    int m = lane + i * 64;
    if (m < KA_)
      out[m] = (m < N_ && ((rr[m >> 6] >> (m & 63)) & 1ull)) ? one : zer;
  }
  if (lane == 0) {
    int dg = __popcll(rr[0]) + __popcll(rr[1]) + __popcll(rr[2]) + __popcll(rr[3]);
    deg[row] = (float)(dg > 0 ? dg : 1);
  }
}

// ---------------- merged ego+msg GEMM over concat weights [1024][K] ----------------
// Cols 0-511 = ego (biasE), 512-1023 = msg (biasM).
// MODE 1 (layer1): ego -> relu -> h1[:, :512]; msg -> msg buffer.
// MODE 2 (layer2): ego -> relu -> per-batch pool atomics (offset D2_, batch-split);
//                  msg -> msg buffer.
template <int MODE>
__global__ __launch_bounds__(256) void mfma_fused(const __hip_bfloat16* __restrict__ X,
                                                  const __hip_bfloat16* __restrict__ Wcat,
                                                  const float* __restrict__ biasE,
                                                  const float* __restrict__ biasM,
                                                  __hip_bfloat16* __restrict__ h1,
                                                  __hip_bfloat16* __restrict__ msg,
                                                  float* __restrict__ pool,
                                                  int K) {
  __shared__ short As[4096];
  __shared__ short Bs[4096];
  const int t = threadIdx.x;
  const int m0 = blockIdx.y * 128, o0 = blockIdx.x * 128;
  const int l = t & 63, w = t >> 6;
  const int wm = (w >> 1) * 64, wn = (w & 1) * 64;
  const int frow = l & 15, fch = l >> 4;
  const int srow = t >> 2, sslot = t & 3;
  const char* Abase = (const char*)(X + (size_t)m0 * K);
  const char* Bbase = (const char*)(Wcat + (size_t)o0 * K);
  const int rb = K * 2;
  char* AsB = (char*)As;
  char* BsB = (char*)Bs;
  f32x4 zero = {0.f, 0.f, 0.f, 0.f};
  f32x4 acc[4][4];
#pragma unroll
  for (int i = 0; i < 4; i++)
#pragma unroll
    for (int j = 0; j < 4; j++) acc[i][j] = zero;
  const int KT = K >> 5;
  for (int kt = 0; kt < KT; kt++) {
    const int kb = kt * 64;
#pragma unroll
    for (int u = 0; u < 2; u++) {
      int grow = u * 64 + srow;
      int gslot = sslot ^ (grow & 3);
      gll16(Abase + (size_t)grow * rb + kb + gslot * 16, AsB + u * 4096 + t * 16);
      gll16(Bbase + (size_t)grow * rb + kb + gslot * 16, BsB + u * 4096 + t * 16);
    }
    __syncthreads();
    bf16x8 af[4], bfv[4];
#pragma unroll
    for (int i = 0; i < 4; i++) {
      int ar = wm + i * 16 + frow;
      af[i] = *(const bf16x8*)(AsB + ar * 64 + ((fch ^ (ar & 3)) * 16));
      int br = wn + i * 16 + frow;
      bfv[i] = *(const bf16x8*)(BsB + br * 64 + ((fch ^ (br & 3)) * 16));
    }
#pragma unroll
    for (int i = 0; i < 4; i++)
#pragma unroll
      for (int j = 0; j < 4; j++)
        acc[i][j] = __builtin_amdgcn_mfma_f32_16x16x32_bf16(af[i], bfv[j], acc[i][j], 0, 0, 0);
    __syncthreads();
  }
  const bool ego = (o0 < 512);
#pragma unroll
  for (int j = 0; j < 4; j++) {
    int c = o0 + wn + j * 16 + frow;
    if (ego) {
      float bv = biasE[c];
      if (MODE == 1) {
#pragma unroll
        for (int i = 0; i < 4; i++) {
          int r0 = m0 + wm + i * 16 + fch * 4;
#pragma unroll
          for (int r = 0; r < 4; r++) {
            float v = fmaxf(acc[i][j][r] + bv, 0.f);
            h1[(size_t)(r0 + r) * D2_ + c] = __float2bfloat16(v);
          }
        }
      } else {
        // pool-only, batch-boundary-aware (wave rows = [m0+wm, m0+wm+64))
        int rw = m0 + wm;
        int b0 = rw / N_;
        int rB = (b0 + 1) * N_;
        float sA = 0.f, sB = 0.f;
#pragma unroll
        for (int i = 0; i < 4; i++) {
          int r0 = m0 + wm + i * 16 + fch * 4;
#pragma unroll
          for (int r = 0; r < 4; r++) {
            float v = fmaxf(acc[i][j][r] + bv, 0.f);
            if (r0 + r < rB) sA += v; else sB += v;
          }
        }
        sA += __shfl_down(sA, 32);
        sA += __shfl_down(sA, 16);
        sB += __shfl_down(sB, 32);
        sB += __shfl_down(sB, 16);
        if (l < 16) {
          atomicAdd(&pool[(size_t)b0 * D4_ + D2_ + c], sA);
          if (rw + 64 > rB) atomicAdd(&pool[(size_t)(b0 + 1) * D4_ + D2_ + c], sB);
        }
      }
    } else {
      float bv = biasM[c - 512];
#pragma unroll
      for (int i = 0; i < 4; i++) {
        int r0 = m0 + wm + i * 16 + fch * 4;
#pragma unroll
        for (int r = 0; r < 4; r++)
          msg[(size_t)(r0 + r) * NH_ + (c - 512)] = __float2bfloat16(acc[i][j][r] + bv);
      }
    }
  }
}

// ---------------- MFMA aggregation: A2 @ msg (per batch) ----------------
// MODE 0: write h1[:,512:] + pool atomics at offset 512; MODE 1: pool-only (poolOff).
template <int MODE>
__global__ __launch_bounds__(256) void mfma_agg(const __hip_bfloat16* __restrict__ A2bf,
                                                const __hip_bfloat16* __restrict__ msg,
                                                const float* __restrict__ deg,
                                                __hip_bfloat16* __restrict__ H,
                                                float* __restrict__ pool, int poolOff) {
  __shared__ short As[4096];
  __shared__ short Bs[4096];
  const int t = threadIdx.x;
  const int b = blockIdx.z;
  const int m0 = blockIdx.y * 128, o0 = blockIdx.x * 128;
  const int l = t & 63, w = t >> 6;
  const int wm = (w >> 1) * 64, wn = (w & 1) * 64;
  const int frow = l & 15, fch = l >> 4;
  const int srow = t >> 2, sslot = t & 3;
  const char* Abase = (const char*)(A2bf + ((size_t)b * NA_ + m0) * KA_);
  const __hip_bfloat16* Mb = msg + (size_t)b * N_ * NH_;
  const int bk = t >> 3;
  const int bf0 = (t & 7) * 16;
  char* AsB = (char*)As;
  char* BsB = (char*)Bs;
  f32x4 zero = {0.f, 0.f, 0.f, 0.f};
  f32x4 acc[4][4];
#pragma unroll
  for (int i = 0; i < 4; i++)
#pragma unroll
    for (int j = 0; j < 4; j++) acc[i][j] = zero;
  for (int kt = 0; kt < 7; kt++) {
#pragma unroll
    for (int u = 0; u < 2; u++) {
      int grow = u * 64 + srow;
      int gslot = sslot ^ (grow & 3);
      gll16(Abase + (size_t)grow * (KA_ * 2) + kt * 64 + gslot * 16, AsB + u * 4096 + t * 16);
    }
    int krow = kt * 32 + bk;
    const __hip_bfloat16* mp = Mb + (size_t)krow * NH_ + o0 + bf0;
    bf16x8 v0 = *(const bf16x8*)mp;
    bf16x8 v1 = *(const bf16x8*)(mp + 8);
#pragma unroll
    for (int e = 0; e < 8; e++) {
      int f0a = bf0 + e;
      int f1a = bf0 + 8 + e;
      *(short*)(BsB + f0a * 64 + (((bk >> 3) ^ (f0a & 3)) * 16) + (bk & 7) * 2) = v0[e];
      *(short*)(BsB + f1a * 64 + (((bk >> 3) ^ (f1a & 3)) * 16) + (bk & 7) * 2) = v1[e];
    }
    __syncthreads();
    bf16x8 af[4], bfv[4];
#pragma unroll
    for (int i = 0; i < 4; i++) {
      int ar = wm + i * 16 + frow;
      af[i] = *(const bf16x8*)(AsB + ar * 64 + ((fch ^ (ar & 3)) * 16));
      int br = wn + i * 16 + frow;
      bfv[i] = *(const bf16x8*)(BsB + br * 64 + ((fch ^ (br & 3)) * 16));
    }
#pragma unroll
    for (int i = 0; i < 4; i++)
#pragma unroll
      for (int j = 0; j < 4; j++)
        acc[i][j] = __builtin_amdgcn_mfma_f32_16x16x32_bf16(af[i], bfv[j], acc[i][j], 0, 0, 0);
    __syncthreads();
  }
#pragma unroll
  for (int j = 0; j < 4; j++) {
    int c = o0 + wn + j * 16 + frow;
    float s = 0.f;
#pragma unroll
    for (int i = 0; i < 4; i++) {
#pragma unroll
      for (int r = 0; r < 4; r++) {
        int n = m0 + wm + i * 16 + fch * 4 + r;
        if (n < N_) {
          float dv = deg[b * N_ + n];
          float v = fmaxf(acc[i][j][r] / dv, 0.f);
          if (MODE == 0)
            H[((size_t)b * N_ + n) * D2_ + NH_ + c] = __float2bfloat16(v);
          s += v;
        }
      }
    }
    s += __shfl_down(s, 32);
    s += __shfl_down(s, 16);
    if (l < 16) atomicAdd(&pool[(size_t)b * D4_ + poolOff + c], s);
  }
}

// ---------------- pooling: gf[:, :512] = mean h1[:, :512] ----------------
__global__ __launch_bounds__(256) void pool_h1ego(const __hip_bfloat16* __restrict__ h1,
                                                  float* __restrict__ gf) {
  int b = blockIdx.y;
  int c = blockIdx.x * 256 + threadIdx.x;  // 0..511
  const __hip_bfloat16* p = h1 + (size_t)b * N_ * D2_ + c;
  float s = 0.f;
  for (int n = 0; n < N_; n++) s += __bfloat162float(p[(size_t)n * D2_]);
  gf[(size_t)b * D4_ + c] = s * (1.f / N_);
}

// ---------------- gf[:, 512:2048] = pool / N ----------------
__global__ __launch_bounds__(256) void scale_pool(const float* __restrict__ pool,
                                                  float* __restrict__ gf) {
  int b = blockIdx.y;
  int c = NH_ + blockIdx.x * 256 + threadIdx.x;  // 512..2047
  gf[(size_t)b * D4_ + c] = pool[(size_t)b * D4_ + c] * (1.f / N_);
}

// ---------------- head GEMM: split-K f32, atomic accumulate ----------------
template <bool RELUX>
__global__ __launch_bounds__(256) void head_gemm(const float* __restrict__ Xg,
                                                 const float* __restrict__ W,
                                                 const float* __restrict__ bias,
                                                 float* __restrict__ Y,
                                                 int Rows, int Fin, int O, int kchunk) {
  __shared__ float Xs[16][68];
  __shared__ float Ws[16][68];
  int tx = threadIdx.x, ty = threadIdx.y;
  int tid = ty * 16 + tx;
  int lr = tid >> 2;
  int lk = (tid & 3) * 4;
  int rbase = blockIdx.y * 64;
  int o0 = blockIdx.x * 64;
  int k0base = blockIdx.z * kchunk;
  float acc[4][4] = {};
  for (int k0 = k0base; k0 < k0base + kchunk; k0 += 16) {
    float4 xv = make_float4(0.f, 0.f, 0.f, 0.f);
    if (rbase + lr < Rows) xv = *(const float4*)&Xg[(size_t)(rbase + lr) * Fin + k0 + lk];
    if (RELUX) {
      xv.x = fmaxf(xv.x, 0.f); xv.y = fmaxf(xv.y, 0.f);
      xv.z = fmaxf(xv.z, 0.f); xv.w = fmaxf(xv.w, 0.f);
    }
    Xs[lk][lr] = xv.x; Xs[lk + 1][lr] = xv.y; Xs[lk + 2][lr] = xv.z; Xs[lk + 3][lr] = xv.w;
    float4 wv = make_float4(0.f, 0.f, 0.f, 0.f);
    if (o0 + lr < O) wv = *(const float4*)&W[(size_t)(o0 + lr) * Fin + k0 + lk];
    Ws[lk][lr] = wv.x; Ws[lk + 1][lr] = wv.y; Ws[lk + 2][lr] = wv.z; Ws[lk + 3][lr] = wv.w;
    __syncthreads();
#pragma unroll
    for (int k = 0; k < 16; k++) {
      float4 a = *(const float4*)&Xs[k][ty * 4];
      float4 bb = *(const float4*)&Ws[k][tx * 4];
      float av[4] = {a.x, a.y, a.z, a.w};
      float bv[4] = {bb.x, bb.y, bb.z, bb.w};
#pragma unroll
      for (int i = 0; i < 4; i++)
#pragma unroll
        for (int j = 0; j < 4; j++) acc[i][j] = fmaf(av[i], bv[j], acc[i][j]);
    }
    __syncthreads();
  }
#pragma unroll
  for (int i = 0; i < 4; i++) {
    int rrow = rbase + ty * 4 + i;
    if (rrow >= Rows) continue;
#pragma unroll
    for (int j = 0; j < 4; j++) {
      int c = o0 + tx * 4 + j;
      if (c >= O) continue;
      float vv = acc[i][j] + ((blockIdx.z == 0) ? bias[c] : 0.f);
      atomicAdd(&Y[(size_t)rrow * O + c], vv);
    }
  }
}

// ---------------- host launch ----------------
extern "C" void kernel_launch(void* const* d_in, const int* in_sizes, int n_in,
                              void* d_out, int out_size, void* d_ws, size_t ws_size,
                              hipStream_t stream) {
  const float* Fet  = (const float*)d_in[0];
  const float* w1_0 = (const float*)d_in[1];
  const float* b1_0 = (const float*)d_in[2];
  const float* w2_0 = (const float*)d_in[3];
  const float* b2_0 = (const float*)d_in[4];
  const float* w1_1 = (const float*)d_in[5];
  const float* b1_1 = (const float*)d_in[6];
  const float* w2_1 = (const float*)d_in[7];
  const float* b2_1 = (const float*)d_in[8];
  const float* fc1_w = (const float*)d_in[9];
  const float* fc1_b = (const float*)d_in[10];
  const float* fc2_w = (const float*)d_in[11];
  const float* fc2_b = (const float*)d_in[12];

  char* ws = (char*)d_ws;
  float* g0 = (float*)(ws + OFF_DIST0);
  float* g1 = (float*)(ws + OFF_DIST1);
  __hip_bfloat16* A2bf = (__hip_bfloat16*)(ws + OFF_DIST0);  // overlay (g0 dead after topk)
  float* sq = (float*)(ws + OFF_SQ);
  unsigned long long* Abits = (unsigned long long*)(ws + OFF_ABITS);
  float* deg = (float*)(ws + OFF_DEG);
  __hip_bfloat16* Fet_hi = (__hip_bfloat16*)(ws + OFF_FETHI);
  __hip_bfloat16* Fet_lo = (__hip_bfloat16*)(ws + OFF_FETLO);  // overlay msg/h1 head
  __hip_bfloat16* msg = (__hip_bfloat16*)(ws + OFF_MSG);
  __hip_bfloat16* h1 = (__hip_bfloat16*)(ws + OFF_H1);
  float* pool = (float*)(ws + OFF_POOL);
  float* p = (float*)(ws + OFF_P);
  __hip_bfloat16* wc1 = (__hip_bfloat16*)(ws + OFF_WC1);
  __hip_bfloat16* wc2 = (__hip_bfloat16*)(ws + OFF_WC2);

  float* out = (float*)d_out;          // [B, NC]
  float* gf = out + (size_t)B_ * NC_;  // [B, D4]

  hipMemsetAsync(Abits, 0, (size_t)ROWS_ * 4 * sizeof(unsigned long long), stream);
  hipMemsetAsync(pool, 0, (size_t)B_ * D4_ * sizeof(float), stream);
  hipMemsetAsync(p, 0, (size_t)B_ * NH_ * sizeof(float), stream);
  hipMemsetAsync(out, 0, (size_t)B_ * NC_ * sizeof(float), stream);

  // casts: features hi/lo+sq fused; weights into concat buffers
  cast_hilo_sq<<<ROWS_ / 4, 256, 0, stream>>>(Fet, Fet_hi, Fet_lo, sq);
  cast_bf16_kernel<<<384, 256, 0, stream>>>(w1_0, wc1, NH_ * F_ / 4);
  cast_bf16_kernel<<<384, 256, 0, stream>>>(w2_0, wc1 + (size_t)NH_ * F_, NH_ * F_ / 4);
  cast_bf16_kernel<<<512, 256, 0, stream>>>(w1_1, wc2, NH_ * D2_ / 4);
  cast_bf16_kernel<<<512, 256, 0, stream>>>(w2_1, wc2 + (size_t)NH_ * D2_, NH_ * D2_ / 4);

  // graph construction
  mfma_gram<<<dim3(3, 2, B_), 256, 0, stream>>>(Fet_hi, Fet_lo, g0, g1);
  topk_kernel<<<ROWS_ / 4, 256, 0, stream>>>(g0, g1, sq, Abits);
  a2_kernel<<<ROWS_ / 4, 256, 0, stream>>>(Abits, A2bf, deg);

  // layer 1 (Fet_lo dead from here; msg/h1 overwrite it)
  mfma_fused<1><<<dim3(8, 197), 256, 0, stream>>>(
      Fet_hi, wc1, b1_0, b2_0, h1, msg, nullptr, F_);
  mfma_agg<0><<<dim3(4, 2, B_), 256, 0, stream>>>(A2bf, msg, deg, h1, pool, NH_);

  // layer 2 (ego2 pooled in-epilogue, msg2 -> agg2 pooled)
  mfma_fused<2><<<dim3(8, 197), 256, 0, stream>>>(
      h1, wc2, b1_1, b2_1, nullptr, msg, pool, D2_);
  mfma_agg<1><<<dim3(4, 2, B_), 256, 0, stream>>>(A2bf, msg, deg, nullptr, pool, D2_ + NH_);

  // pooling -> graph_features
  pool_h1ego<<<dim3(2, B_), 256, 0, stream>>>(h1, gf);
  scale_pool<<<dim3(6, B_), 256, 0, stream>>>(pool, gf);

  // head (f32, split-K + atomics; fc1 relu folded into fc2 X-load)
  head_gemm<false><<<dim3(8, 2, 16), dim3(16, 16), 0, stream>>>(
      gf, fc1_w, fc1_b, p, B_, D4_, NH_, 128);
  head_gemm<true><<<dim3(16, 2, 8), dim3(16, 16), 0, stream>>>(
      p, fc2_w, fc2_b, out, B_, NH_, NC_, 64);
}

// Round 6
// 525.175 us; speedup vs baseline: 4.1144x; 1.0198x over previous
//
#include <hip/hip_runtime.h>
#include <hip/hip_bf16.h>
#include <math.h>

typedef __attribute__((ext_vector_type(8))) short bf16x8;
typedef __attribute__((ext_vector_type(4))) float f32x4;

#define B_ 128
#define N_ 197
#define F_ 768
#define NH_ 512
#define D2_ 1024
#define D4_ 2048
#define NC_ 1000
#define ROWS_ (B_ * N_)   // 25216 = 197 * 128 (exact 128-row tiling)
#define KA_ 224           // agg K padded (197 -> 224 = 7*32)
#define NA_ 256           // agg node rows padded (197 -> 256 = 2*128)

// workspace offsets (bytes).
// g0 (f32) overlays A2bf: g0 dead after topk.
// Fet_lo overlays msgT + h1 head: lo dead after mfma_gram; every msgT byte is a
// written Fet_lo bf16 (finite) so the A2-zero-padded K columns can't produce NaN.
#define OFF_DIST0  0ull
#define OFF_SQ     19871232ull
#define OFF_ABITS  19972352ull
#define OFF_DEG    20779520ull
#define OFF_FETHI  20880640ull    // [25280][768] bf16 (64 slack rows for gram over-read)
#define OFF_MSGT   59710720ull    // [128][512][224] bf16 = 29,360,128
#define OFF_H1     89070848ull    // [25216][1024] bf16
#define OFF_FETLO  OFF_MSGT       // overlay: [25216][768] bf16, ends 98,442,496
#define OFF_POOL   140844288ull   // [128][2048] f32
#define OFF_P      141892864ull   // [128][512] f32
#define OFF_WC1    142155008ull   // [1024][768] bf16: rows 0-511=w1_0(ego), 512-1023=w2_0(msg)
#define OFF_WC2    143727872ull   // [1024][1024] bf16
#define OFF_DIST1  145825024ull   // [B][N][N] f32, end 165,696,256

__device__ __forceinline__ void gll16(const void* g, void* l) {
  __builtin_amdgcn_global_load_lds((const __attribute__((address_space(1))) void*)g,
                                   (__attribute__((address_space(3))) void*)l, 16, 0, 0);
}

// LDS slot swizzle: logical (row, slot) lives at phys slot (slot ^ slot_of(row)).
// (r&3)^((r>>2)&3) spreads each 16-row group so each 4-bank group is hit exactly
// twice per quarter-wave (2-way = free) instead of 4-way.
__device__ __forceinline__ int slot_of(int row) { return (row & 3) ^ ((row >> 2) & 3); }

// ---------------- f32 -> bf16 cast (weights) ----------------
__global__ __launch_bounds__(256) void cast_bf16_kernel(const float* __restrict__ src,
                                                        __hip_bfloat16* __restrict__ dst,
                                                        int n4) {
  int i = blockIdx.x * 256 + threadIdx.x;
  if (i >= n4) return;
  float4 v = ((const float4*)src)[i];
  union { __hip_bfloat16 h[4]; uint2 u; } pk;
  pk.h[0] = __float2bfloat16(v.x);
  pk.h[1] = __float2bfloat16(v.y);
  pk.h[2] = __float2bfloat16(v.z);
  pk.h[3] = __float2bfloat16(v.w);
  ((uint2*)dst)[i] = pk.u;
}

// ---------------- f32 -> bf16 hi/lo split + squared norms (one Fet read) ----------------
__global__ __launch_bounds__(256) void cast_hilo_sq(const float* __restrict__ X,
                                                    __hip_bfloat16* __restrict__ hi,
                                                    __hip_bfloat16* __restrict__ lo,
                                                    float* __restrict__ sq) {
  int row = blockIdx.x * 4 + (threadIdx.x >> 6);
  int lane = threadIdx.x & 63;
  const float4* xp = (const float4*)(X + (size_t)row * F_);
  uint2* hp = (uint2*)(hi + (size_t)row * F_);
  uint2* lp = (uint2*)(lo + (size_t)row * F_);
  float s = 0.f;
#pragma unroll
  for (int i = 0; i < 3; i++) {  // 768/4 = 192 = 3*64
    float4 v = xp[lane + i * 64];
    s += v.x * v.x + v.y * v.y + v.z * v.z + v.w * v.w;
    float f[4] = {v.x, v.y, v.z, v.w};
    union { __hip_bfloat16 h[4]; uint2 u; } ph, pl;
#pragma unroll
    for (int k = 0; k < 4; k++) {
      __hip_bfloat16 h = __float2bfloat16(f[k]);
      ph.h[k] = h;
      pl.h[k] = __float2bfloat16(f[k] - __bfloat162float(h));
    }
    hp[lane + i * 64] = ph.u;
    lp[lane + i * 64] = pl.u;
  }
#pragma unroll
  for (int o = 32; o > 0; o >>= 1) s += __shfl_down(s, o);
  if (lane == 0) sq[row] = s;
}

// ---------------- pairwise Gram via MFMA, split-bf16 3-pass, K-split x2 ----------------
// 1D grid 768 = 128 b x {3 bx} x {2 khalf}; XCD swizzle clusters same-b blocks.
__global__ __launch_bounds__(256) void mfma_gram(const __hip_bfloat16* __restrict__ Xhi,
                                                 const __hip_bfloat16* __restrict__ Xlo,
                                                 float* __restrict__ g0,
                                                 float* __restrict__ g1) {
  __shared__ short AsH[4096];
  __shared__ short BsH[4096];
  __shared__ short AsL[4096];
  __shared__ short BsL[4096];
  const int t = threadIdx.x;
  const int wgid = blockIdx.x;
  const int L = (wgid & 7) * 96 + (wgid >> 3);
  const int b = L / 6;
  const int rbx = L - b * 6;
  const int bx = rbx % 3;
  const int khalf = rbx / 3;
  const int m0 = (bx == 0) ? 0 : 128;
  const int o0 = (bx == 2) ? 128 : 0;
  const bool mirror = (bx == 1);
  const int l = t & 63, w = t >> 6;
  const int wm = (w >> 1) * 64, wn = (w & 1) * 64;
  const int frow = l & 15, fch = l >> 4;
  const int srow = t >> 2, sslot = t & 3;
  const size_t rowbase = (size_t)b * N_;
  const char* AhiB = (const char*)(Xhi + (rowbase + m0) * F_);
  const char* AloB = (const char*)(Xlo + (rowbase + m0) * F_);
  const char* BhiB = (const char*)(Xhi + (rowbase + o0) * F_);
  const char* BloB = (const char*)(Xlo + (rowbase + o0) * F_);
  const int rb = F_ * 2;
  char* AsHB = (char*)AsH;
  char* BsHB = (char*)BsH;
  char* AsLB = (char*)AsL;
  char* BsLB = (char*)BsL;
  float* go = khalf ? g1 : g0;
  f32x4 zero = {0.f, 0.f, 0.f, 0.f};
  f32x4 acc[4][4];
#pragma unroll
  for (int i = 0; i < 4; i++)
#pragma unroll
    for (int j = 0; j < 4; j++) acc[i][j] = zero;
  const int kt0 = khalf * 12;
  for (int kt = kt0; kt < kt0 + 12; kt++) {
    const int kb = kt * 64;
#pragma unroll
    for (int u = 0; u < 2; u++) {
      int grow = u * 64 + srow;
      int gslot = sslot ^ slot_of(grow);
      size_t goff = (size_t)grow * rb + kb + gslot * 16;
      gll16(AhiB + goff, AsHB + u * 4096 + t * 16);
      gll16(BhiB + goff, BsHB + u * 4096 + t * 16);
      gll16(AloB + goff, AsLB + u * 4096 + t * 16);
      gll16(BloB + goff, BsLB + u * 4096 + t * 16);
    }
    __syncthreads();
    bf16x8 ah[4], al[4], bh[4], bl[4];
#pragma unroll
    for (int i = 0; i < 4; i++) {
      int ar = wm + i * 16 + frow;
      int aoff = ar * 64 + ((fch ^ slot_of(ar)) * 16);
      ah[i] = *(const bf16x8*)(AsHB + aoff);
      al[i] = *(const bf16x8*)(AsLB + aoff);
      int br = wn + i * 16 + frow;
      int boff = br * 64 + ((fch ^ slot_of(br)) * 16);
      bh[i] = *(const bf16x8*)(BsHB + boff);
      bl[i] = *(const bf16x8*)(BsLB + boff);
    }
#pragma unroll
    for (int i = 0; i < 4; i++)
#pragma unroll
      for (int j = 0; j < 4; j++) {
        acc[i][j] = __builtin_amdgcn_mfma_f32_16x16x32_bf16(ah[i], bh[j], acc[i][j], 0, 0, 0);
        acc[i][j] = __builtin_amdgcn_mfma_f32_16x16x32_bf16(ah[i], bl[j], acc[i][j], 0, 0, 0);
        acc[i][j] = __builtin_amdgcn_mfma_f32_16x16x32_bf16(al[i], bh[j], acc[i][j], 0, 0, 0);
      }
    __syncthreads();
  }
#pragma unroll
  for (int j = 0; j < 4; j++) {
    int m = o0 + wn + j * 16 + frow;
    if (m >= N_) continue;
#pragma unroll
    for (int i = 0; i < 4; i++) {
      int nb = m0 + wm + i * 16 + fch * 4;
#pragma unroll
      for (int r = 0; r < 4; r++) {
        int n = nb + r;
        if (n >= N_) continue;
        float g = acc[i][j][r];
        go[(rowbase + n) * N_ + m] = g;
        if (mirror) go[(rowbase + m) * N_ + n] = g;
      }
    }
  }
}

// ---------------- top-4 per row -> symmetric adjacency bitmask ----------------
__global__ __launch_bounds__(256) void topk_kernel(const float* __restrict__ g0,
                                                   const float* __restrict__ g1,
                                                   const float* __restrict__ sq,
                                                   unsigned long long* __restrict__ Abits) {
  int row = blockIdx.x * 4 + (threadIdx.x >> 6);
  int lane = threadIdx.x & 63;
  int b = row / N_, n = row - b * N_;
  const float* g0r = g0 + (size_t)row * N_;
  const float* g1r = g1 + (size_t)row * N_;
  const float* sqb = sq + (size_t)b * N_;
  float v[4];
  int vi[4];
#pragma unroll
  for (int i = 0; i < 4; i++) {
    int m = lane + i * 64;
    bool ok = (m < N_) && (m != n);
    v[i] = ok ? (sqb[m] - 2.f * (g0r[m] + g1r[m])) : INFINITY;
    vi[i] = ok ? m : 0x3fffffff;
  }
  unsigned long long nbr[4] = {0ull, 0ull, 0ull, 0ull};
#pragma unroll
  for (int t = 0; t < 4; t++) {
    float bv = v[0];
    int bi = vi[0];
#pragma unroll
    for (int i = 1; i < 4; i++)
      if (v[i] < bv || (v[i] == bv && vi[i] < bi)) { bv = v[i]; bi = vi[i]; }
#pragma unroll
    for (int o = 1; o < 64; o <<= 1) {
      float ov = __shfl_xor(bv, o);
      int oi = __shfl_xor(bi, o);
      if (ov < bv || (ov == bv && oi < bi)) { bv = ov; bi = oi; }
    }
#pragma unroll
    for (int i = 0; i < 4; i++)
      if (vi[i] == bi) { v[i] = INFINITY; vi[i] = 0x3fffffff; }
    if (lane == 0) {
      nbr[bi >> 6] |= 1ull << (bi & 63);
      atomicOr(&Abits[((size_t)b * N_ + bi) * 4 + (n >> 6)], 1ull << (n & 63));
    }
  }
  if (lane == 0) {
#pragma unroll
    for (int w = 0; w < 4; w++)
      if (nbr[w]) atomicOr(&Abits[(size_t)row * 4 + w], nbr[w]);
  }
}

// ---------------- 2-hop adjacency -> bf16 [B][256][224] + deg ----------------
__global__ __launch_bounds__(256) void a2_kernel(const unsigned long long* __restrict__ Abits,
                                                 __hip_bfloat16* __restrict__ A2bf,
                                                 float* __restrict__ deg) {
  int row = blockIdx.x * 4 + (threadIdx.x >> 6);
  int lane = threadIdx.x & 63;
  int b = row / N_, n = row - b * N_;
  const unsigned long long* arow = Abits + (size_t)row * 4;
  const unsigned long long* base = Abits + (size_t)b * N_ * 4;
  unsigned long long r0 = 0, r1 = 0, r2 = 0, r3 = 0;
#pragma unroll
  for (int w = 0; w < 4; w++) {
    if ((arow[w] >> lane) & 1ull) {
      const unsigned long long* mr = base + (size_t)(w * 64 + lane) * 4;
      r0 |= mr[0]; r1 |= mr[1]; r2 |= mr[2]; r3 |= mr[3];
    }
  }
#pragma unroll
  for (int o = 1; o < 64; o <<= 1) {
    r0 |= __shfl_xor(r0, o);
    r1 |= __shfl_xor(r1, o);
    r2 |= __shfl_xor(r2, o);
    r3 |= __shfl_xor(r3, o);
  }
  unsigned long long rr[4] = {r0, r1, r2, r3};
  rr[n >> 6] &= ~(1ull << (n & 63));
  __hip_bfloat16* out = A2bf + ((size_t)b * NA_ + n) * KA_;
  const __hip_bfloat16 one = __float2bfloat16(1.f);
  const __hip_bfloat16 zer = __float2bfloat16(0.f);
#pragma unroll
  for (int i = 0; i < 4; i++) {
    int m = lane + i * 64;
    if (m < KA_)
      out[m] = (m < N_ && ((rr[m >> 6] >> (m & 63)) & 1ull)) ? one : zer;
  }
  if (lane == 0) {
    int dg = __popcll(rr[0]) + __popcll(rr[1]) + __popcll(rr[2]) + __popcll(rr[3]);
    deg[row] = (float)(dg > 0 ? dg : 1);
  }
}

// ---------------- merged ego+msg GEMM over concat weights [1024][K] ----------------
// 1D grid 1576, XCD-swizzled so all 8 o-tiles of an m-tile share one XCD's L2.
// o-tiles 0-3 (ego): normal mfma -> h1 / pool. o-tiles 4-7 (msg): SWAPPED mfma
// (D = W·X^T) -> msgT[b][512][224] directly (saves the agg-side transpose).
template <int MODE>
__global__ __launch_bounds__(256) void mfma_fused(const __hip_bfloat16* __restrict__ X,
                                                  const __hip_bfloat16* __restrict__ Wcat,
                                                  const float* __restrict__ biasE,
                                                  const float* __restrict__ biasM,
                                                  __hip_bfloat16* __restrict__ h1,
                                                  __hip_bfloat16* __restrict__ msgT,
                                                  float* __restrict__ pool,
                                                  int K) {
  __shared__ short As[4096];
  __shared__ short Bs[4096];
  const int t = threadIdx.x;
  const int wgid = blockIdx.x;
  const int L = (wgid & 7) * 197 + (wgid >> 3);
  const int m0 = (L >> 3) * 128, o0 = (L & 7) * 128;
  const int l = t & 63, w = t >> 6;
  const int wm = (w >> 1) * 64, wn = (w & 1) * 64;
  const int frow = l & 15, fch = l >> 4;
  const int srow = t >> 2, sslot = t & 3;
  const char* Abase = (const char*)(X + (size_t)m0 * K);
  const char* Bbase = (const char*)(Wcat + (size_t)o0 * K);
  const int rb = K * 2;
  char* AsB = (char*)As;
  char* BsB = (char*)Bs;
  const bool swap = (o0 >= 512);
  f32x4 zero = {0.f, 0.f, 0.f, 0.f};
  f32x4 acc[4][4];
#pragma unroll
  for (int i = 0; i < 4; i++)
#pragma unroll
    for (int j = 0; j < 4; j++) acc[i][j] = zero;
  const int KT = K >> 5;
  for (int kt = 0; kt < KT; kt++) {
    const int kb = kt * 64;
#pragma unroll
    for (int u = 0; u < 2; u++) {
      int grow = u * 64 + srow;
      int gslot = sslot ^ slot_of(grow);
      gll16(Abase + (size_t)grow * rb + kb + gslot * 16, AsB + u * 4096 + t * 16);
      gll16(Bbase + (size_t)grow * rb + kb + gslot * 16, BsB + u * 4096 + t * 16);
    }
    __syncthreads();
    bf16x8 af[4], bfv[4];
#pragma unroll
    for (int i = 0; i < 4; i++) {
      int ar = wm + i * 16 + frow;
      af[i] = *(const bf16x8*)(AsB + ar * 64 + ((fch ^ slot_of(ar)) * 16));
      int br = wn + i * 16 + frow;
      bfv[i] = *(const bf16x8*)(BsB + br * 64 + ((fch ^ slot_of(br)) * 16));
    }
    if (!swap) {
#pragma unroll
      for (int i = 0; i < 4; i++)
#pragma unroll
        for (int j = 0; j < 4; j++)
          acc[i][j] = __builtin_amdgcn_mfma_f32_16x16x32_bf16(af[i], bfv[j], acc[i][j], 0, 0, 0);
    } else {
#pragma unroll
      for (int i = 0; i < 4; i++)
#pragma unroll
        for (int j = 0; j < 4; j++)
          acc[i][j] = __builtin_amdgcn_mfma_f32_16x16x32_bf16(bfv[j], af[i], acc[i][j], 0, 0, 0);
    }
    __syncthreads();
  }
  if (!swap) {  // ego half: D rows = X rows, cols = weight rows (c)
#pragma unroll
    for (int j = 0; j < 4; j++) {
      int c = o0 + wn + j * 16 + frow;
      float bv = biasE[c];
      if (MODE == 1) {
#pragma unroll
        for (int i = 0; i < 4; i++) {
          int r0 = m0 + wm + i * 16 + fch * 4;
#pragma unroll
          for (int r = 0; r < 4; r++) {
            float v = fmaxf(acc[i][j][r] + bv, 0.f);
            h1[(size_t)(r0 + r) * D2_ + c] = __float2bfloat16(v);
          }
        }
      } else {
        int rw = m0 + wm;
        int b0 = rw / N_;
        int rB = (b0 + 1) * N_;
        float sA = 0.f, sB = 0.f;
#pragma unroll
        for (int i = 0; i < 4; i++) {
          int r0 = m0 + wm + i * 16 + fch * 4;
#pragma unroll
          for (int r = 0; r < 4; r++) {
            float v = fmaxf(acc[i][j][r] + bv, 0.f);
            if (r0 + r < rB) sA += v; else sB += v;
          }
        }
        sA += __shfl_down(sA, 32);
        sA += __shfl_down(sA, 16);
        sB += __shfl_down(sB, 32);
        sB += __shfl_down(sB, 16);
        if (l < 16) {
          atomicAdd(&pool[(size_t)b0 * D4_ + D2_ + c], sA);
          if (rw + 64 > rB) atomicAdd(&pool[(size_t)(b0 + 1) * D4_ + D2_ + c], sB);
        }
      }
    }
  } else {  // msg half, swapped: D rows = weight rows (cm), cols = X rows
#pragma unroll
    for (int i = 0; i < 4; i++) {
      int xrow = m0 + wm + i * 16 + frow;
      int bb = xrow / N_;
      int rr = xrow - bb * N_;
      __hip_bfloat16* mt = msgT + (size_t)bb * NH_ * KA_ + rr;
#pragma unroll
      for (int j = 0; j < 4; j++) {
#pragma unroll
        for (int r = 0; r < 4; r++) {
          int cm = (o0 - 512) + wn + j * 16 + fch * 4 + r;
          float v = acc[i][j][r] + biasM[cm];
          mt[(size_t)cm * KA_] = __float2bfloat16(v);
        }
      }
    }
  }
}

// ---------------- MFMA aggregation: A2[b] @ msgT[b]^T, pure gll16 GEMM ----------------
// 1D grid 1024, XCD-swizzled so the 8 blocks of a batch share one XCD's L2.
// MODE 0: write h1[:,512:] + pool at offset 512; MODE 1: pool-only (poolOff).
template <int MODE>
__global__ __launch_bounds__(256) void mfma_agg(const __hip_bfloat16* __restrict__ A2bf,
                                                const __hip_bfloat16* __restrict__ msgT,
                                                const float* __restrict__ deg,
                                                __hip_bfloat16* __restrict__ H,
                                                float* __restrict__ pool, int poolOff) {
  __shared__ short As[4096];
  __shared__ short Bs[4096];
  const int t = threadIdx.x;
  const int wgid = blockIdx.x;
  const int L = (wgid & 7) * 128 + (wgid >> 3);
  const int b = L >> 3;
  const int o0 = ((L >> 1) & 3) * 128;
  const int m0 = (L & 1) * 128;
  const int l = t & 63, w = t >> 6;
  const int wm = (w >> 1) * 64, wn = (w & 1) * 64;
  const int frow = l & 15, fch = l >> 4;
  const int srow = t >> 2, sslot = t & 3;
  const char* Abase = (const char*)(A2bf + ((size_t)b * NA_ + m0) * KA_);
  const char* Bbase = (const char*)(msgT + ((size_t)b * NH_ + o0) * KA_);
  const int rb = KA_ * 2;
  char* AsB = (char*)As;
  char* BsB = (char*)Bs;
  f32x4 zero = {0.f, 0.f, 0.f, 0.f};
  f32x4 acc[4][4];
#pragma unroll
  for (int i = 0; i < 4; i++)
#pragma unroll
    for (int j = 0; j < 4; j++) acc[i][j] = zero;
  for (int kt = 0; kt < 7; kt++) {
    const int kb = kt * 64;
#pragma unroll
    for (int u = 0; u < 2; u++) {
      int grow = u * 64 + srow;
      int gslot = sslot ^ slot_of(grow);
      gll16(Abase + (size_t)grow * rb + kb + gslot * 16, AsB + u * 4096 + t * 16);
      gll16(Bbase + (size_t)grow * rb + kb + gslot * 16, BsB + u * 4096 + t * 16);
    }
    __syncthreads();
    bf16x8 af[4], bfv[4];
#pragma unroll
    for (int i = 0; i < 4; i++) {
      int ar = wm + i * 16 + frow;
      af[i] = *(const bf16x8*)(AsB + ar * 64 + ((fch ^ slot_of(ar)) * 16));
      int br = wn + i * 16 + frow;
      bfv[i] = *(const bf16x8*)(BsB + br * 64 + ((fch ^ slot_of(br)) * 16));
    }
#pragma unroll
    for (int i = 0; i < 4; i++)
#pragma unroll
      for (int j = 0; j < 4; j++)
        acc[i][j] = __builtin_amdgcn_mfma_f32_16x16x32_bf16(af[i], bfv[j], acc[i][j], 0, 0, 0);
    __syncthreads();
  }
#pragma unroll
  for (int j = 0; j < 4; j++) {
    int c = o0 + wn + j * 16 + frow;
    float s = 0.f;
#pragma unroll
    for (int i = 0; i < 4; i++) {
#pragma unroll
      for (int r = 0; r < 4; r++) {
        int n = m0 + wm + i * 16 + fch * 4 + r;
        if (n < N_) {
          float dv = deg[b * N_ + n];
          float v = fmaxf(acc[i][j][r] / dv, 0.f);
          if (MODE == 0)
            H[((size_t)b * N_ + n) * D2_ + NH_ + c] = __float2bfloat16(v);
          s += v;
        }
      }
    }
    s += __shfl_down(s, 32);
    s += __shfl_down(s, 16);
    if (l < 16) atomicAdd(&pool[(size_t)b * D4_ + poolOff + c], s);
  }
}

// ---------------- pooling: gf[:, :512] = mean h1[:, :512] ----------------
__global__ __launch_bounds__(256) void pool_h1ego(const __hip_bfloat16* __restrict__ h1,
                                                  float* __restrict__ gf) {
  int b = blockIdx.y;
  int c = blockIdx.x * 256 + threadIdx.x;  // 0..511
  const __hip_bfloat16* p = h1 + (size_t)b * N_ * D2_ + c;
  float s = 0.f;
  for (int n = 0; n < N_; n++) s += __bfloat162float(p[(size_t)n * D2_]);
  gf[(size_t)b * D4_ + c] = s * (1.f / N_);
}

// ---------------- gf[:, 512:2048] = pool / N ----------------
__global__ __launch_bounds__(256) void scale_pool(const float* __restrict__ pool,
                                                  float* __restrict__ gf) {
  int b = blockIdx.y;
  int c = NH_ + blockIdx.x * 256 + threadIdx.x;  // 512..2047
  gf[(size_t)b * D4_ + c] = pool[(size_t)b * D4_ + c] * (1.f / N_);
}

// ---------------- head GEMM: split-K f32, atomic accumulate ----------------
template <bool RELUX>
__global__ __launch_bounds__(256) void head_gemm(const float* __restrict__ Xg,
                                                 const float* __restrict__ W,
                                                 const float* __restrict__ bias,
                                                 float* __restrict__ Y,
                                                 int Rows, int Fin, int O, int kchunk) {
  __shared__ float Xs[16][68];
  __shared__ float Ws[16][68];
  int tx = threadIdx.x, ty = threadIdx.y;
  int tid = ty * 16 + tx;
  int lr = tid >> 2;
  int lk = (tid & 3) * 4;
  int rbase = blockIdx.y * 64;
  int o0 = blockIdx.x * 64;
  int k0base = blockIdx.z * kchunk;
  float acc[4][4] = {};
  for (int k0 = k0base; k0 < k0base + kchunk; k0 += 16) {
    float4 xv = make_float4(0.f, 0.f, 0.f, 0.f);
    if (rbase + lr < Rows) xv = *(const float4*)&Xg[(size_t)(rbase + lr) * Fin + k0 + lk];
    if (RELUX) {
      xv.x = fmaxf(xv.x, 0.f); xv.y = fmaxf(xv.y, 0.f);
      xv.z = fmaxf(xv.z, 0.f); xv.w = fmaxf(xv.w, 0.f);
    }
    Xs[lk][lr] = xv.x; Xs[lk + 1][lr] = xv.y; Xs[lk + 2][lr] = xv.z; Xs[lk + 3][lr] = xv.w;
    float4 wv = make_float4(0.f, 0.f, 0.f, 0.f);
    if (o0 + lr < O) wv = *(const float4*)&W[(size_t)(o0 + lr) * Fin + k0 + lk];
    Ws[lk][lr] = wv.x; Ws[lk + 1][lr] = wv.y; Ws[lk + 2][lr] = wv.z; Ws[lk + 3][lr] = wv.w;
    __syncthreads();
#pragma unroll
    for (int k = 0; k < 16; k++) {
      float4 a = *(const float4*)&Xs[k][ty * 4];
      float4 bb = *(const float4*)&Ws[k][tx * 4];
      float av[4] = {a.x, a.y, a.z, a.w};
      float bv[4] = {bb.x, bb.y, bb.z, bb.w};
#pragma unroll
      for (int i = 0; i < 4; i++)
#pragma unroll
        for (int j = 0; j < 4; j++) acc[i][j] = fmaf(av[i], bv[j], acc[i][j]);
    }
    __syncthreads();
  }
#pragma unroll
  for (int i = 0; i < 4; i++) {
    int rrow = rbase + ty * 4 + i;
    if (rrow >= Rows) continue;
#pragma unroll
    for (int j = 0; j < 4; j++) {
      int c = o0 + tx * 4 + j;
      if (c >= O) continue;
      float vv = acc[i][j] + ((blockIdx.z == 0) ? bias[c] : 0.f);
      atomicAdd(&Y[(size_t)rrow * O + c], vv);
    }
  }
}

// ---------------- host launch ----------------
extern "C" void kernel_launch(void* const* d_in, const int* in_sizes, int n_in,
                              void* d_out, int out_size, void* d_ws, size_t ws_size,
                              hipStream_t stream) {
  const float* Fet  = (const float*)d_in[0];
  const float* w1_0 = (const float*)d_in[1];
  const float* b1_0 = (const float*)d_in[2];
  const float* w2_0 = (const float*)d_in[3];
  const float* b2_0 = (const float*)d_in[4];
  const float* w1_1 = (const float*)d_in[5];
  const float* b1_1 = (const float*)d_in[6];
  const float* w2_1 = (const float*)d_in[7];
  const float* b2_1 = (const float*)d_in[8];
  const float* fc1_w = (const float*)d_in[9];
  const float* fc1_b = (const float*)d_in[10];
  const float* fc2_w = (const float*)d_in[11];
  const float* fc2_b = (const float*)d_in[12];

  char* ws = (char*)d_ws;
  float* g0 = (float*)(ws + OFF_DIST0);
  float* g1 = (float*)(ws + OFF_DIST1);
  __hip_bfloat16* A2bf = (__hip_bfloat16*)(ws + OFF_DIST0);  // overlay (g0 dead after topk)
  float* sq = (float*)(ws + OFF_SQ);
  unsigned long long* Abits = (unsigned long long*)(ws + OFF_ABITS);
  float* deg = (float*)(ws + OFF_DEG);
  __hip_bfloat16* Fet_hi = (__hip_bfloat16*)(ws + OFF_FETHI);
  __hip_bfloat16* Fet_lo = (__hip_bfloat16*)(ws + OFF_FETLO);  // overlay msgT/h1 head
  __hip_bfloat16* msgT = (__hip_bfloat16*)(ws + OFF_MSGT);
  __hip_bfloat16* h1 = (__hip_bfloat16*)(ws + OFF_H1);
  float* pool = (float*)(ws + OFF_POOL);
  float* p = (float*)(ws + OFF_P);
  __hip_bfloat16* wc1 = (__hip_bfloat16*)(ws + OFF_WC1);
  __hip_bfloat16* wc2 = (__hip_bfloat16*)(ws + OFF_WC2);

  float* out = (float*)d_out;          // [B, NC]
  float* gf = out + (size_t)B_ * NC_;  // [B, D4]

  hipMemsetAsync(Abits, 0, (size_t)ROWS_ * 4 * sizeof(unsigned long long), stream);
  hipMemsetAsync(pool, 0, (size_t)B_ * D4_ * sizeof(float), stream);
  hipMemsetAsync(p, 0, (size_t)B_ * NH_ * sizeof(float), stream);
  hipMemsetAsync(out, 0, (size_t)B_ * NC_ * sizeof(float), stream);

  // casts: features hi/lo+sq fused; weights into concat buffers
  cast_hilo_sq<<<ROWS_ / 4, 256, 0, stream>>>(Fet, Fet_hi, Fet_lo, sq);
  cast_bf16_kernel<<<384, 256, 0, stream>>>(w1_0, wc1, NH_ * F_ / 4);
  cast_bf16_kernel<<<384, 256, 0, stream>>>(w2_0, wc1 + (size_t)NH_ * F_, NH_ * F_ / 4);
  cast_bf16_kernel<<<512, 256, 0, stream>>>(w1_1, wc2, NH_ * D2_ / 4);
  cast_bf16_kernel<<<512, 256, 0, stream>>>(w2_1, wc2 + (size_t)NH_ * D2_, NH_ * D2_ / 4);

  // graph construction
  mfma_gram<<<768, 256, 0, stream>>>(Fet_hi, Fet_lo, g0, g1);
  topk_kernel<<<ROWS_ / 4, 256, 0, stream>>>(g0, g1, sq, Abits);
  a2_kernel<<<ROWS_ / 4, 256, 0, stream>>>(Abits, A2bf, deg);

  // layer 1 (Fet_lo dead from here; msgT/h1 overwrite it)
  mfma_fused<1><<<1576, 256, 0, stream>>>(Fet_hi, wc1, b1_0, b2_0, h1, msgT, nullptr, F_);
  mfma_agg<0><<<1024, 256, 0, stream>>>(A2bf, msgT, deg, h1, pool, NH_);

  // layer 2 (ego2 pooled in-epilogue; msg2 -> msgT -> agg2 pooled)
  mfma_fused<2><<<1576, 256, 0, stream>>>(h1, wc2, b1_1, b2_1, nullptr, msgT, pool, D2_);
  mfma_agg<1><<<1024, 256, 0, stream>>>(A2bf, msgT, deg, nullptr, pool, D2_ + NH_);

  // pooling -> graph_features
  pool_h1ego<<<dim3(2, B_), 256, 0, stream>>>(h1, gf);
  scale_pool<<<dim3(6, B_), 256, 0, stream>>>(pool, gf);

  // head (f32, split-K + atomics; fc1 relu folded into fc2 X-load)
  head_gemm<false><<<dim3(8, 2, 16), dim3(16, 16), 0, stream>>>(
      gf, fc1_w, fc1_b, p, B_, D4_, NH_, 128);
  head_gemm<true><<<dim3(16, 2, 8), dim3(16, 16), 0, stream>>>(
      p, fc2_w, fc2_b, out, B_, NH_, NC_, 64);
}

// Round 7
// 461.047 us; speedup vs baseline: 4.6867x; 1.1391x over previous
//
#include <hip/hip_runtime.h>
#include <hip/hip_bf16.h>
#include <math.h>

typedef __attribute__((ext_vector_type(8))) short bf16x8;
typedef __attribute__((ext_vector_type(4))) float f32x4;

#define B_ 128
#define N_ 197
#define F_ 768
#define NH_ 512
#define D2_ 1024
#define D4_ 2048
#define NC_ 1000
#define ROWS_ (B_ * N_)   // 25216 = 197 * 128
#define KA_ 224           // agg K padded per batch (197 -> 224), with per-batch phase pad b&3
#define NA_ 256           // agg node rows padded (197 -> 256)
#define LDG_ 200          // dist/gram leading dim (197 -> 200, mult of 4 for f32x4 stores)
#define MT_LD_ (B_ * KA_) // msgT row length: 128*224 = 28672

// workspace offsets (bytes).
// g0 overlays A2bf (g0 dead after topk). Fet_lo overlays msgT+h1 head (lo dead after gram).
#define OFF_G0     0ull           // [25216][200] f32 = 20,172,800
#define OFF_SQ     20172800ull    // [25216] f32
#define OFF_ABITS  20273664ull    // [25216][4] u64
#define OFF_DEG    21080576ull    // [25216] f32
#define OFF_FETHI  21181440ull    // [25280][768] bf16 (64 slack rows)
#define OFF_MSGT   60011520ull    // [512][28672] bf16 = 29,360,128
#define OFF_H1     89371648ull    // [25216][1024] bf16
#define OFF_FETLO  OFF_MSGT       // overlay, extends into h1 region (ok, h1 written later)
#define OFF_POOL   141014016ull   // [128][2048] f32
#define OFF_P      142062592ull   // [128][512] f32
#define OFF_WC1    142324736ull   // [1024][768] bf16
#define OFF_WC2    143897600ull   // [1024][1024] bf16
#define OFF_G1     145994752ull   // [25216][200] f32, end 166,167,552

__device__ __forceinline__ void gll16(const void* g, void* l) {
  __builtin_amdgcn_global_load_lds((const __attribute__((address_space(1))) void*)g,
                                   (__attribute__((address_space(3))) void*)l, 16, 0, 0);
}

__device__ __forceinline__ int slot_of(int row) { return (row & 3) ^ ((row >> 2) & 3); }

// ---------------- all four weight casts in one launch ----------------
__global__ __launch_bounds__(256) void cast_weights(const float* __restrict__ w10,
                                                    const float* __restrict__ w20,
                                                    const float* __restrict__ w11,
                                                    const float* __restrict__ w21,
                                                    __hip_bfloat16* __restrict__ wc1,
                                                    __hip_bfloat16* __restrict__ wc2) {
  const int S1 = NH_ * F_ / 4;   // 98304
  const int S2 = NH_ * D2_ / 4;  // 131072
  int i = blockIdx.x * 256 + threadIdx.x;
  const float* src;
  __hip_bfloat16* dst;
  int off;
  if (i < S1) { src = w10; dst = wc1; off = i; }
  else if (i < 2 * S1) { src = w20; dst = wc1 + (size_t)NH_ * F_; off = i - S1; }
  else if (i < 2 * S1 + S2) { src = w11; dst = wc2; off = i - 2 * S1; }
  else { src = w21; dst = wc2 + (size_t)NH_ * D2_; off = i - 2 * S1 - S2; }
  float4 v = ((const float4*)src)[off];
  union { __hip_bfloat16 h[4]; uint2 u; } pk;
  pk.h[0] = __float2bfloat16(v.x);
  pk.h[1] = __float2bfloat16(v.y);
  pk.h[2] = __float2bfloat16(v.z);
  pk.h[3] = __float2bfloat16(v.w);
  ((uint2*)dst)[off] = pk.u;
}

// ---------------- f32 -> bf16 hi/lo split + squared norms (one Fet read) ----------------
__global__ __launch_bounds__(256) void cast_hilo_sq(const float* __restrict__ X,
                                                    __hip_bfloat16* __restrict__ hi,
                                                    __hip_bfloat16* __restrict__ lo,
                                                    float* __restrict__ sq) {
  int row = blockIdx.x * 4 + (threadIdx.x >> 6);
  int lane = threadIdx.x & 63;
  const float4* xp = (const float4*)(X + (size_t)row * F_);
  uint2* hp = (uint2*)(hi + (size_t)row * F_);
  uint2* lp = (uint2*)(lo + (size_t)row * F_);
  float s = 0.f;
#pragma unroll
  for (int i = 0; i < 3; i++) {
    float4 v = xp[lane + i * 64];
    s += v.x * v.x + v.y * v.y + v.z * v.z + v.w * v.w;
    float f[4] = {v.x, v.y, v.z, v.w};
    union { __hip_bfloat16 h[4]; uint2 u; } ph, pl;
#pragma unroll
    for (int k = 0; k < 4; k++) {
      __hip_bfloat16 h = __float2bfloat16(f[k]);
      ph.h[k] = h;
      pl.h[k] = __float2bfloat16(f[k] - __bfloat162float(h));
    }
    hp[lane + i * 64] = ph.u;
    lp[lane + i * 64] = pl.u;
  }
#pragma unroll
  for (int o = 32; o > 0; o >>= 1) s += __shfl_down(s, o);
  if (lane == 0) sq[row] = s;
}

// ---------------- pairwise Gram via MFMA, split-bf16 3-pass, K-split x2 ----------------
// SWAPPED mfma: D col(frow)=n, row(fch*4+r)=m -> f32x4 packed stores into [.,200] rows.
__global__ __launch_bounds__(256) void mfma_gram(const __hip_bfloat16* __restrict__ Xhi,
                                                 const __hip_bfloat16* __restrict__ Xlo,
                                                 float* __restrict__ g0,
                                                 float* __restrict__ g1) {
  __shared__ short AsH[4096];
  __shared__ short BsH[4096];
  __shared__ short AsL[4096];
  __shared__ short BsL[4096];
  const int t = threadIdx.x;
  const int wgid = blockIdx.x;
  const int L = (wgid & 7) * 96 + (wgid >> 3);
  const int b = L / 6;
  const int rbx = L - b * 6;
  const int bx = rbx % 3;
  const int khalf = rbx / 3;
  const int m0 = (bx == 0) ? 0 : 128;
  const int o0 = (bx == 2) ? 128 : 0;
  const bool mirror = (bx == 1);
  const int l = t & 63, w = t >> 6;
  const int wm = (w >> 1) * 64, wn = (w & 1) * 64;
  const int frow = l & 15, fch = l >> 4;
  const int srow = t >> 2, sslot = t & 3;
  const size_t rowbase = (size_t)b * N_;
  const char* AhiB = (const char*)(Xhi + (rowbase + m0) * F_);
  const char* AloB = (const char*)(Xlo + (rowbase + m0) * F_);
  const char* BhiB = (const char*)(Xhi + (rowbase + o0) * F_);
  const char* BloB = (const char*)(Xlo + (rowbase + o0) * F_);
  const int rb = F_ * 2;
  char* AsHB = (char*)AsH;
  char* BsHB = (char*)BsH;
  char* AsLB = (char*)AsL;
  char* BsLB = (char*)BsL;
  float* go = khalf ? g1 : g0;
  f32x4 zero = {0.f, 0.f, 0.f, 0.f};
  f32x4 acc[4][4];
#pragma unroll
  for (int i = 0; i < 4; i++)
#pragma unroll
    for (int j = 0; j < 4; j++) acc[i][j] = zero;
  const int kt0 = khalf * 12;
  for (int kt = kt0; kt < kt0 + 12; kt++) {
    const int kb = kt * 64;
#pragma unroll
    for (int u = 0; u < 2; u++) {
      int grow = u * 64 + srow;
      int gslot = sslot ^ slot_of(grow);
      size_t goff = (size_t)grow * rb + kb + gslot * 16;
      gll16(AhiB + goff, AsHB + u * 4096 + t * 16);
      gll16(BhiB + goff, BsHB + u * 4096 + t * 16);
      gll16(AloB + goff, AsLB + u * 4096 + t * 16);
      gll16(BloB + goff, BsLB + u * 4096 + t * 16);
    }
    __syncthreads();
    bf16x8 ah[4], al[4], bh[4], bl[4];
#pragma unroll
    for (int i = 0; i < 4; i++) {
      int ar = wm + i * 16 + frow;
      int aoff = ar * 64 + ((fch ^ slot_of(ar)) * 16);
      ah[i] = *(const bf16x8*)(AsHB + aoff);
      al[i] = *(const bf16x8*)(AsLB + aoff);
      int br = wn + i * 16 + frow;
      int boff = br * 64 + ((fch ^ slot_of(br)) * 16);
      bh[i] = *(const bf16x8*)(BsHB + boff);
      bl[i] = *(const bf16x8*)(BsLB + boff);
    }
    // swapped: B-tile fragments first -> D col = A-tile row (n), D row = B-tile row (m)
#pragma unroll
    for (int i = 0; i < 4; i++)
#pragma unroll
      for (int j = 0; j < 4; j++) {
        acc[i][j] = __builtin_amdgcn_mfma_f32_16x16x32_bf16(bh[j], ah[i], acc[i][j], 0, 0, 0);
        acc[i][j] = __builtin_amdgcn_mfma_f32_16x16x32_bf16(bl[j], ah[i], acc[i][j], 0, 0, 0);
        acc[i][j] = __builtin_amdgcn_mfma_f32_16x16x32_bf16(bh[j], al[i], acc[i][j], 0, 0, 0);
      }
    __syncthreads();
  }
#pragma unroll
  for (int i = 0; i < 4; i++) {
    int n = m0 + wm + i * 16 + frow;
    if (n >= N_) continue;
    float* gr = go + (rowbase + n) * LDG_;
#pragma unroll
    for (int j = 0; j < 4; j++) {
      int mb = o0 + wn + j * 16 + fch * 4;
      if (mb >= LDG_) continue;  // mb mult of 4; mb<=196 -> full in-row pack
      f32x4 pv = acc[i][j];
      *(f32x4*)&gr[mb] = pv;
      if (mirror) {
#pragma unroll
        for (int r = 0; r < 4; r++)
          go[(rowbase + mb + r) * LDG_ + n] = pv[r];
      }
    }
  }
}

// ---------------- top-4 per row -> symmetric adjacency bitmask ----------------
__global__ __launch_bounds__(256) void topk_kernel(const float* __restrict__ g0,
                                                   const float* __restrict__ g1,
                                                   const float* __restrict__ sq,
                                                   unsigned long long* __restrict__ Abits) {
  int row = blockIdx.x * 4 + (threadIdx.x >> 6);
  int lane = threadIdx.x & 63;
  int b = row / N_, n = row - b * N_;
  const float* g0r = g0 + (size_t)row * LDG_;
  const float* g1r = g1 + (size_t)row * LDG_;
  const float* sqb = sq + (size_t)b * N_;
  float v[4];
  int vi[4];
#pragma unroll
  for (int i = 0; i < 4; i++) {
    int m = lane + i * 64;
    bool ok = (m < N_) && (m != n);
    v[i] = ok ? (sqb[m] - 2.f * (g0r[m] + g1r[m])) : INFINITY;
    vi[i] = ok ? m : 0x3fffffff;
  }
  unsigned long long nbr[4] = {0ull, 0ull, 0ull, 0ull};
#pragma unroll
  for (int t = 0; t < 4; t++) {
    float bv = v[0];
    int bi = vi[0];
#pragma unroll
    for (int i = 1; i < 4; i++)
      if (v[i] < bv || (v[i] == bv && vi[i] < bi)) { bv = v[i]; bi = vi[i]; }
#pragma unroll
    for (int o = 1; o < 64; o <<= 1) {
      float ov = __shfl_xor(bv, o);
      int oi = __shfl_xor(bi, o);
      if (ov < bv || (ov == bv && oi < bi)) { bv = ov; bi = oi; }
    }
#pragma unroll
    for (int i = 0; i < 4; i++)
      if (vi[i] == bi) { v[i] = INFINITY; vi[i] = 0x3fffffff; }
    if (lane == 0) {
      nbr[bi >> 6] |= 1ull << (bi & 63);
      atomicOr(&Abits[((size_t)b * N_ + bi) * 4 + (n >> 6)], 1ull << (n & 63));
    }
  }
  if (lane == 0) {
#pragma unroll
    for (int w = 0; w < 4; w++)
      if (nbr[w]) atomicOr(&Abits[(size_t)row * 4 + w], nbr[w]);
  }
}

// ---------------- 2-hop adjacency -> bf16 [B][256][224] (phase-shifted by b&3) + deg ----
__global__ __launch_bounds__(256) void a2_kernel(const unsigned long long* __restrict__ Abits,
                                                 __hip_bfloat16* __restrict__ A2bf,
                                                 float* __restrict__ deg) {
  int row = blockIdx.x * 4 + (threadIdx.x >> 6);
  int lane = threadIdx.x & 63;
  int b = row / N_, n = row - b * N_;
  const unsigned long long* arow = Abits + (size_t)row * 4;
  const unsigned long long* base = Abits + (size_t)b * N_ * 4;
  unsigned long long r0 = 0, r1 = 0, r2 = 0, r3 = 0;
#pragma unroll
  for (int w = 0; w < 4; w++) {
    if ((arow[w] >> lane) & 1ull) {
      const unsigned long long* mr = base + (size_t)(w * 64 + lane) * 4;
      r0 |= mr[0]; r1 |= mr[1]; r2 |= mr[2]; r3 |= mr[3];
    }
  }
#pragma unroll
  for (int o = 1; o < 64; o <<= 1) {
    r0 |= __shfl_xor(r0, o);
    r1 |= __shfl_xor(r1, o);
    r2 |= __shfl_xor(r2, o);
    r3 |= __shfl_xor(r3, o);
  }
  unsigned long long rr[4] = {r0, r1, r2, r3};
  rr[n >> 6] &= ~(1ull << (n & 63));
  const int pad = b & 3;  // phase shift matches msgT store alignment
  __hip_bfloat16* out = A2bf + ((size_t)b * NA_ + n) * KA_;
  const __hip_bfloat16 one = __float2bfloat16(1.f);
  const __hip_bfloat16 zer = __float2bfloat16(0.f);
#pragma unroll
  for (int i = 0; i < 4; i++) {
    int m = lane + i * 64;
    if (m < KA_) {
      int k = m - pad;
      bool bit = (k >= 0 && k < N_ && ((rr[k >> 6] >> (k & 63)) & 1ull));
      out[m] = bit ? one : zer;
    }
  }
  if (lane == 0) {
    int dg = __popcll(rr[0]) + __popcll(rr[1]) + __popcll(rr[2]) + __popcll(rr[3]);
    deg[row] = (float)(dg > 0 ? dg : 1);
  }
}

// ---------------- merged ego+msg GEMM over concat weights [1024][K] ----------------
// o-tiles 0-3 = ego, 4-7 = msg. MODE 1 ego: SWAPPED mfma -> packed h1 stores.
// MODE 2 ego: normal mfma -> pool reduce. msg (both modes): normal mfma -> packed
// msgT[cm][b*224 + (b&3) + rr] stores (aligned by the a2 phase shift).
template <int MODE>
__global__ __launch_bounds__(256) void mfma_fused(const __hip_bfloat16* __restrict__ X,
                                                  const __hip_bfloat16* __restrict__ Wcat,
                                                  const float* __restrict__ biasE,
                                                  const float* __restrict__ biasM,
                                                  __hip_bfloat16* __restrict__ h1,
                                                  __hip_bfloat16* __restrict__ msgT,
                                                  float* __restrict__ pool,
                                                  int K) {
  __shared__ short As[4096];
  __shared__ short Bs[4096];
  const int t = threadIdx.x;
  const int wgid = blockIdx.x;
  const int L = (wgid & 7) * 197 + (wgid >> 3);
  const int m0 = (L >> 3) * 128, o0 = (L & 7) * 128;
  const int l = t & 63, w = t >> 6;
  const int wm = (w >> 1) * 64, wn = (w & 1) * 64;
  const int frow = l & 15, fch = l >> 4;
  const int srow = t >> 2, sslot = t & 3;
  const char* Abase = (const char*)(X + (size_t)m0 * K);
  const char* Bbase = (const char*)(Wcat + (size_t)o0 * K);
  const int rb = K * 2;
  char* AsB = (char*)As;
  char* BsB = (char*)Bs;
  const bool ego = (o0 < 512);
  const bool swap = (MODE == 1) && ego;
  f32x4 zero = {0.f, 0.f, 0.f, 0.f};
  f32x4 acc[4][4];
#pragma unroll
  for (int i = 0; i < 4; i++)
#pragma unroll
    for (int j = 0; j < 4; j++) acc[i][j] = zero;
  const int KT = K >> 5;
  for (int kt = 0; kt < KT; kt++) {
    const int kb = kt * 64;
#pragma unroll
    for (int u = 0; u < 2; u++) {
      int grow = u * 64 + srow;
      int gslot = sslot ^ slot_of(grow);
      gll16(Abase + (size_t)grow * rb + kb + gslot * 16, AsB + u * 4096 + t * 16);
      gll16(Bbase + (size_t)grow * rb + kb + gslot * 16, BsB + u * 4096 + t * 16);
    }
    __syncthreads();
    bf16x8 af[4], bfv[4];
#pragma unroll
    for (int i = 0; i < 4; i++) {
      int ar = wm + i * 16 + frow;
      af[i] = *(const bf16x8*)(AsB + ar * 64 + ((fch ^ slot_of(ar)) * 16));
      int br = wn + i * 16 + frow;
      bfv[i] = *(const bf16x8*)(BsB + br * 64 + ((fch ^ slot_of(br)) * 16));
    }
    if (!swap) {
#pragma unroll
      for (int i = 0; i < 4; i++)
#pragma unroll
        for (int j = 0; j < 4; j++)
          acc[i][j] = __builtin_amdgcn_mfma_f32_16x16x32_bf16(af[i], bfv[j], acc[i][j], 0, 0, 0);
    } else {
#pragma unroll
      for (int i = 0; i < 4; i++)
#pragma unroll
        for (int j = 0; j < 4; j++)
          acc[i][j] = __builtin_amdgcn_mfma_f32_16x16x32_bf16(bfv[j], af[i], acc[i][j], 0, 0, 0);
    }
    __syncthreads();
  }
  if (ego) {
    if (MODE == 1) {
      // swapped: col(frow)=xrow, row(fch*4+r)=c -> packed uint2 along c
#pragma unroll
      for (int j = 0; j < 4; j++) {
        int c0 = o0 + wn + j * 16 + fch * 4;
        float4 b4 = *(const float4*)&biasE[c0];
        float bb4[4] = {b4.x, b4.y, b4.z, b4.w};
#pragma unroll
        for (int i = 0; i < 4; i++) {
          int xrow = m0 + wm + i * 16 + frow;
          union { __hip_bfloat16 h[4]; uint2 u; } pk;
#pragma unroll
          for (int r = 0; r < 4; r++)
            pk.h[r] = __float2bfloat16(fmaxf(acc[i][j][r] + bb4[r], 0.f));
          *(uint2*)&h1[(size_t)xrow * D2_ + c0] = pk.u;
        }
      }
    } else {
      // normal: col(frow)=c, rows along fch*4+r -> pool reduce (batch-boundary aware)
#pragma unroll
      for (int j = 0; j < 4; j++) {
        int c = o0 + wn + j * 16 + frow;
        float bv = biasE[c];
        int rw = m0 + wm;
        int b0 = rw / N_;
        int rB = (b0 + 1) * N_;
        float sA = 0.f, sB = 0.f;
#pragma unroll
        for (int i = 0; i < 4; i++) {
          int r0 = m0 + wm + i * 16 + fch * 4;
#pragma unroll
          for (int r = 0; r < 4; r++) {
            float v = fmaxf(acc[i][j][r] + bv, 0.f);
            if (r0 + r < rB) sA += v; else sB += v;
          }
        }
        sA += __shfl_down(sA, 32);
        sA += __shfl_down(sA, 16);
        sB += __shfl_down(sB, 32);
        sB += __shfl_down(sB, 16);
        if (l < 16) {
          atomicAdd(&pool[(size_t)b0 * D4_ + D2_ + c], sA);
          if (rw + 64 > rB) atomicAdd(&pool[(size_t)(b0 + 1) * D4_ + D2_ + c], sB);
        }
      }
    }
  } else {
    // msg half, normal: col(frow)=cm, rows along fch*4+r = xrow -> packed along rr
#pragma unroll
    for (int j = 0; j < 4; j++) {
      int cm = (o0 - 512) + wn + j * 16 + frow;
      float bm = biasM[cm];
      __hip_bfloat16* mrow = msgT + (size_t)cm * MT_LD_;
#pragma unroll
      for (int i = 0; i < 4; i++) {
        int x0 = m0 + wm + i * 16 + fch * 4;
        int b0 = x0 / N_;
        int r0 = x0 - b0 * N_;
        union { __hip_bfloat16 h[4]; uint2 u; } pk;
#pragma unroll
        for (int r = 0; r < 4; r++) pk.h[r] = __float2bfloat16(acc[i][j][r] + bm);
        if (r0 + 3 < N_) {
          *(uint2*)&mrow[b0 * KA_ + (b0 & 3) + r0] = pk.u;  // aligned by construction
        } else {
#pragma unroll
          for (int r = 0; r < 4; r++) {
            int x = x0 + r;
            int bb = x / N_;
            int rx = x - bb * N_;
            mrow[bb * KA_ + (bb & 3) + rx] = pk.h[r];
          }
        }
      }
    }
  }
}

// ---------------- MFMA aggregation: A2[b] @ msgT-slice, SWAPPED -> packed h1 ----------
// MODE 0: h1[:,512:] + pool@poolOff; MODE 1: pool-only.
template <int MODE>
__global__ __launch_bounds__(256) void mfma_agg(const __hip_bfloat16* __restrict__ A2bf,
                                                const __hip_bfloat16* __restrict__ msgT,
                                                const float* __restrict__ deg,
                                                __hip_bfloat16* __restrict__ h1,
                                                float* __restrict__ pool, int poolOff) {
  __shared__ short As[4096];
  __shared__ short Bs[4096];
  const int t = threadIdx.x;
  const int wgid = blockIdx.x;
  const int L = (wgid & 7) * 128 + (wgid >> 3);
  const int b = L >> 3;
  const int o0 = ((L >> 1) & 3) * 128;
  const int m0 = (L & 1) * 128;
  const int l = t & 63, w = t >> 6;
  const int wm = (w >> 1) * 64, wn = (w & 1) * 64;
  const int frow = l & 15, fch = l >> 4;
  const int srow = t >> 2, sslot = t & 3;
  const char* Abase = (const char*)(A2bf + ((size_t)b * NA_ + m0) * KA_);
  const char* Bbase = (const char*)(msgT + (size_t)o0 * MT_LD_ + (size_t)b * KA_);
  char* AsB = (char*)As;
  char* BsB = (char*)Bs;
  f32x4 zero = {0.f, 0.f, 0.f, 0.f};
  f32x4 acc[4][4];
#pragma unroll
  for (int i = 0; i < 4; i++)
#pragma unroll
    for (int j = 0; j < 4; j++) acc[i][j] = zero;
  for (int kt = 0; kt < 7; kt++) {
    const int kb = kt * 64;
#pragma unroll
    for (int u = 0; u < 2; u++) {
      int grow = u * 64 + srow;
      int gslot = sslot ^ slot_of(grow);
      gll16(Abase + (size_t)grow * (KA_ * 2) + kb + gslot * 16, AsB + u * 4096 + t * 16);
      gll16(Bbase + (size_t)grow * (MT_LD_ * 2) + kb + gslot * 16, BsB + u * 4096 + t * 16);
    }
    __syncthreads();
    bf16x8 af[4], bfv[4];
#pragma unroll
    for (int i = 0; i < 4; i++) {
      int ar = wm + i * 16 + frow;
      af[i] = *(const bf16x8*)(AsB + ar * 64 + ((fch ^ slot_of(ar)) * 16));
      int br = wn + i * 16 + frow;
      bfv[i] = *(const bf16x8*)(BsB + br * 64 + ((fch ^ slot_of(br)) * 16));
    }
    // swapped: D col(frow) = A2 row (n), D row(fch*4+r) = msgT row (c)
#pragma unroll
    for (int i = 0; i < 4; i++)
#pragma unroll
      for (int j = 0; j < 4; j++)
        acc[i][j] = __builtin_amdgcn_mfma_f32_16x16x32_bf16(bfv[j], af[i], acc[i][j], 0, 0, 0);
    __syncthreads();
  }
  float sv[4][4];
#pragma unroll
  for (int j = 0; j < 4; j++)
#pragma unroll
    for (int r = 0; r < 4; r++) sv[j][r] = 0.f;
#pragma unroll
  for (int i = 0; i < 4; i++) {
    int n = m0 + wm + i * 16 + frow;
    bool ok = (n < N_);
    float dinv = ok ? (1.f / deg[b * N_ + n]) : 0.f;
#pragma unroll
    for (int j = 0; j < 4; j++) {
      int c0 = o0 + wn + j * 16 + fch * 4;
      union { __hip_bfloat16 h[4]; uint2 u; } pk;
#pragma unroll
      for (int r = 0; r < 4; r++) {
        float v = ok ? fmaxf(acc[i][j][r] * dinv, 0.f) : 0.f;
        sv[j][r] += v;
        pk.h[r] = __float2bfloat16(v);
      }
      if (MODE == 0 && ok)
        *(uint2*)&h1[((size_t)b * N_ + n) * D2_ + NH_ + c0] = pk.u;
    }
  }
#pragma unroll
  for (int j = 0; j < 4; j++) {
#pragma unroll
    for (int r = 0; r < 4; r++) {
      float s = sv[j][r];
      s += __shfl_down(s, 8, 16);
      s += __shfl_down(s, 4, 16);
      s += __shfl_down(s, 2, 16);
      s += __shfl_down(s, 1, 16);
      if ((l & 15) == 0)
        atomicAdd(&pool[(size_t)b * D4_ + poolOff + o0 + wn + j * 16 + fch * 4 + r], s);
    }
  }
}

// ---------------- pooling: gf[:, :512] = mean h1[:, :512] ----------------
__global__ __launch_bounds__(256) void pool_h1ego(const __hip_bfloat16* __restrict__ h1,
                                                  float* __restrict__ gf) {
  int b = blockIdx.y;
  int c = blockIdx.x * 256 + threadIdx.x;  // 0..511
  const __hip_bfloat16* p = h1 + (size_t)b * N_ * D2_ + c;
  float s = 0.f;
  for (int n = 0; n < N_; n++) s += __bfloat162float(p[(size_t)n * D2_]);
  gf[(size_t)b * D4_ + c] = s * (1.f / N_);
}

// ---------------- gf[:, 512:2048] = pool / N ----------------
__global__ __launch_bounds__(256) void scale_pool(const float* __restrict__ pool,
                                                  float* __restrict__ gf) {
  int b = blockIdx.y;
  int c = NH_ + blockIdx.x * 256 + threadIdx.x;  // 512..2047
  gf[(size_t)b * D4_ + c] = pool[(size_t)b * D4_ + c] * (1.f / N_);
}

// ---------------- head GEMM: split-K f32, atomic accumulate ----------------
template <bool RELUX>
__global__ __launch_bounds__(256) void head_gemm(const float* __restrict__ Xg,
                                                 const float* __restrict__ W,
                                                 const float* __restrict__ bias,
                                                 float* __restrict__ Y,
                                                 int Rows, int Fin, int O, int kchunk) {
  __shared__ float Xs[16][68];
  __shared__ float Ws[16][68];
  int tx = threadIdx.x, ty = threadIdx.y;
  int tid = ty * 16 + tx;
  int lr = tid >> 2;
  int lk = (tid & 3) * 4;
  int rbase = blockIdx.y * 64;
  int o0 = blockIdx.x * 64;
  int k0base = blockIdx.z * kchunk;
  float acc[4][4] = {};
  for (int k0 = k0base; k0 < k0base + kchunk; k0 += 16) {
    float4 xv = make_float4(0.f, 0.f, 0.f, 0.f);
    if (rbase + lr < Rows) xv = *(const float4*)&Xg[(size_t)(rbase + lr) * Fin + k0 + lk];
    if (RELUX) {
      xv.x = fmaxf(xv.x, 0.f); xv.y = fmaxf(xv.y, 0.f);
      xv.z = fmaxf(xv.z, 0.f); xv.w = fmaxf(xv.w, 0.f);
    }
    Xs[lk][lr] = xv.x; Xs[lk + 1][lr] = xv.y; Xs[lk + 2][lr] = xv.z; Xs[lk + 3][lr] = xv.w;
    float4 wv = make_float4(0.f, 0.f, 0.f, 0.f);
    if (o0 + lr < O) wv = *(const float4*)&W[(size_t)(o0 + lr) * Fin + k0 + lk];
    Ws[lk][lr] = wv.x; Ws[lk + 1][lr] = wv.y; Ws[lk + 2][lr] = wv.z; Ws[lk + 3][lr] = wv.w;
    __syncthreads();
#pragma unroll
    for (int k = 0; k < 16; k++) {
      float4 a = *(const float4*)&Xs[k][ty * 4];
      float4 bb = *(const float4*)&Ws[k][tx * 4];
      float av[4] = {a.x, a.y, a.z, a.w};
      float bv[4] = {bb.x, bb.y, bb.z, bb.w};
#pragma unroll
      for (int i = 0; i < 4; i++)
#pragma unroll
        for (int j = 0; j < 4; j++) acc[i][j] = fmaf(av[i], bv[j], acc[i][j]);
    }
    __syncthreads();
  }
#pragma unroll
  for (int i = 0; i < 4; i++) {
    int rrow = rbase + ty * 4 + i;
    if (rrow >= Rows) continue;
#pragma unroll
    for (int j = 0; j < 4; j++) {
      int c = o0 + tx * 4 + j;
      if (c >= O) continue;
      float vv = acc[i][j] + ((blockIdx.z == 0) ? bias[c] : 0.f);
      atomicAdd(&Y[(size_t)rrow * O + c], vv);
    }
  }
}

// ---------------- host launch ----------------
extern "C" void kernel_launch(void* const* d_in, const int* in_sizes, int n_in,
                              void* d_out, int out_size, void* d_ws, size_t ws_size,
                              hipStream_t stream) {
  const float* Fet  = (const float*)d_in[0];
  const float* w1_0 = (const float*)d_in[1];
  const float* b1_0 = (const float*)d_in[2];
  const float* w2_0 = (const float*)d_in[3];
  const float* b2_0 = (const float*)d_in[4];
  const float* w1_1 = (const float*)d_in[5];
  const float* b1_1 = (const float*)d_in[6];
  const float* w2_1 = (const float*)d_in[7];
  const float* b2_1 = (const float*)d_in[8];
  const float* fc1_w = (const float*)d_in[9];
  const float* fc1_b = (const float*)d_in[10];
  const float* fc2_w = (const float*)d_in[11];
  const float* fc2_b = (const float*)d_in[12];

  char* ws = (char*)d_ws;
  float* g0 = (float*)(ws + OFF_G0);
  float* g1 = (float*)(ws + OFF_G1);
  __hip_bfloat16* A2bf = (__hip_bfloat16*)(ws + OFF_G0);  // overlay (g0 dead after topk)
  float* sq = (float*)(ws + OFF_SQ);
  unsigned long long* Abits = (unsigned long long*)(ws + OFF_ABITS);
  float* deg = (float*)(ws + OFF_DEG);
  __hip_bfloat16* Fet_hi = (__hip_bfloat16*)(ws + OFF_FETHI);
  __hip_bfloat16* Fet_lo = (__hip_bfloat16*)(ws + OFF_FETLO);  // overlay msgT/h1 head
  __hip_bfloat16* msgT = (__hip_bfloat16*)(ws + OFF_MSGT);
  __hip_bfloat16* h1 = (__hip_bfloat16*)(ws + OFF_H1);
  float* pool = (float*)(ws + OFF_POOL);
  float* p = (float*)(ws + OFF_P);
  __hip_bfloat16* wc1 = (__hip_bfloat16*)(ws + OFF_WC1);
  __hip_bfloat16* wc2 = (__hip_bfloat16*)(ws + OFF_WC2);

  float* out = (float*)d_out;          // [B, NC]
  float* gf = out + (size_t)B_ * NC_;  // [B, D4]

  hipMemsetAsync(Abits, 0, (size_t)ROWS_ * 4 * sizeof(unsigned long long), stream);
  hipMemsetAsync(pool, 0, (size_t)B_ * D4_ * sizeof(float), stream);
  hipMemsetAsync(p, 0, (size_t)B_ * NH_ * sizeof(float), stream);
  hipMemsetAsync(out, 0, (size_t)B_ * NC_ * sizeof(float), stream);

  // casts
  cast_hilo_sq<<<ROWS_ / 4, 256, 0, stream>>>(Fet, Fet_hi, Fet_lo, sq);
  cast_weights<<<1792, 256, 0, stream>>>(w1_0, w2_0, w1_1, w2_1, wc1, wc2);

  // graph construction
  mfma_gram<<<768, 256, 0, stream>>>(Fet_hi, Fet_lo, g0, g1);
  topk_kernel<<<ROWS_ / 4, 256, 0, stream>>>(g0, g1, sq, Abits);
  a2_kernel<<<ROWS_ / 4, 256, 0, stream>>>(Abits, A2bf, deg);

  // layer 1 (Fet_lo dead from here; msgT/h1 overwrite it)
  mfma_fused<1><<<1576, 256, 0, stream>>>(Fet_hi, wc1, b1_0, b2_0, h1, msgT, nullptr, F_);
  mfma_agg<0><<<1024, 256, 0, stream>>>(A2bf, msgT, deg, h1, pool, NH_);

  // layer 2 (ego2 pooled in-epilogue; msg2 -> msgT -> agg2 pooled)
  mfma_fused<2><<<1576, 256, 0, stream>>>(h1, wc2, b1_1, b2_1, nullptr, msgT, pool, D2_);
  mfma_agg<1><<<1024, 256, 0, stream>>>(A2bf, msgT, deg, nullptr, pool, D2_ + NH_);

  // pooling -> graph_features
  pool_h1ego<<<dim3(2, B_), 256, 0, stream>>>(h1, gf);
  scale_pool<<<dim3(6, B_), 256, 0, stream>>>(pool, gf);

  // head (f32, split-K + atomics; fc1 relu folded into fc2 X-load)
  head_gemm<false><<<dim3(8, 2, 16), dim3(16, 16), 0, stream>>>(
      gf, fc1_w, fc1_b, p, B_, D4_, NH_, 128);
  head_gemm<true><<<dim3(16, 2, 8), dim3(16, 16), 0, stream>>>(
      p, fc2_w, fc2_b, out, B_, NH_, NC_, 64);
}